// Round 1
// baseline (5474.744 us; speedup 1.0000x reference)
//
#include <hip/hip_runtime.h>
#include <hip/hip_bf16.h>
#include <math.h>

#define NEG 0.2f

// ---- float ordered <-> uint encoding for atomicMax on floats (incl. negatives)
__device__ __forceinline__ unsigned f2ord(float f) {
    unsigned u = __float_as_uint(f);
    return (u & 0x80000000u) ? ~u : (u | 0x80000000u);
}
__device__ __forceinline__ float ord2f(unsigned u) {
    return __uint_as_float((u & 0x80000000u) ? (u ^ 0x80000000u) : ~u);
}

// ---- Y[n][256] = X[n][256] @ W[256][256] + b[256]
__global__ __launch_bounds__(256) void gemm256(const float* __restrict__ X,
                                               const float* __restrict__ W,
                                               const float* __restrict__ b,
                                               float* __restrict__ Y, int nrows) {
    const int ROWS = 8;
    __shared__ float xs[ROWS][256];
    int c = threadIdx.x;
    int row0 = blockIdx.x * ROWS;
#pragma unroll
    for (int r = 0; r < ROWS; ++r) {
        int row = row0 + r;
        xs[r][c] = (row < nrows) ? X[(size_t)row * 256 + c] : 0.f;
    }
    __syncthreads();
    float acc[ROWS];
#pragma unroll
    for (int r = 0; r < ROWS; ++r) acc[r] = 0.f;
#pragma unroll 4
    for (int k = 0; k < 256; ++k) {
        float w = W[k * 256 + c];
#pragma unroll
        for (int r = 0; r < ROWS; ++r) acc[r] += xs[r][k] * w;
    }
    float bb = b[c];
#pragma unroll
    for (int r = 0; r < ROWS; ++r) {
        int row = row0 + r;
        if (row < nrows) Y[(size_t)row * 256 + c] = acc[r] + bb;
    }
}

// ---- per edge (one wave64 each): logit = att . leaky_relu(xl[src]+xr[dst]);
//      segment max into m_enc[dst]
__global__ __launch_bounds__(256) void edge_logits(const float* __restrict__ xl,
                                                   const float* __restrict__ xr,
                                                   const int* __restrict__ src,
                                                   const int* __restrict__ dst,
                                                   int Ereal, int nedges,
                                                   const float* __restrict__ att,
                                                   float* __restrict__ logit,
                                                   unsigned* __restrict__ m_enc) {
    int wid = (int)((blockIdx.x * (size_t)blockDim.x + threadIdx.x) >> 6);
    int lane = threadIdx.x & 63;
    if (wid >= nedges) return;
    int s, d;
    if (wid < Ereal) { s = src[wid]; d = dst[wid]; }
    else             { s = d = wid - Ereal; }

    float4 a = ((const float4*)(xl + (size_t)s * 256))[lane];
    float4 b = ((const float4*)(xr + (size_t)d * 256))[lane];
    float4 t = ((const float4*)att)[lane];
    float v0 = a.x + b.x; v0 = v0 > 0.f ? v0 : NEG * v0;
    float v1 = a.y + b.y; v1 = v1 > 0.f ? v1 : NEG * v1;
    float v2 = a.z + b.z; v2 = v2 > 0.f ? v2 : NEG * v2;
    float v3 = a.w + b.w; v3 = v3 > 0.f ? v3 : NEG * v3;
    float dot = v0 * t.x + v1 * t.y + v2 * t.z + v3 * t.w;
#pragma unroll
    for (int off = 32; off > 0; off >>= 1) dot += __shfl_down(dot, off);
    if (lane == 0) {
        logit[wid] = dot;
        atomicMax(m_enc + d, f2ord(dot));
    }
}

// ---- per edge: ex = exp(logit - m[dst]); out[dst] += ex*xl[src]; s[dst] += ex
__global__ __launch_bounds__(256) void edge_accum(const float* __restrict__ xl,
                                                  const int* __restrict__ src,
                                                  const int* __restrict__ dst,
                                                  int Ereal, int nedges,
                                                  const float* __restrict__ logit,
                                                  const unsigned* __restrict__ m_enc,
                                                  float* __restrict__ out,
                                                  float* __restrict__ ssum) {
    int wid = (int)((blockIdx.x * (size_t)blockDim.x + threadIdx.x) >> 6);
    int lane = threadIdx.x & 63;
    if (wid >= nedges) return;
    int s, d;
    if (wid < Ereal) { s = src[wid]; d = dst[wid]; }
    else             { s = d = wid - Ereal; }

    float m = ord2f(m_enc[d]);
    float ex = expf(logit[wid] - m);
    float4 a = ((const float4*)(xl + (size_t)s * 256))[lane];
    float* o = out + (size_t)d * 256 + lane * 4;
    atomicAdd(o + 0, ex * a.x);
    atomicAdd(o + 1, ex * a.y);
    atomicAdd(o + 2, ex * a.z);
    atomicAdd(o + 3, ex * a.w);
    if (lane == 0) atomicAdd(ssum + d, ex);
}

// ---- y = leaky_relu(acc / s + bias), in place over [n*256]
__global__ __launch_bounds__(256) void finalize_layer(float* __restrict__ C,
                                                      const float* __restrict__ ssum,
                                                      const float* __restrict__ bias,
                                                      int n) {
    int i = blockIdx.x * blockDim.x + threadIdx.x;
    if (i >= n * 256) return;
    int node = i >> 8;
    int c = i & 255;
    float v = C[i] / ssum[node] + bias[c];
    C[i] = v > 0.f ? v : NEG * v;
}

// ---- per node (one wave64): z = y @ Wlin + blin; out = log_softmax(z)
__global__ __launch_bounds__(256) void head_kernel(const float* __restrict__ y,
                                                   const float* __restrict__ Wlin,
                                                   const float* __restrict__ blin,
                                                   float* __restrict__ out, int n) {
    int wid = (int)((blockIdx.x * (size_t)blockDim.x + threadIdx.x) >> 6);
    int lane = threadIdx.x & 63;
    if (wid >= n) return;
    float4 a = ((const float4*)(y + (size_t)wid * 256))[lane];
    // Wlin is [256][2]; float4 pairs cover rows (c0,c0+1) and (c0+2,c0+3)
    float4 w01 = ((const float4*)Wlin)[lane * 2];
    float4 w23 = ((const float4*)Wlin)[lane * 2 + 1];
    float z0 = a.x * w01.x + a.y * w01.z + a.z * w23.x + a.w * w23.z;
    float z1 = a.x * w01.y + a.y * w01.w + a.z * w23.y + a.w * w23.w;
#pragma unroll
    for (int off = 32; off > 0; off >>= 1) {
        z0 += __shfl_down(z0, off);
        z1 += __shfl_down(z1, off);
    }
    if (lane == 0) {
        z0 += blin[0];
        z1 += blin[1];
        float mx = fmaxf(z0, z1);
        float lse = mx + logf(expf(z0 - mx) + expf(z1 - mx));
        out[(size_t)wid * 2 + 0] = z0 - lse;
        out[(size_t)wid * 2 + 1] = z1 - lse;
    }
}

extern "C" void kernel_launch(void* const* d_in, const int* in_sizes, int n_in,
                              void* d_out, int out_size, void* d_ws, size_t ws_size,
                              hipStream_t stream) {
    const float* fts   = (const float*)d_in[0];
    const int*   graph = (const int*)d_in[1];
    const float* Wl0 = (const float*)d_in[2];
    const float* Wr0 = (const float*)d_in[3];
    const float* bl0 = (const float*)d_in[4];
    const float* br0 = (const float*)d_in[5];
    const float* att0 = (const float*)d_in[6];
    const float* b0  = (const float*)d_in[7];
    const float* Wl1 = (const float*)d_in[8];
    const float* Wr1 = (const float*)d_in[9];
    const float* bl1 = (const float*)d_in[10];
    const float* br1 = (const float*)d_in[11];
    const float* att1 = (const float*)d_in[12];
    const float* b1  = (const float*)d_in[13];
    const float* Wlin = (const float*)d_in[14];
    const float* blin = (const float*)d_in[15];

    int N = out_size / 2;                                   // 40000
    long T = in_sizes[0] / ((long)N * 256);                 // 4
    long E = in_sizes[1] / (2 * T);                         // 640000
    int EP = (int)E + N;                                    // edges + self loops

    // workspace partition (256B aligned slices)
    char* ws = (char*)d_ws;
    size_t off = 0;
    auto alloc = [&](size_t bytes) -> void* {
        void* p = ws + off;
        off += (bytes + 255) & ~(size_t)255;
        return p;
    };
    float*    A     = (float*)alloc((size_t)N * 256 * 4);   // xl
    float*    B     = (float*)alloc((size_t)N * 256 * 4);   // xr
    float*    C     = (float*)alloc((size_t)N * 256 * 4);   // acc / y (reused)
    float*    logit = (float*)alloc((size_t)EP * 4);
    unsigned* m_enc = (unsigned*)alloc((size_t)N * 4);
    float*    ssum  = (float*)alloc((size_t)N * 4);
    (void)ws_size; (void)n_in;

    int gemm_blocks = (N + 7) / 8;
    int edge_blocks = (EP + 3) / 4;     // 4 waves (edges) per 256-thread block
    int fin_blocks  = (N * 256 + 255) / 256;
    int head_blocks = (N + 3) / 4;

    // ---------- layer 0 (x = fts[0], edges from t=0) ----------
    const int* src0 = graph;            // graph[0,0,:]
    const int* dst0 = graph + E;        // graph[0,1,:]
    gemm256<<<gemm_blocks, 256, 0, stream>>>(fts, Wl0, bl0, A, N);
    gemm256<<<gemm_blocks, 256, 0, stream>>>(fts, Wr0, br0, B, N);
    hipMemsetAsync(C, 0, (size_t)N * 256 * 4, stream);
    hipMemsetAsync(m_enc, 0, (size_t)N * 4, stream);
    hipMemsetAsync(ssum, 0, (size_t)N * 4, stream);
    edge_logits<<<edge_blocks, 256, 0, stream>>>(A, B, src0, dst0, (int)E, EP, att0, logit, m_enc);
    edge_accum<<<edge_blocks, 256, 0, stream>>>(A, src0, dst0, (int)E, EP, logit, m_enc, C, ssum);
    finalize_layer<<<fin_blocks, 256, 0, stream>>>(C, ssum, b0, N);

    // ---------- layer 1 (x = C, edges from t=T-1) ----------
    const int* srcL = graph + (T - 1) * 2 * E;
    const int* dstL = graph + (T - 1) * 2 * E + E;
    gemm256<<<gemm_blocks, 256, 0, stream>>>(C, Wl1, bl1, A, N);
    gemm256<<<gemm_blocks, 256, 0, stream>>>(C, Wr1, br1, B, N);
    hipMemsetAsync(C, 0, (size_t)N * 256 * 4, stream);   // C (y) is dead after the two GEMMs
    hipMemsetAsync(m_enc, 0, (size_t)N * 4, stream);
    hipMemsetAsync(ssum, 0, (size_t)N * 4, stream);
    edge_logits<<<edge_blocks, 256, 0, stream>>>(A, B, srcL, dstL, (int)E, EP, att1, logit, m_enc);
    edge_accum<<<edge_blocks, 256, 0, stream>>>(A, srcL, dstL, (int)E, EP, logit, m_enc, C, ssum);
    finalize_layer<<<fin_blocks, 256, 0, stream>>>(C, ssum, b1, N);

    // ---------- head ----------
    head_kernel<<<head_blocks, 256, 0, stream>>>(C, Wlin, blin, (float*)d_out, N);
}

// Round 2
// 943.379 us; speedup vs baseline: 5.8033x; 5.8033x over previous
//
#include <hip/hip_runtime.h>
#include <hip/hip_bf16.h>
#include <math.h>

#define NEG 0.2f

// ---- fused dual GEMM: A = X@Wl + bl, B = X@Wr + br  (all [n,256]x[256,256])
__global__ __launch_bounds__(256) void gemm256_dual(const float* __restrict__ X,
                                                    const float* __restrict__ Wl,
                                                    const float* __restrict__ bl,
                                                    const float* __restrict__ Wr,
                                                    const float* __restrict__ br,
                                                    float* __restrict__ A,
                                                    float* __restrict__ B, int nrows) {
    const int ROWS = 8;
    __shared__ float xs[ROWS][256];
    int c = threadIdx.x;
    int row0 = blockIdx.x * ROWS;
#pragma unroll
    for (int r = 0; r < ROWS; ++r) {
        int row = row0 + r;
        xs[r][c] = (row < nrows) ? X[(size_t)row * 256 + c] : 0.f;
    }
    __syncthreads();
    float accl[ROWS], accr[ROWS];
#pragma unroll
    for (int r = 0; r < ROWS; ++r) { accl[r] = 0.f; accr[r] = 0.f; }
#pragma unroll 2
    for (int k = 0; k < 256; ++k) {
        float wl = Wl[k * 256 + c];
        float wr = Wr[k * 256 + c];
#pragma unroll
        for (int r = 0; r < ROWS; ++r) {
            float x = xs[r][k];
            accl[r] += x * wl;
            accr[r] += x * wr;
        }
    }
    float bbl = bl[c], bbr = br[c];
#pragma unroll
    for (int r = 0; r < ROWS; ++r) {
        int row = row0 + r;
        if (row < nrows) {
            A[(size_t)row * 256 + c] = accl[r] + bbl;
            B[(size_t)row * 256 + c] = accr[r] + bbr;
        }
    }
}

// ---- CSR build: histogram of dst (incl. self loops)
__global__ __launch_bounds__(256) void hist_kernel(const int* __restrict__ dst,
                                                   int Ereal, int nedges,
                                                   int* __restrict__ count) {
    int i = blockIdx.x * blockDim.x + threadIdx.x;
    if (i >= nedges) return;
    int d = (i < Ereal) ? dst[i] : (i - Ereal);
    atomicAdd(&count[d], 1);
}

// ---- single-block exclusive scan: rowptr[0..n], next[i]=rowptr[i]
__global__ __launch_bounds__(1024) void scan_kernel(const int* __restrict__ count,
                                                    int* __restrict__ rowptr,
                                                    int* __restrict__ next, int n) {
    __shared__ int part[1024];
    int tid = threadIdx.x;
    int chunk = (n + 1023) / 1024;
    int beg = tid * chunk;
    int end = beg + chunk; if (end > n) end = n; if (beg > n) beg = n;
    int s = 0;
    for (int i = beg; i < end; ++i) s += count[i];
    part[tid] = s;
    __syncthreads();
    for (int off = 1; off < 1024; off <<= 1) {
        int v = (tid >= off) ? part[tid - off] : 0;
        __syncthreads();
        part[tid] += v;
        __syncthreads();
    }
    int run = (tid == 0) ? 0 : part[tid - 1];
    for (int i = beg; i < end; ++i) {
        rowptr[i] = run;
        next[i] = run;
        run += count[i];
    }
    if (tid == 0) rowptr[n] = part[1023];
}

// ---- CSR scatter: csr_src[pos] = src of each edge, grouped by dst
__global__ __launch_bounds__(256) void scatter_kernel(const int* __restrict__ src,
                                                      const int* __restrict__ dst,
                                                      int Ereal, int nedges,
                                                      int* __restrict__ next,
                                                      int* __restrict__ csr_src) {
    int i = blockIdx.x * blockDim.x + threadIdx.x;
    if (i >= nedges) return;
    int s, d;
    if (i < Ereal) { s = src[i]; d = dst[i]; }
    else           { s = d = i - Ereal; }
    int pos = atomicAdd(&next[d], 1);
    csr_src[pos] = s;
}

// ---- fused GATv2 node pass: one wave64 per node, online softmax over incoming
//      edges; y = leaky_relu(acc/s + bias)
__global__ __launch_bounds__(256) void gat_node(const float* __restrict__ xl,
                                                const float* __restrict__ xr,
                                                const int* __restrict__ rowptr,
                                                const int* __restrict__ csr_src,
                                                const float* __restrict__ att,
                                                const float* __restrict__ bias,
                                                float* __restrict__ y, int n) {
    int wid = (int)((blockIdx.x * (size_t)blockDim.x + threadIdx.x) >> 6);
    int lane = threadIdx.x & 63;
    if (wid >= n) return;
    int beg = rowptr[wid], end = rowptr[wid + 1];
    float4 xrv = ((const float4*)(xr + (size_t)wid * 256))[lane];
    float4 t = ((const float4*)att)[lane];
    float m = -INFINITY, ssum = 0.f;
    float4 acc = make_float4(0.f, 0.f, 0.f, 0.f);
    for (int j = beg; j < end; ++j) {
        int s = csr_src[j];
        float4 a = ((const float4*)(xl + (size_t)s * 256))[lane];
        float v0 = a.x + xrv.x; v0 = v0 > 0.f ? v0 : NEG * v0;
        float v1 = a.y + xrv.y; v1 = v1 > 0.f ? v1 : NEG * v1;
        float v2 = a.z + xrv.z; v2 = v2 > 0.f ? v2 : NEG * v2;
        float v3 = a.w + xrv.w; v3 = v3 > 0.f ? v3 : NEG * v3;
        float dot = v0 * t.x + v1 * t.y + v2 * t.z + v3 * t.w;
#pragma unroll
        for (int off = 32; off > 0; off >>= 1) dot += __shfl_xor(dot, off);
        float newm = fmaxf(m, dot);
        float scale = expf(m - newm);       // m=-inf first iter -> 0
        float p = expf(dot - newm);
        ssum = ssum * scale + p;
        acc.x = acc.x * scale + p * a.x;
        acc.y = acc.y * scale + p * a.y;
        acc.z = acc.z * scale + p * a.z;
        acc.w = acc.w * scale + p * a.w;
        m = newm;
    }
    float inv = 1.f / ssum;
    float4 bb = ((const float4*)bias)[lane];
    float4 o;
    o.x = acc.x * inv + bb.x; o.x = o.x > 0.f ? o.x : NEG * o.x;
    o.y = acc.y * inv + bb.y; o.y = o.y > 0.f ? o.y : NEG * o.y;
    o.z = acc.z * inv + bb.z; o.z = o.z > 0.f ? o.z : NEG * o.z;
    o.w = acc.w * inv + bb.w; o.w = o.w > 0.f ? o.w : NEG * o.w;
    ((float4*)(y + (size_t)wid * 256))[lane] = o;
}

// ---- per node (one wave64): z = y @ Wlin + blin; out = log_softmax(z)
__global__ __launch_bounds__(256) void head_kernel(const float* __restrict__ y,
                                                   const float* __restrict__ Wlin,
                                                   const float* __restrict__ blin,
                                                   float* __restrict__ out, int n) {
    int wid = (int)((blockIdx.x * (size_t)blockDim.x + threadIdx.x) >> 6);
    int lane = threadIdx.x & 63;
    if (wid >= n) return;
    float4 a = ((const float4*)(y + (size_t)wid * 256))[lane];
    float4 w01 = ((const float4*)Wlin)[lane * 2];
    float4 w23 = ((const float4*)Wlin)[lane * 2 + 1];
    float z0 = a.x * w01.x + a.y * w01.z + a.z * w23.x + a.w * w23.z;
    float z1 = a.x * w01.y + a.y * w01.w + a.z * w23.y + a.w * w23.w;
#pragma unroll
    for (int off = 32; off > 0; off >>= 1) {
        z0 += __shfl_down(z0, off);
        z1 += __shfl_down(z1, off);
    }
    if (lane == 0) {
        z0 += blin[0];
        z1 += blin[1];
        float mx = fmaxf(z0, z1);
        float lse = mx + logf(expf(z0 - mx) + expf(z1 - mx));
        out[(size_t)wid * 2 + 0] = z0 - lse;
        out[(size_t)wid * 2 + 1] = z1 - lse;
    }
}

extern "C" void kernel_launch(void* const* d_in, const int* in_sizes, int n_in,
                              void* d_out, int out_size, void* d_ws, size_t ws_size,
                              hipStream_t stream) {
    const float* fts   = (const float*)d_in[0];
    const int*   graph = (const int*)d_in[1];
    const float* Wl0 = (const float*)d_in[2];
    const float* Wr0 = (const float*)d_in[3];
    const float* bl0 = (const float*)d_in[4];
    const float* br0 = (const float*)d_in[5];
    const float* att0 = (const float*)d_in[6];
    const float* b0  = (const float*)d_in[7];
    const float* Wl1 = (const float*)d_in[8];
    const float* Wr1 = (const float*)d_in[9];
    const float* bl1 = (const float*)d_in[10];
    const float* br1 = (const float*)d_in[11];
    const float* att1 = (const float*)d_in[12];
    const float* b1  = (const float*)d_in[13];
    const float* Wlin = (const float*)d_in[14];
    const float* blin = (const float*)d_in[15];

    int N = out_size / 2;                                   // 40000
    long T = in_sizes[0] / ((long)N * 256);                 // 4
    long E = in_sizes[1] / (2 * T);                         // 640000
    int EP = (int)E + N;                                    // edges + self loops

    char* ws = (char*)d_ws;
    size_t off = 0;
    auto alloc = [&](size_t bytes) -> void* {
        void* p = ws + off;
        off += (bytes + 255) & ~(size_t)255;
        return p;
    };
    float* A       = (float*)alloc((size_t)N * 256 * 4);    // xl
    float* B       = (float*)alloc((size_t)N * 256 * 4);    // xr
    float* C       = (float*)alloc((size_t)N * 256 * 4);    // x in / y out
    int*   count   = (int*)alloc((size_t)N * 4);
    int*   rowptr  = (int*)alloc((size_t)(N + 1) * 4);
    int*   next    = (int*)alloc((size_t)N * 4);
    int*   csr_src = (int*)alloc((size_t)EP * 4);
    (void)ws_size; (void)n_in;

    int gemm_blocks = (N + 7) / 8;
    int edge_blocks = (EP + 255) / 256;
    int node_blocks = (N + 3) / 4;

    // ---------- layer 0 (x = fts[0], edges from t=0) ----------
    const int* src0 = graph;
    const int* dst0 = graph + E;
    gemm256_dual<<<gemm_blocks, 256, 0, stream>>>(fts, Wl0, bl0, Wr0, br0, A, B, N);
    hipMemsetAsync(count, 0, (size_t)N * 4, stream);
    hist_kernel<<<edge_blocks, 256, 0, stream>>>(dst0, (int)E, EP, count);
    scan_kernel<<<1, 1024, 0, stream>>>(count, rowptr, next, N);
    scatter_kernel<<<edge_blocks, 256, 0, stream>>>(src0, dst0, (int)E, EP, next, csr_src);
    gat_node<<<node_blocks, 256, 0, stream>>>(A, B, rowptr, csr_src, att0, b0, C, N);

    // ---------- layer 1 (x = C, edges from t=T-1) ----------
    const int* srcL = graph + (T - 1) * 2 * E;
    const int* dstL = graph + (T - 1) * 2 * E + E;
    gemm256_dual<<<gemm_blocks, 256, 0, stream>>>(C, Wl1, bl1, Wr1, br1, A, B, N);
    hipMemsetAsync(count, 0, (size_t)N * 4, stream);
    hist_kernel<<<edge_blocks, 256, 0, stream>>>(dstL, (int)E, EP, count);
    scan_kernel<<<1, 1024, 0, stream>>>(count, rowptr, next, N);
    scatter_kernel<<<edge_blocks, 256, 0, stream>>>(srcL, dstL, (int)E, EP, next, csr_src);
    gat_node<<<node_blocks, 256, 0, stream>>>(A, B, rowptr, csr_src, att1, b1, C, N);

    // ---------- head ----------
    head_kernel<<<node_blocks, 256, 0, stream>>>(C, Wlin, blin, (float*)d_out, N);
}

// Round 3
// 844.148 us; speedup vs baseline: 6.4855x; 1.1176x over previous
//
#include <hip/hip_runtime.h>
#include <hip/hip_bf16.h>
#include <math.h>

#define NEG 0.2f

typedef short bf16x8 __attribute__((ext_vector_type(8)));
typedef float f32x4 __attribute__((ext_vector_type(4)));

__device__ __forceinline__ unsigned short f2bf(float x) {
    unsigned u = __float_as_uint(x);
    unsigned r = (u + 0x7fffu + ((u >> 16) & 1u)) >> 16;
    return (unsigned short)r;
}
__device__ __forceinline__ float bf2f(unsigned short b) {
    return __uint_as_float(((unsigned)b) << 16);
}

// ---- fp32 -> bf16 hi/lo split, vectorized 4 at a time
__global__ __launch_bounds__(256) void convert_x(const float* __restrict__ X,
                                                 unsigned short* __restrict__ hi,
                                                 unsigned short* __restrict__ lo,
                                                 int total4) {
    int i = blockIdx.x * blockDim.x + threadIdx.x;
    if (i >= total4) return;
    float4 v = ((const float4*)X)[i];
    ushort4 h, l;
    h.x = f2bf(v.x); l.x = f2bf(v.x - bf2f(h.x));
    h.y = f2bf(v.y); l.y = f2bf(v.y - bf2f(h.y));
    h.z = f2bf(v.z); l.z = f2bf(v.z - bf2f(h.z));
    h.w = f2bf(v.w); l.w = f2bf(v.w - bf2f(h.w));
    ((ushort4*)hi)[i] = h;
    ((ushort4*)lo)[i] = l;
}

// ---- build transposed combined weight Wt[n][k] (n<256: Wl col n, else Wr col n-256)
__global__ __launch_bounds__(256) void convert_w(const float* __restrict__ Wl,
                                                 const float* __restrict__ Wr,
                                                 unsigned short* __restrict__ Wthi,
                                                 unsigned short* __restrict__ Wtlo) {
    int idx = blockIdx.x * blockDim.x + threadIdx.x;   // n*256 + k
    int n = idx >> 8, k = idx & 255;
    float v = (n < 256) ? Wl[k * 256 + n] : Wr[k * 256 + (n - 256)];
    unsigned short h = f2bf(v);
    Wthi[idx] = h;
    Wtlo[idx] = f2bf(v - bf2f(h));
}

// ---- split-bf16 MFMA GEMM: [M,256] x [256,512] -> A (cols 0-255, +bl), B (cols 256-511, +br)
//      tile 128x128, 4 waves; fragments loaded directly from L2/L3 (no LDS)
__global__ __launch_bounds__(256) void mfma_gemm(const unsigned short* __restrict__ Xhi,
                                                 const unsigned short* __restrict__ Xlo,
                                                 const unsigned short* __restrict__ Wthi,
                                                 const unsigned short* __restrict__ Wtlo,
                                                 const float* __restrict__ bl,
                                                 const float* __restrict__ br,
                                                 float* __restrict__ A,
                                                 float* __restrict__ B, int M) {
    int wave = threadIdx.x >> 6, lane = threadIdx.x & 63;
    int m0 = blockIdx.x * 128 + wave * 32;
    int n0 = blockIdx.y * 128;
    int lr = lane & 15;          // A row-in-tile / B col-in-tile
    int kq = (lane >> 4) * 8;    // k chunk base

    f32x4 acc[2][8];
#pragma unroll
    for (int r = 0; r < 2; ++r)
#pragma unroll
        for (int c = 0; c < 8; ++c) acc[r][c] = (f32x4){0.f, 0.f, 0.f, 0.f};

    for (int k0 = 0; k0 < 256; k0 += 32) {
        int kk = k0 + kq;
        bf16x8 ah[2], al[2];
#pragma unroll
        for (int r = 0; r < 2; ++r) {
            int row = m0 + r * 16 + lr;
            if (row > M - 1) row = M - 1;
            ah[r] = *(const bf16x8*)(Xhi + (size_t)row * 256 + kk);
            al[r] = *(const bf16x8*)(Xlo + (size_t)row * 256 + kk);
        }
#pragma unroll
        for (int c = 0; c < 8; ++c) {
            int n = n0 + c * 16 + lr;
            bf16x8 bh = *(const bf16x8*)(Wthi + (size_t)n * 256 + kk);
            bf16x8 bo = *(const bf16x8*)(Wtlo + (size_t)n * 256 + kk);
#pragma unroll
            for (int r = 0; r < 2; ++r) {
                acc[r][c] = __builtin_amdgcn_mfma_f32_16x16x32_bf16(ah[r], bh, acc[r][c], 0, 0, 0);
                acc[r][c] = __builtin_amdgcn_mfma_f32_16x16x32_bf16(al[r], bh, acc[r][c], 0, 0, 0);
                acc[r][c] = __builtin_amdgcn_mfma_f32_16x16x32_bf16(ah[r], bo, acc[r][c], 0, 0, 0);
            }
        }
    }

#pragma unroll
    for (int c = 0; c < 8; ++c) {
        int n = n0 + c * 16 + lr;
        bool left = n < 256;
        float bb = left ? bl[n] : br[n - 256];
        float* Y = left ? A : B;
        int col = left ? n : n - 256;
#pragma unroll
        for (int r = 0; r < 2; ++r) {
            int rowb = m0 + r * 16 + (lane >> 4) * 4;
#pragma unroll
            for (int j = 0; j < 4; ++j) {
                int row = rowb + j;
                if (row < M) Y[(size_t)row * 256 + col] = acc[r][c][j] + bb;
            }
        }
    }
}

// ---- CSR build: histogram of dst (incl. self loops)
__global__ __launch_bounds__(256) void hist_kernel(const int* __restrict__ dst,
                                                   int Ereal, int nedges,
                                                   int* __restrict__ count) {
    int i = blockIdx.x * blockDim.x + threadIdx.x;
    if (i >= nedges) return;
    int d = (i < Ereal) ? dst[i] : (i - Ereal);
    atomicAdd(&count[d], 1);
}

// ---- single-block exclusive scan
__global__ __launch_bounds__(1024) void scan_kernel(const int* __restrict__ count,
                                                    int* __restrict__ rowptr,
                                                    int* __restrict__ next, int n) {
    __shared__ int part[1024];
    int tid = threadIdx.x;
    int chunk = (n + 1023) / 1024;
    int beg = tid * chunk;
    int end = beg + chunk; if (end > n) end = n; if (beg > n) beg = n;
    int s = 0;
    for (int i = beg; i < end; ++i) s += count[i];
    part[tid] = s;
    __syncthreads();
    for (int off = 1; off < 1024; off <<= 1) {
        int v = (tid >= off) ? part[tid - off] : 0;
        __syncthreads();
        part[tid] += v;
        __syncthreads();
    }
    int run = (tid == 0) ? 0 : part[tid - 1];
    for (int i = beg; i < end; ++i) {
        rowptr[i] = run;
        next[i] = run;
        run += count[i];
    }
    if (tid == 0) rowptr[n] = part[1023];
}

// ---- CSR scatter
__global__ __launch_bounds__(256) void scatter_kernel(const int* __restrict__ src,
                                                      const int* __restrict__ dst,
                                                      int Ereal, int nedges,
                                                      int* __restrict__ next,
                                                      int* __restrict__ csr_src) {
    int i = blockIdx.x * blockDim.x + threadIdx.x;
    if (i >= nedges) return;
    int s, d;
    if (i < Ereal) { s = src[i]; d = dst[i]; }
    else           { s = d = i - Ereal; }
    int pos = atomicAdd(&next[d], 1);
    csr_src[pos] = s;
}

// ---- fused GATv2 node pass: one wave64 per node, online softmax
__global__ __launch_bounds__(256) void gat_node(const float* __restrict__ xl,
                                                const float* __restrict__ xr,
                                                const int* __restrict__ rowptr,
                                                const int* __restrict__ csr_src,
                                                const float* __restrict__ att,
                                                const float* __restrict__ bias,
                                                float* __restrict__ y, int n) {
    int wid = (int)((blockIdx.x * (size_t)blockDim.x + threadIdx.x) >> 6);
    int lane = threadIdx.x & 63;
    if (wid >= n) return;
    int beg = rowptr[wid], end = rowptr[wid + 1];
    float4 xrv = ((const float4*)(xr + (size_t)wid * 256))[lane];
    float4 t = ((const float4*)att)[lane];
    float m = -INFINITY, ssum = 0.f;
    float4 acc = make_float4(0.f, 0.f, 0.f, 0.f);
    for (int j = beg; j < end; ++j) {
        int s = csr_src[j];
        float4 a = ((const float4*)(xl + (size_t)s * 256))[lane];
        float v0 = a.x + xrv.x; v0 = v0 > 0.f ? v0 : NEG * v0;
        float v1 = a.y + xrv.y; v1 = v1 > 0.f ? v1 : NEG * v1;
        float v2 = a.z + xrv.z; v2 = v2 > 0.f ? v2 : NEG * v2;
        float v3 = a.w + xrv.w; v3 = v3 > 0.f ? v3 : NEG * v3;
        float dot = v0 * t.x + v1 * t.y + v2 * t.z + v3 * t.w;
#pragma unroll
        for (int off = 32; off > 0; off >>= 1) dot += __shfl_xor(dot, off);
        float newm = fmaxf(m, dot);
        float scale = expf(m - newm);
        float p = expf(dot - newm);
        ssum = ssum * scale + p;
        acc.x = acc.x * scale + p * a.x;
        acc.y = acc.y * scale + p * a.y;
        acc.z = acc.z * scale + p * a.z;
        acc.w = acc.w * scale + p * a.w;
        m = newm;
    }
    float inv = 1.f / ssum;
    float4 bb = ((const float4*)bias)[lane];
    float4 o;
    o.x = acc.x * inv + bb.x; o.x = o.x > 0.f ? o.x : NEG * o.x;
    o.y = acc.y * inv + bb.y; o.y = o.y > 0.f ? o.y : NEG * o.y;
    o.z = acc.z * inv + bb.z; o.z = o.z > 0.f ? o.z : NEG * o.z;
    o.w = acc.w * inv + bb.w; o.w = o.w > 0.f ? o.w : NEG * o.w;
    ((float4*)(y + (size_t)wid * 256))[lane] = o;
}

// ---- head: z = y @ Wlin + blin; out = log_softmax(z)
__global__ __launch_bounds__(256) void head_kernel(const float* __restrict__ y,
                                                   const float* __restrict__ Wlin,
                                                   const float* __restrict__ blin,
                                                   float* __restrict__ out, int n) {
    int wid = (int)((blockIdx.x * (size_t)blockDim.x + threadIdx.x) >> 6);
    int lane = threadIdx.x & 63;
    if (wid >= n) return;
    float4 a = ((const float4*)(y + (size_t)wid * 256))[lane];
    float4 w01 = ((const float4*)Wlin)[lane * 2];
    float4 w23 = ((const float4*)Wlin)[lane * 2 + 1];
    float z0 = a.x * w01.x + a.y * w01.z + a.z * w23.x + a.w * w23.z;
    float z1 = a.x * w01.y + a.y * w01.w + a.z * w23.y + a.w * w23.w;
#pragma unroll
    for (int off = 32; off > 0; off >>= 1) {
        z0 += __shfl_down(z0, off);
        z1 += __shfl_down(z1, off);
    }
    if (lane == 0) {
        z0 += blin[0];
        z1 += blin[1];
        float mx = fmaxf(z0, z1);
        float lse = mx + logf(expf(z0 - mx) + expf(z1 - mx));
        out[(size_t)wid * 2 + 0] = z0 - lse;
        out[(size_t)wid * 2 + 1] = z1 - lse;
    }
}

extern "C" void kernel_launch(void* const* d_in, const int* in_sizes, int n_in,
                              void* d_out, int out_size, void* d_ws, size_t ws_size,
                              hipStream_t stream) {
    const float* fts   = (const float*)d_in[0];
    const int*   graph = (const int*)d_in[1];
    const float* Wl0 = (const float*)d_in[2];
    const float* Wr0 = (const float*)d_in[3];
    const float* bl0 = (const float*)d_in[4];
    const float* br0 = (const float*)d_in[5];
    const float* att0 = (const float*)d_in[6];
    const float* b0  = (const float*)d_in[7];
    const float* Wl1 = (const float*)d_in[8];
    const float* Wr1 = (const float*)d_in[9];
    const float* bl1 = (const float*)d_in[10];
    const float* br1 = (const float*)d_in[11];
    const float* att1 = (const float*)d_in[12];
    const float* b1  = (const float*)d_in[13];
    const float* Wlin = (const float*)d_in[14];
    const float* blin = (const float*)d_in[15];

    int N = out_size / 2;                                   // 40000
    long T = in_sizes[0] / ((long)N * 256);                 // 4
    long E = in_sizes[1] / (2 * T);                         // 640000
    int EP = (int)E + N;

    char* ws = (char*)d_ws;
    size_t off = 0;
    auto alloc = [&](size_t bytes) -> void* {
        void* p = ws + off;
        off += (bytes + 255) & ~(size_t)255;
        return p;
    };
    float* A  = (float*)alloc((size_t)N * 256 * 4);         // xl
    float* B  = (float*)alloc((size_t)N * 256 * 4);         // xr
    float* C  = (float*)alloc((size_t)N * 256 * 4);         // x in / y out
    unsigned short* Xhi  = (unsigned short*)alloc((size_t)N * 256 * 2);
    unsigned short* Xlo  = (unsigned short*)alloc((size_t)N * 256 * 2);
    unsigned short* Wthi = (unsigned short*)alloc((size_t)512 * 256 * 2);
    unsigned short* Wtlo = (unsigned short*)alloc((size_t)512 * 256 * 2);
    int*   count   = (int*)alloc((size_t)N * 4);
    int*   rowptr  = (int*)alloc((size_t)(N + 1) * 4);
    int*   next    = (int*)alloc((size_t)N * 4);
    int*   csr_src = (int*)alloc((size_t)EP * 4);
    (void)ws_size; (void)n_in;

    int conv_blocks = (N * 256 / 4 + 255) / 256;
    dim3 gemm_grid((N + 127) / 128, 4);
    int edge_blocks = (EP + 255) / 256;
    int node_blocks = (N + 3) / 4;

    // ---------- layer 0 ----------
    const int* src0 = graph;
    const int* dst0 = graph + E;
    convert_x<<<conv_blocks, 256, 0, stream>>>(fts, Xhi, Xlo, N * 256 / 4);
    convert_w<<<512, 256, 0, stream>>>(Wl0, Wr0, Wthi, Wtlo);
    mfma_gemm<<<gemm_grid, 256, 0, stream>>>(Xhi, Xlo, Wthi, Wtlo, bl0, br0, A, B, N);
    hipMemsetAsync(count, 0, (size_t)N * 4, stream);
    hist_kernel<<<edge_blocks, 256, 0, stream>>>(dst0, (int)E, EP, count);
    scan_kernel<<<1, 1024, 0, stream>>>(count, rowptr, next, N);
    scatter_kernel<<<edge_blocks, 256, 0, stream>>>(src0, dst0, (int)E, EP, next, csr_src);
    gat_node<<<node_blocks, 256, 0, stream>>>(A, B, rowptr, csr_src, att0, b0, C, N);

    // ---------- layer 1 ----------
    const int* srcL = graph + (T - 1) * 2 * E;
    const int* dstL = graph + (T - 1) * 2 * E + E;
    convert_x<<<conv_blocks, 256, 0, stream>>>(C, Xhi, Xlo, N * 256 / 4);
    convert_w<<<512, 256, 0, stream>>>(Wl1, Wr1, Wthi, Wtlo);
    mfma_gemm<<<gemm_grid, 256, 0, stream>>>(Xhi, Xlo, Wthi, Wtlo, bl1, br1, A, B, N);
    hipMemsetAsync(count, 0, (size_t)N * 4, stream);
    hist_kernel<<<edge_blocks, 256, 0, stream>>>(dstL, (int)E, EP, count);
    scan_kernel<<<1, 1024, 0, stream>>>(count, rowptr, next, N);
    scatter_kernel<<<edge_blocks, 256, 0, stream>>>(srcL, dstL, (int)E, EP, next, csr_src);
    gat_node<<<node_blocks, 256, 0, stream>>>(A, B, rowptr, csr_src, att1, b1, C, N);

    // ---------- head ----------
    head_kernel<<<node_blocks, 256, 0, stream>>>(C, Wlin, blin, (float*)d_out, N);
}

// Round 4
// 682.968 us; speedup vs baseline: 8.0161x; 1.2360x over previous
//
#include <hip/hip_runtime.h>
#include <hip/hip_bf16.h>
#include <math.h>

#define NEG 0.2f

typedef short bf16x8 __attribute__((ext_vector_type(8)));
typedef float f32x4 __attribute__((ext_vector_type(4)));

typedef __attribute__((address_space(3))) void as3_void;
typedef __attribute__((address_space(1))) const void as1_void;

__device__ __forceinline__ void gl_lds16(const void* g, void* l) {
    __builtin_amdgcn_global_load_lds((as1_void*)g, (as3_void*)l, 16, 0, 0);
}

__device__ __forceinline__ unsigned short f2bf(float x) {
    unsigned u = __float_as_uint(x);
    unsigned r = (u + 0x7fffu + ((u >> 16) & 1u)) >> 16;
    return (unsigned short)r;
}
__device__ __forceinline__ float bf2f(unsigned short b) {
    return __uint_as_float(((unsigned)b) << 16);
}

// ---- fp32 -> bf16 hi/lo split, vectorized 4 at a time
__global__ __launch_bounds__(256) void convert_x(const float* __restrict__ X,
                                                 unsigned short* __restrict__ hi,
                                                 unsigned short* __restrict__ lo,
                                                 int total4) {
    int i = blockIdx.x * blockDim.x + threadIdx.x;
    if (i >= total4) return;
    float4 v = ((const float4*)X)[i];
    ushort4 h, l;
    h.x = f2bf(v.x); l.x = f2bf(v.x - bf2f(h.x));
    h.y = f2bf(v.y); l.y = f2bf(v.y - bf2f(h.y));
    h.z = f2bf(v.z); l.z = f2bf(v.z - bf2f(h.z));
    h.w = f2bf(v.w); l.w = f2bf(v.w - bf2f(h.w));
    ((ushort4*)hi)[i] = h;
    ((ushort4*)lo)[i] = l;
}

// ---- build transposed combined weight Wt[n][k] (n<256: Wl col n, else Wr col n-256)
__global__ __launch_bounds__(256) void convert_w(const float* __restrict__ Wl,
                                                 const float* __restrict__ Wr,
                                                 unsigned short* __restrict__ Wthi,
                                                 unsigned short* __restrict__ Wtlo) {
    int idx = blockIdx.x * blockDim.x + threadIdx.x;   // n*256 + k
    int n = idx >> 8, k = idx & 255;
    float v = (n < 256) ? Wl[k * 256 + n] : Wr[k * 256 + (n - 256)];
    unsigned short h = f2bf(v);
    Wthi[idx] = h;
    Wtlo[idx] = f2bf(v - bf2f(h));
}

// ---- stage one 128-row x 32-k tile (hi|lo packed as [128][64] bf16, 16KB) into LDS
//      linear dest, source pre-swizzled: linear slot s holds global chunk s^(row&7)
__device__ __forceinline__ void stage32(const unsigned short* __restrict__ hi,
                                        const unsigned short* __restrict__ lo,
                                        int row_base, int row_max, int k0,
                                        char* lds, int wave, int lane) {
#pragma unroll
    for (int q = 0; q < 4; ++q) {
        int off = q * 4096 + wave * 1024 + lane * 16;  // linear byte offset incl. lane
        int row = off >> 7;                            // 128 B per row
        int slot = (off >> 4) & 7;                     // 16B slot within row
        int se = slot ^ (row & 7);                     // swizzled global chunk
        int grow = row_base + row;
        if (grow > row_max) grow = row_max;
        const unsigned short* g = (se < 4)
            ? hi + (size_t)grow * 256 + k0 + se * 8
            : lo + (size_t)grow * 256 + k0 + (se - 4) * 8;
        gl_lds16(g, lds + q * 4096 + wave * 1024);     // wave-uniform LDS base
    }
}

// ---- split-bf16 MFMA GEMM: [M,256] x [256,512] -> A (cols 0-255,+bl), B (cols 256-511,+br)
//      128x128 tile, 4 waves (2x2 of 64x64), BK=32, double-buffered LDS
__global__ __launch_bounds__(256) void mfma_gemm(const unsigned short* __restrict__ Xhi,
                                                 const unsigned short* __restrict__ Xlo,
                                                 const unsigned short* __restrict__ Wthi,
                                                 const unsigned short* __restrict__ Wtlo,
                                                 const float* __restrict__ bl,
                                                 const float* __restrict__ br,
                                                 float* __restrict__ A,
                                                 float* __restrict__ B, int M) {
    __shared__ char smem[65536];                      // 2 bufs x (A 16K + B 16K)
    int tid = threadIdx.x;
    int wave = tid >> 6, lane = tid & 63;
    int bid = blockIdx.x;
    int m_blk = bid >> 2, n_blk = bid & 3;            // 4 consecutive bids share X rows
    int m0 = m_blk * 128;
    int wr = wave >> 1, wc = wave & 1;
    int r15 = lane & 15, c = lane >> 4;

    f32x4 acc[4][4];
#pragma unroll
    for (int mf = 0; mf < 4; ++mf)
#pragma unroll
        for (int nf = 0; nf < 4; ++nf) acc[mf][nf] = (f32x4){0.f, 0.f, 0.f, 0.f};

    stage32(Xhi, Xlo, m0, M - 1, 0, smem, wave, lane);
    stage32(Wthi, Wtlo, n_blk * 128, 511, 0, smem + 16384, wave, lane);
    __syncthreads();

    for (int t = 0; t < 8; ++t) {
        int buf = t & 1;
        if (t < 7) {
            char* nb = smem + (buf ^ 1) * 32768;
            stage32(Xhi, Xlo, m0, M - 1, (t + 1) * 32, nb, wave, lane);
            stage32(Wthi, Wtlo, n_blk * 128, 511, (t + 1) * 32, nb + 16384, wave, lane);
        }
        const char* At = smem + buf * 32768;
        const char* Bt = At + 16384;
        bf16x8 ah[4], al[4], bh[4], bo[4];
#pragma unroll
        for (int f = 0; f < 4; ++f) {
            int ar = wr * 64 + f * 16 + r15;
            ah[f] = *(const bf16x8*)(At + ar * 128 + ((c ^ (ar & 7)) << 4));
            al[f] = *(const bf16x8*)(At + ar * 128 + (((4 + c) ^ (ar & 7)) << 4));
            int br_ = wc * 64 + f * 16 + r15;
            bh[f] = *(const bf16x8*)(Bt + br_ * 128 + ((c ^ (br_ & 7)) << 4));
            bo[f] = *(const bf16x8*)(Bt + br_ * 128 + (((4 + c) ^ (br_ & 7)) << 4));
        }
#pragma unroll
        for (int mf = 0; mf < 4; ++mf)
#pragma unroll
            for (int nf = 0; nf < 4; ++nf) {
                acc[mf][nf] = __builtin_amdgcn_mfma_f32_16x16x32_bf16(ah[mf], bh[nf], acc[mf][nf], 0, 0, 0);
                acc[mf][nf] = __builtin_amdgcn_mfma_f32_16x16x32_bf16(al[mf], bh[nf], acc[mf][nf], 0, 0, 0);
                acc[mf][nf] = __builtin_amdgcn_mfma_f32_16x16x32_bf16(ah[mf], bo[nf], acc[mf][nf], 0, 0, 0);
            }
        __syncthreads();
    }

    int q4 = (lane >> 4) * 4;
#pragma unroll
    for (int nf = 0; nf < 4; ++nf) {
        int n_abs = n_blk * 128 + wc * 64 + nf * 16 + r15;
        bool left = n_abs < 256;
        float bb = left ? bl[n_abs] : br[n_abs - 256];
        float* Y = left ? A : B;
        int col = n_abs & 255;
#pragma unroll
        for (int mf = 0; mf < 4; ++mf) {
            int rowb = m0 + wr * 64 + mf * 16 + q4;
#pragma unroll
            for (int j = 0; j < 4; ++j) {
                int row = rowb + j;
                if (row < M) Y[(size_t)row * 256 + col] = acc[mf][nf][j] + bb;
            }
        }
    }
}

// ---- CSR build: histogram of dst (incl. self loops)
__global__ __launch_bounds__(256) void hist_kernel(const int* __restrict__ dst,
                                                   int Ereal, int nedges,
                                                   int* __restrict__ count) {
    int i = blockIdx.x * blockDim.x + threadIdx.x;
    if (i >= nedges) return;
    int d = (i < Ereal) ? dst[i] : (i - Ereal);
    atomicAdd(&count[d], 1);
}

// ---- single-block exclusive scan
__global__ __launch_bounds__(1024) void scan_kernel(const int* __restrict__ count,
                                                    int* __restrict__ rowptr,
                                                    int* __restrict__ next, int n) {
    __shared__ int part[1024];
    int tid = threadIdx.x;
    int chunk = (n + 1023) / 1024;
    int beg = tid * chunk;
    int end = beg + chunk; if (end > n) end = n; if (beg > n) beg = n;
    int s = 0;
    for (int i = beg; i < end; ++i) s += count[i];
    part[tid] = s;
    __syncthreads();
    for (int off = 1; off < 1024; off <<= 1) {
        int v = (tid >= off) ? part[tid - off] : 0;
        __syncthreads();
        part[tid] += v;
        __syncthreads();
    }
    int run = (tid == 0) ? 0 : part[tid - 1];
    for (int i = beg; i < end; ++i) {
        rowptr[i] = run;
        next[i] = run;
        run += count[i];
    }
    if (tid == 0) rowptr[n] = part[1023];
}

// ---- CSR scatter
__global__ __launch_bounds__(256) void scatter_kernel(const int* __restrict__ src,
                                                      const int* __restrict__ dst,
                                                      int Ereal, int nedges,
                                                      int* __restrict__ next,
                                                      int* __restrict__ csr_src) {
    int i = blockIdx.x * blockDim.x + threadIdx.x;
    if (i >= nedges) return;
    int s, d;
    if (i < Ereal) { s = src[i]; d = dst[i]; }
    else           { s = d = i - Ereal; }
    int pos = atomicAdd(&next[d], 1);
    csr_src[pos] = s;
}

// ---- fused GATv2 node pass: one wave64 per node, online softmax.
//      MODE 0: write bf16 hi/lo split (feeds next layer's MFMA GEMM)
//      MODE 1: fuse 256->2 head + log_softmax, write d_out
template <int MODE>
__global__ __launch_bounds__(256) void gat_node(const float* __restrict__ xl,
                                                const float* __restrict__ xr,
                                                const int* __restrict__ rowptr,
                                                const int* __restrict__ csr_src,
                                                const float* __restrict__ att,
                                                const float* __restrict__ bias,
                                                unsigned short* __restrict__ yhi,
                                                unsigned short* __restrict__ ylo,
                                                const float* __restrict__ Wlin,
                                                const float* __restrict__ blin,
                                                float* __restrict__ out, int n) {
    int wid = (int)((blockIdx.x * (size_t)blockDim.x + threadIdx.x) >> 6);
    int lane = threadIdx.x & 63;
    if (wid >= n) return;
    int beg = rowptr[wid], end = rowptr[wid + 1];
    float4 xrv = ((const float4*)(xr + (size_t)wid * 256))[lane];
    float4 t = ((const float4*)att)[lane];
    float m = -INFINITY, ssum = 0.f;
    float4 acc = make_float4(0.f, 0.f, 0.f, 0.f);
    for (int j = beg; j < end; ++j) {
        int s = csr_src[j];
        float4 a = ((const float4*)(xl + (size_t)s * 256))[lane];
        float v0 = a.x + xrv.x; v0 = v0 > 0.f ? v0 : NEG * v0;
        float v1 = a.y + xrv.y; v1 = v1 > 0.f ? v1 : NEG * v1;
        float v2 = a.z + xrv.z; v2 = v2 > 0.f ? v2 : NEG * v2;
        float v3 = a.w + xrv.w; v3 = v3 > 0.f ? v3 : NEG * v3;
        float dot = v0 * t.x + v1 * t.y + v2 * t.z + v3 * t.w;
#pragma unroll
        for (int off = 32; off > 0; off >>= 1) dot += __shfl_xor(dot, off);
        float newm = fmaxf(m, dot);
        float scale = expf(m - newm);
        float p = expf(dot - newm);
        ssum = ssum * scale + p;
        acc.x = acc.x * scale + p * a.x;
        acc.y = acc.y * scale + p * a.y;
        acc.z = acc.z * scale + p * a.z;
        acc.w = acc.w * scale + p * a.w;
        m = newm;
    }
    float inv = 1.f / ssum;
    float4 bb = ((const float4*)bias)[lane];
    float4 o;
    o.x = acc.x * inv + bb.x; o.x = o.x > 0.f ? o.x : NEG * o.x;
    o.y = acc.y * inv + bb.y; o.y = o.y > 0.f ? o.y : NEG * o.y;
    o.z = acc.z * inv + bb.z; o.z = o.z > 0.f ? o.z : NEG * o.z;
    o.w = acc.w * inv + bb.w; o.w = o.w > 0.f ? o.w : NEG * o.w;

    if (MODE == 0) {
        ushort4 h, l;
        h.x = f2bf(o.x); l.x = f2bf(o.x - bf2f(h.x));
        h.y = f2bf(o.y); l.y = f2bf(o.y - bf2f(h.y));
        h.z = f2bf(o.z); l.z = f2bf(o.z - bf2f(h.z));
        h.w = f2bf(o.w); l.w = f2bf(o.w - bf2f(h.w));
        ((ushort4*)(yhi + (size_t)wid * 256))[lane] = h;
        ((ushort4*)(ylo + (size_t)wid * 256))[lane] = l;
    } else {
        float4 w01 = ((const float4*)Wlin)[lane * 2];
        float4 w23 = ((const float4*)Wlin)[lane * 2 + 1];
        float z0 = o.x * w01.x + o.y * w01.z + o.z * w23.x + o.w * w23.z;
        float z1 = o.x * w01.y + o.y * w01.w + o.z * w23.y + o.w * w23.w;
#pragma unroll
        for (int off = 32; off > 0; off >>= 1) {
            z0 += __shfl_down(z0, off);
            z1 += __shfl_down(z1, off);
        }
        if (lane == 0) {
            z0 += blin[0];
            z1 += blin[1];
            float mx = fmaxf(z0, z1);
            float lse = mx + logf(expf(z0 - mx) + expf(z1 - mx));
            out[(size_t)wid * 2 + 0] = z0 - lse;
            out[(size_t)wid * 2 + 1] = z1 - lse;
        }
    }
}

extern "C" void kernel_launch(void* const* d_in, const int* in_sizes, int n_in,
                              void* d_out, int out_size, void* d_ws, size_t ws_size,
                              hipStream_t stream) {
    const float* fts   = (const float*)d_in[0];
    const int*   graph = (const int*)d_in[1];
    const float* Wl0 = (const float*)d_in[2];
    const float* Wr0 = (const float*)d_in[3];
    const float* bl0 = (const float*)d_in[4];
    const float* br0 = (const float*)d_in[5];
    const float* att0 = (const float*)d_in[6];
    const float* b0  = (const float*)d_in[7];
    const float* Wl1 = (const float*)d_in[8];
    const float* Wr1 = (const float*)d_in[9];
    const float* bl1 = (const float*)d_in[10];
    const float* br1 = (const float*)d_in[11];
    const float* att1 = (const float*)d_in[12];
    const float* b1  = (const float*)d_in[13];
    const float* Wlin = (const float*)d_in[14];
    const float* blin = (const float*)d_in[15];

    int N = out_size / 2;                                   // 40000
    long T = in_sizes[0] / ((long)N * 256);                 // 4
    long E = in_sizes[1] / (2 * T);                         // 640000
    int EP = (int)E + N;

    char* ws = (char*)d_ws;
    size_t off = 0;
    auto alloc = [&](size_t bytes) -> void* {
        void* p = ws + off;
        off += (bytes + 255) & ~(size_t)255;
        return p;
    };
    float* A  = (float*)alloc((size_t)N * 256 * 4);         // xl
    float* B  = (float*)alloc((size_t)N * 256 * 4);         // xr
    unsigned short* Xhi  = (unsigned short*)alloc((size_t)N * 256 * 2);
    unsigned short* Xlo  = (unsigned short*)alloc((size_t)N * 256 * 2);
    unsigned short* Wthi = (unsigned short*)alloc((size_t)512 * 256 * 2);
    unsigned short* Wtlo = (unsigned short*)alloc((size_t)512 * 256 * 2);
    int*   count   = (int*)alloc((size_t)N * 4);
    int*   rowptr  = (int*)alloc((size_t)(N + 1) * 4);
    int*   next    = (int*)alloc((size_t)N * 4);
    int*   csr_src = (int*)alloc((size_t)EP * 4);
    (void)ws_size; (void)n_in;

    int conv_blocks = (N * 256 / 4 + 255) / 256;
    int gemm_blocks = ((N + 127) / 128) * 4;
    int edge_blocks = (EP + 255) / 256;
    int node_blocks = (N + 3) / 4;

    // ---------- layer 0 ----------
    const int* src0 = graph;
    const int* dst0 = graph + E;
    convert_x<<<conv_blocks, 256, 0, stream>>>(fts, Xhi, Xlo, N * 256 / 4);
    convert_w<<<512, 256, 0, stream>>>(Wl0, Wr0, Wthi, Wtlo);
    mfma_gemm<<<gemm_blocks, 256, 0, stream>>>(Xhi, Xlo, Wthi, Wtlo, bl0, br0, A, B, N);
    hipMemsetAsync(count, 0, (size_t)N * 4, stream);
    hist_kernel<<<edge_blocks, 256, 0, stream>>>(dst0, (int)E, EP, count);
    scan_kernel<<<1, 1024, 0, stream>>>(count, rowptr, next, N);
    scatter_kernel<<<edge_blocks, 256, 0, stream>>>(src0, dst0, (int)E, EP, next, csr_src);
    gat_node<0><<<node_blocks, 256, 0, stream>>>(A, B, rowptr, csr_src, att0, b0,
                                                 Xhi, Xlo, nullptr, nullptr, nullptr, N);

    // ---------- layer 1 ----------
    const int* srcL = graph + (T - 1) * 2 * E;
    const int* dstL = graph + (T - 1) * 2 * E + E;
    convert_w<<<512, 256, 0, stream>>>(Wl1, Wr1, Wthi, Wtlo);
    mfma_gemm<<<gemm_blocks, 256, 0, stream>>>(Xhi, Xlo, Wthi, Wtlo, bl1, br1, A, B, N);
    hipMemsetAsync(count, 0, (size_t)N * 4, stream);
    hist_kernel<<<edge_blocks, 256, 0, stream>>>(dstL, (int)E, EP, count);
    scan_kernel<<<1, 1024, 0, stream>>>(count, rowptr, next, N);
    scatter_kernel<<<edge_blocks, 256, 0, stream>>>(srcL, dstL, (int)E, EP, next, csr_src);
    gat_node<1><<<node_blocks, 256, 0, stream>>>(A, B, rowptr, csr_src, att1, b1,
                                                 nullptr, nullptr, Wlin, blin, (float*)d_out, N);
}

// Round 5
// 638.821 us; speedup vs baseline: 8.5701x; 1.0691x over previous
//
#include <hip/hip_runtime.h>
#include <hip/hip_bf16.h>
#include <math.h>

#define NEG 0.2f

typedef short bf16x8 __attribute__((ext_vector_type(8)));
typedef float f32x4 __attribute__((ext_vector_type(4)));
typedef _Float16 f16;
typedef _Float16 f16x2 __attribute__((ext_vector_type(2)));
typedef _Float16 f16x4 __attribute__((ext_vector_type(4)));

#if defined(__has_builtin)
#if __has_builtin(__builtin_amdgcn_fdot2)
#define HAVE_FDOT2 1
#endif
#endif

typedef __attribute__((address_space(3))) void as3_void;
typedef __attribute__((address_space(1))) const void as1_void;

__device__ __forceinline__ void gl_lds16(const void* g, void* l) {
    __builtin_amdgcn_global_load_lds((as1_void*)g, (as3_void*)l, 16, 0, 0);
}

__device__ __forceinline__ unsigned short f2bf(float x) {
    unsigned u = __float_as_uint(x);
    unsigned r = (u + 0x7fffu + ((u >> 16) & 1u)) >> 16;
    return (unsigned short)r;
}
__device__ __forceinline__ float bf2f(unsigned short b) {
    return __uint_as_float(((unsigned)b) << 16);
}

// ---- fp32 -> bf16 hi/lo split, vectorized 4 at a time
__global__ __launch_bounds__(256) void convert_x(const float* __restrict__ X,
                                                 unsigned short* __restrict__ hi,
                                                 unsigned short* __restrict__ lo,
                                                 int total4) {
    int i = blockIdx.x * blockDim.x + threadIdx.x;
    if (i >= total4) return;
    float4 v = ((const float4*)X)[i];
    ushort4 h, l;
    h.x = f2bf(v.x); l.x = f2bf(v.x - bf2f(h.x));
    h.y = f2bf(v.y); l.y = f2bf(v.y - bf2f(h.y));
    h.z = f2bf(v.z); l.z = f2bf(v.z - bf2f(h.z));
    h.w = f2bf(v.w); l.w = f2bf(v.w - bf2f(h.w));
    ((ushort4*)hi)[i] = h;
    ((ushort4*)lo)[i] = l;
}

// ---- build transposed combined weight Wt[n][k] (n<256: Wl col n, else Wr col n-256)
__global__ __launch_bounds__(256) void convert_w(const float* __restrict__ Wl,
                                                 const float* __restrict__ Wr,
                                                 unsigned short* __restrict__ Wthi,
                                                 unsigned short* __restrict__ Wtlo) {
    int idx = blockIdx.x * blockDim.x + threadIdx.x;   // n*256 + k
    int n = idx >> 8, k = idx & 255;
    float v = (n < 256) ? Wl[k * 256 + n] : Wr[k * 256 + (n - 256)];
    unsigned short h = f2bf(v);
    Wthi[idx] = h;
    Wtlo[idx] = f2bf(v - bf2f(h));
}

// ---- stage one 128-row x 32-k tile (hi|lo packed as [128][64] bf16, 16KB) into LDS
__device__ __forceinline__ void stage32(const unsigned short* __restrict__ hi,
                                        const unsigned short* __restrict__ lo,
                                        int row_base, int row_max, int k0,
                                        char* lds, int wave, int lane) {
#pragma unroll
    for (int q = 0; q < 4; ++q) {
        int off = q * 4096 + wave * 1024 + lane * 16;  // linear byte offset incl. lane
        int row = off >> 7;                            // 128 B per row
        int slot = (off >> 4) & 7;                     // 16B slot within row
        int se = slot ^ (row & 7);                     // swizzled global chunk
        int grow = row_base + row;
        if (grow > row_max) grow = row_max;
        const unsigned short* g = (se < 4)
            ? hi + (size_t)grow * 256 + k0 + se * 8
            : lo + (size_t)grow * 256 + k0 + (se - 4) * 8;
        gl_lds16(g, lds + q * 4096 + wave * 1024);     // wave-uniform LDS base
    }
}

// ---- split-bf16 MFMA GEMM: [M,256] x [256,512] -> Af f16 (cols 0-255,+bl), B f32 (cols 256-511,+br)
__global__ __launch_bounds__(256) void mfma_gemm(const unsigned short* __restrict__ Xhi,
                                                 const unsigned short* __restrict__ Xlo,
                                                 const unsigned short* __restrict__ Wthi,
                                                 const unsigned short* __restrict__ Wtlo,
                                                 const float* __restrict__ bl,
                                                 const float* __restrict__ br,
                                                 _Float16* __restrict__ Af,
                                                 float* __restrict__ B, int M) {
    __shared__ char smem[65536];                      // 2 bufs x (A 16K + B 16K)
    int tid = threadIdx.x;
    int wave = tid >> 6, lane = tid & 63;
    int bid = blockIdx.x;
    int m_blk = bid >> 2, n_blk = bid & 3;
    int m0 = m_blk * 128;
    int wr = wave >> 1, wc = wave & 1;
    int r15 = lane & 15, c = lane >> 4;

    f32x4 acc[4][4];
#pragma unroll
    for (int mf = 0; mf < 4; ++mf)
#pragma unroll
        for (int nf = 0; nf < 4; ++nf) acc[mf][nf] = (f32x4){0.f, 0.f, 0.f, 0.f};

    stage32(Xhi, Xlo, m0, M - 1, 0, smem, wave, lane);
    stage32(Wthi, Wtlo, n_blk * 128, 511, 0, smem + 16384, wave, lane);
    __syncthreads();

    for (int t = 0; t < 8; ++t) {
        int buf = t & 1;
        if (t < 7) {
            char* nb = smem + (buf ^ 1) * 32768;
            stage32(Xhi, Xlo, m0, M - 1, (t + 1) * 32, nb, wave, lane);
            stage32(Wthi, Wtlo, n_blk * 128, 511, (t + 1) * 32, nb + 16384, wave, lane);
        }
        const char* At = smem + buf * 32768;
        const char* Bt = At + 16384;
        bf16x8 ah[4], al[4], bh[4], bo[4];
#pragma unroll
        for (int f = 0; f < 4; ++f) {
            int ar = wr * 64 + f * 16 + r15;
            ah[f] = *(const bf16x8*)(At + ar * 128 + ((c ^ (ar & 7)) << 4));
            al[f] = *(const bf16x8*)(At + ar * 128 + (((4 + c) ^ (ar & 7)) << 4));
            int br_ = wc * 64 + f * 16 + r15;
            bh[f] = *(const bf16x8*)(Bt + br_ * 128 + ((c ^ (br_ & 7)) << 4));
            bo[f] = *(const bf16x8*)(Bt + br_ * 128 + (((4 + c) ^ (br_ & 7)) << 4));
        }
#pragma unroll
        for (int mf = 0; mf < 4; ++mf)
#pragma unroll
            for (int nf = 0; nf < 4; ++nf) {
                acc[mf][nf] = __builtin_amdgcn_mfma_f32_16x16x32_bf16(ah[mf], bh[nf], acc[mf][nf], 0, 0, 0);
                acc[mf][nf] = __builtin_amdgcn_mfma_f32_16x16x32_bf16(al[mf], bh[nf], acc[mf][nf], 0, 0, 0);
                acc[mf][nf] = __builtin_amdgcn_mfma_f32_16x16x32_bf16(ah[mf], bo[nf], acc[mf][nf], 0, 0, 0);
            }
        __syncthreads();
    }

    int q4 = (lane >> 4) * 4;
#pragma unroll
    for (int nf = 0; nf < 4; ++nf) {
        int n_abs = n_blk * 128 + wc * 64 + nf * 16 + r15;
        bool left = n_abs < 256;
        float bb = left ? bl[n_abs] : br[n_abs - 256];
        int col = n_abs & 255;
#pragma unroll
        for (int mf = 0; mf < 4; ++mf) {
            int rowb = m0 + wr * 64 + mf * 16 + q4;
#pragma unroll
            for (int j = 0; j < 4; ++j) {
                int row = rowb + j;
                if (row < M) {
                    float v = acc[mf][nf][j] + bb;
                    if (left) Af[(size_t)row * 256 + col] = (_Float16)v;
                    else      B[(size_t)row * 256 + col] = v;
                }
            }
        }
    }
}

// ---- CSR build: histogram of dst (incl. self loops)
__global__ __launch_bounds__(256) void hist_kernel(const int* __restrict__ dst,
                                                   int Ereal, int nedges,
                                                   int* __restrict__ count) {
    int i = blockIdx.x * blockDim.x + threadIdx.x;
    if (i >= nedges) return;
    int d = (i < Ereal) ? dst[i] : (i - Ereal);
    atomicAdd(&count[d], 1);
}

// ---- single-block exclusive scan
__global__ __launch_bounds__(1024) void scan_kernel(const int* __restrict__ count,
                                                    int* __restrict__ rowptr,
                                                    int* __restrict__ next, int n) {
    __shared__ int part[1024];
    int tid = threadIdx.x;
    int chunk = (n + 1023) / 1024;
    int beg = tid * chunk;
    int end = beg + chunk; if (end > n) end = n; if (beg > n) beg = n;
    int s = 0;
    for (int i = beg; i < end; ++i) s += count[i];
    part[tid] = s;
    __syncthreads();
    for (int off = 1; off < 1024; off <<= 1) {
        int v = (tid >= off) ? part[tid - off] : 0;
        __syncthreads();
        part[tid] += v;
        __syncthreads();
    }
    int run = (tid == 0) ? 0 : part[tid - 1];
    for (int i = beg; i < end; ++i) {
        rowptr[i] = run;
        next[i] = run;
        run += count[i];
    }
    if (tid == 0) rowptr[n] = part[1023];
}

// ---- CSR scatter
__global__ __launch_bounds__(256) void scatter_kernel(const int* __restrict__ src,
                                                      const int* __restrict__ dst,
                                                      int Ereal, int nedges,
                                                      int* __restrict__ next,
                                                      int* __restrict__ csr_src) {
    int i = blockIdx.x * blockDim.x + threadIdx.x;
    if (i >= nedges) return;
    int s, d;
    if (i < Ereal) { s = src[i]; d = dst[i]; }
    else           { s = d = i - Ereal; }
    int pos = atomicAdd(&next[d], 1);
    csr_src[pos] = s;
}

// ---- fused GATv2 node pass: one wave64 per node, defer-max online softmax,
//      fp16 xl gather + packed-fp16 math.
//      MODE 0: write bf16 hi/lo split (feeds next layer's MFMA GEMM)
//      MODE 1: fuse 256->2 head + log_softmax, write d_out
template <int MODE>
__global__ __launch_bounds__(256) void gat_node(const _Float16* __restrict__ xl,
                                                const float* __restrict__ xr,
                                                const int* __restrict__ rowptr,
                                                const int* __restrict__ csr_src,
                                                const float* __restrict__ att,
                                                const float* __restrict__ bias,
                                                unsigned short* __restrict__ yhi,
                                                unsigned short* __restrict__ ylo,
                                                const float* __restrict__ Wlin,
                                                const float* __restrict__ blin,
                                                float* __restrict__ out, int n) {
    int wid = (int)((blockIdx.x * (size_t)blockDim.x + threadIdx.x) >> 6);
    int lane = threadIdx.x & 63;
    if (wid >= n) return;
    int beg = rowptr[wid], end = rowptr[wid + 1];
    float4 xrv = ((const float4*)(xr + (size_t)wid * 256))[lane];
    f16x2 xr01 = {(f16)xrv.x, (f16)xrv.y};
    f16x2 xr23 = {(f16)xrv.z, (f16)xrv.w};
    float4 t = ((const float4*)att)[lane];
    f16x2 t01 = {(f16)t.x, (f16)t.y};
    f16x2 t23 = {(f16)t.z, (f16)t.w};
    const f16x2 n2 = {(f16)NEG, (f16)NEG};

    float m = -INFINITY, ssum = 0.f;
    float4 acc = make_float4(0.f, 0.f, 0.f, 0.f);

    auto step = [&](f16x4 a) {
        f16x2 a01 = {a.x, a.y}, a23 = {a.z, a.w};
        f16x2 v01 = a01 + xr01, v23 = a23 + xr23;
        f16x2 l01 = __builtin_elementwise_max(v01, v01 * n2);
        f16x2 l23 = __builtin_elementwise_max(v23, v23 * n2);
#ifdef HAVE_FDOT2
        float dot = __builtin_amdgcn_fdot2(l01, t01, 0.f, false);
        dot = __builtin_amdgcn_fdot2(l23, t23, dot, false);
#else
        float dot = (float)l01.x * (float)t01.x + (float)l01.y * (float)t01.y +
                    (float)l23.x * (float)t23.x + (float)l23.y * (float)t23.y;
#endif
#pragma unroll
        for (int off = 32; off > 0; off >>= 1) dot += __shfl_xor(dot, off);
        if (dot > m + 8.f) {            // wave-uniform; rare after warm-up
            float sc = __expf(m - dot); // -inf -> 0 on first edge
            ssum = ssum * sc + 1.f;
            acc.x = acc.x * sc + (float)a.x;
            acc.y = acc.y * sc + (float)a.y;
            acc.z = acc.z * sc + (float)a.z;
            acc.w = acc.w * sc + (float)a.w;
            m = dot;
        } else {                        // p bounded by e^8
            float p = __expf(dot - m);
            ssum += p;
            acc.x += p * (float)a.x;
            acc.y += p * (float)a.y;
            acc.z += p * (float)a.z;
            acc.w += p * (float)a.w;
        }
    };

    for (int j = beg; j < end; j += 2) {
        bool two = (j + 1 < end);       // wave-uniform
        int s0 = csr_src[j];
        f16x4 a0 = ((const f16x4*)(xl + (size_t)s0 * 256))[lane];
        f16x4 a1;
        if (two) {
            int s1 = csr_src[j + 1];
            a1 = ((const f16x4*)(xl + (size_t)s1 * 256))[lane];
        }
        step(a0);
        if (two) step(a1);
    }

    float inv = 1.f / ssum;
    float4 bb = ((const float4*)bias)[lane];
    float4 o;
    o.x = acc.x * inv + bb.x; o.x = o.x > 0.f ? o.x : NEG * o.x;
    o.y = acc.y * inv + bb.y; o.y = o.y > 0.f ? o.y : NEG * o.y;
    o.z = acc.z * inv + bb.z; o.z = o.z > 0.f ? o.z : NEG * o.z;
    o.w = acc.w * inv + bb.w; o.w = o.w > 0.f ? o.w : NEG * o.w;

    if (MODE == 0) {
        ushort4 h, l;
        h.x = f2bf(o.x); l.x = f2bf(o.x - bf2f(h.x));
        h.y = f2bf(o.y); l.y = f2bf(o.y - bf2f(h.y));
        h.z = f2bf(o.z); l.z = f2bf(o.z - bf2f(h.z));
        h.w = f2bf(o.w); l.w = f2bf(o.w - bf2f(h.w));
        ((ushort4*)(yhi + (size_t)wid * 256))[lane] = h;
        ((ushort4*)(ylo + (size_t)wid * 256))[lane] = l;
    } else {
        float4 w01 = ((const float4*)Wlin)[lane * 2];
        float4 w23 = ((const float4*)Wlin)[lane * 2 + 1];
        float z0 = o.x * w01.x + o.y * w01.z + o.z * w23.x + o.w * w23.z;
        float z1 = o.x * w01.y + o.y * w01.w + o.z * w23.y + o.w * w23.w;
#pragma unroll
        for (int off = 32; off > 0; off >>= 1) {
            z0 += __shfl_down(z0, off);
            z1 += __shfl_down(z1, off);
        }
        if (lane == 0) {
            z0 += blin[0];
            z1 += blin[1];
            float mx = fmaxf(z0, z1);
            float lse = mx + logf(expf(z0 - mx) + expf(z1 - mx));
            out[(size_t)wid * 2 + 0] = z0 - lse;
            out[(size_t)wid * 2 + 1] = z1 - lse;
        }
    }
}

extern "C" void kernel_launch(void* const* d_in, const int* in_sizes, int n_in,
                              void* d_out, int out_size, void* d_ws, size_t ws_size,
                              hipStream_t stream) {
    const float* fts   = (const float*)d_in[0];
    const int*   graph = (const int*)d_in[1];
    const float* Wl0 = (const float*)d_in[2];
    const float* Wr0 = (const float*)d_in[3];
    const float* bl0 = (const float*)d_in[4];
    const float* br0 = (const float*)d_in[5];
    const float* att0 = (const float*)d_in[6];
    const float* b0  = (const float*)d_in[7];
    const float* Wl1 = (const float*)d_in[8];
    const float* Wr1 = (const float*)d_in[9];
    const float* bl1 = (const float*)d_in[10];
    const float* br1 = (const float*)d_in[11];
    const float* att1 = (const float*)d_in[12];
    const float* b1  = (const float*)d_in[13];
    const float* Wlin = (const float*)d_in[14];
    const float* blin = (const float*)d_in[15];

    int N = out_size / 2;                                   // 40000
    long T = in_sizes[0] / ((long)N * 256);                 // 4
    long E = in_sizes[1] / (2 * T);                         // 640000
    int EP = (int)E + N;

    char* ws = (char*)d_ws;
    size_t off = 0;
    auto alloc = [&](size_t bytes) -> void* {
        void* p = ws + off;
        off += (bytes + 255) & ~(size_t)255;
        return p;
    };
    _Float16* Af = (_Float16*)alloc((size_t)N * 256 * 2);   // xl (fp16)
    float* B  = (float*)alloc((size_t)N * 256 * 4);         // xr (fp32)
    unsigned short* Xhi  = (unsigned short*)alloc((size_t)N * 256 * 2);
    unsigned short* Xlo  = (unsigned short*)alloc((size_t)N * 256 * 2);
    unsigned short* Wthi = (unsigned short*)alloc((size_t)512 * 256 * 2);
    unsigned short* Wtlo = (unsigned short*)alloc((size_t)512 * 256 * 2);
    int*   count   = (int*)alloc((size_t)N * 4);
    int*   rowptr  = (int*)alloc((size_t)(N + 1) * 4);
    int*   next    = (int*)alloc((size_t)N * 4);
    int*   csr_src = (int*)alloc((size_t)EP * 4);
    (void)ws_size; (void)n_in;

    int conv_blocks = (N * 256 / 4 + 255) / 256;
    int gemm_blocks = ((N + 127) / 128) * 4;
    int edge_blocks = (EP + 255) / 256;
    int node_blocks = (N + 3) / 4;

    // ---------- layer 0 ----------
    const int* src0 = graph;
    const int* dst0 = graph + E;
    convert_x<<<conv_blocks, 256, 0, stream>>>(fts, Xhi, Xlo, N * 256 / 4);
    convert_w<<<512, 256, 0, stream>>>(Wl0, Wr0, Wthi, Wtlo);
    mfma_gemm<<<gemm_blocks, 256, 0, stream>>>(Xhi, Xlo, Wthi, Wtlo, bl0, br0, Af, B, N);
    hipMemsetAsync(count, 0, (size_t)N * 4, stream);
    hist_kernel<<<edge_blocks, 256, 0, stream>>>(dst0, (int)E, EP, count);
    scan_kernel<<<1, 1024, 0, stream>>>(count, rowptr, next, N);
    scatter_kernel<<<edge_blocks, 256, 0, stream>>>(src0, dst0, (int)E, EP, next, csr_src);
    gat_node<0><<<node_blocks, 256, 0, stream>>>(Af, B, rowptr, csr_src, att0, b0,
                                                 Xhi, Xlo, nullptr, nullptr, nullptr, N);

    // ---------- layer 1 ----------
    const int* srcL = graph + (T - 1) * 2 * E;
    const int* dstL = graph + (T - 1) * 2 * E + E;
    convert_w<<<512, 256, 0, stream>>>(Wl1, Wr1, Wthi, Wtlo);
    mfma_gemm<<<gemm_blocks, 256, 0, stream>>>(Xhi, Xlo, Wthi, Wtlo, bl1, br1, Af, B, N);
    hipMemsetAsync(count, 0, (size_t)N * 4, stream);
    hist_kernel<<<edge_blocks, 256, 0, stream>>>(dstL, (int)E, EP, count);
    scan_kernel<<<1, 1024, 0, stream>>>(count, rowptr, next, N);
    scatter_kernel<<<edge_blocks, 256, 0, stream>>>(srcL, dstL, (int)E, EP, next, csr_src);
    gat_node<1><<<node_blocks, 256, 0, stream>>>(Af, B, rowptr, csr_src, att1, b1,
                                                 nullptr, nullptr, Wlin, blin, (float*)d_out, N);
}

// Round 6
// 425.427 us; speedup vs baseline: 12.8688x; 1.5016x over previous
//
#include <hip/hip_runtime.h>
#include <hip/hip_bf16.h>
#include <math.h>

#define NEG 0.2f

typedef short bf16x8 __attribute__((ext_vector_type(8)));
typedef float f32x4 __attribute__((ext_vector_type(4)));
typedef _Float16 f16;
typedef _Float16 f16x2 __attribute__((ext_vector_type(2)));
typedef _Float16 f16x4 __attribute__((ext_vector_type(4)));

#if defined(__has_builtin)
#if __has_builtin(__builtin_amdgcn_fdot2)
#define HAVE_FDOT2 1
#endif
#endif

typedef __attribute__((address_space(3))) void as3_void;
typedef __attribute__((address_space(1))) const void as1_void;

__device__ __forceinline__ void gl_lds16(const void* g, void* l) {
    __builtin_amdgcn_global_load_lds((as1_void*)g, (as3_void*)l, 16, 0, 0);
}

__device__ __forceinline__ unsigned short f2bf(float x) {
    unsigned u = __float_as_uint(x);
    unsigned r = (u + 0x7fffu + ((u >> 16) & 1u)) >> 16;
    return (unsigned short)r;
}
__device__ __forceinline__ float bf2f(unsigned short b) {
    return __uint_as_float(((unsigned)b) << 16);
}

// ---- fp32 -> bf16 hi/lo split, vectorized 4 at a time
__global__ __launch_bounds__(256) void convert_x(const float* __restrict__ X,
                                                 unsigned short* __restrict__ hi,
                                                 unsigned short* __restrict__ lo,
                                                 int total4) {
    int i = blockIdx.x * blockDim.x + threadIdx.x;
    if (i >= total4) return;
    float4 v = ((const float4*)X)[i];
    ushort4 h, l;
    h.x = f2bf(v.x); l.x = f2bf(v.x - bf2f(h.x));
    h.y = f2bf(v.y); l.y = f2bf(v.y - bf2f(h.y));
    h.z = f2bf(v.z); l.z = f2bf(v.z - bf2f(h.z));
    h.w = f2bf(v.w); l.w = f2bf(v.w - bf2f(h.w));
    ((ushort4*)hi)[i] = h;
    ((ushort4*)lo)[i] = l;
}

// ---- build transposed combined weights for BOTH layers in one launch (grid.y = layer)
__global__ __launch_bounds__(256) void convert_w2(const float* __restrict__ Wl0,
                                                  const float* __restrict__ Wr0,
                                                  const float* __restrict__ Wl1,
                                                  const float* __restrict__ Wr1,
                                                  unsigned short* __restrict__ Whi,
                                                  unsigned short* __restrict__ Wlo) {
    int l = blockIdx.y;
    int idx = blockIdx.x * blockDim.x + threadIdx.x;   // n*256 + k
    int n = idx >> 8, k = idx & 255;
    const float* Wl = l ? Wl1 : Wl0;
    const float* Wr = l ? Wr1 : Wr0;
    float v = (n < 256) ? Wl[k * 256 + n] : Wr[k * 256 + (n - 256)];
    unsigned short h = f2bf(v);
    size_t off = (size_t)l * 512 * 256 + idx;
    Whi[off] = h;
    Wlo[off] = f2bf(v - bf2f(h));
}

// ---- stage one 128-row x 32-k tile (hi|lo packed as [128][64] bf16, 16KB) into LDS
__device__ __forceinline__ void stage32(const unsigned short* __restrict__ hi,
                                        const unsigned short* __restrict__ lo,
                                        int row_base, int row_max, int k0,
                                        char* lds, int wave, int lane) {
#pragma unroll
    for (int q = 0; q < 4; ++q) {
        int off = q * 4096 + wave * 1024 + lane * 16;  // linear byte offset incl. lane
        int row = off >> 7;                            // 128 B per row
        int slot = (off >> 4) & 7;                     // 16B slot within row
        int se = slot ^ (row & 7);                     // swizzled global chunk
        int grow = row_base + row;
        if (grow > row_max) grow = row_max;
        const unsigned short* g = (se < 4)
            ? hi + (size_t)grow * 256 + k0 + se * 8
            : lo + (size_t)grow * 256 + k0 + (se - 4) * 8;
        gl_lds16(g, lds + q * 4096 + wave * 1024);     // wave-uniform LDS base
    }
}

// ---- split-bf16 MFMA GEMM: [M,256] x [256,512] -> Af f16 (cols 0-255,+bl), B f32 (cols 256-511,+br)
__global__ __launch_bounds__(256) void mfma_gemm(const unsigned short* __restrict__ Xhi,
                                                 const unsigned short* __restrict__ Xlo,
                                                 const unsigned short* __restrict__ Wthi,
                                                 const unsigned short* __restrict__ Wtlo,
                                                 const float* __restrict__ bl,
                                                 const float* __restrict__ br,
                                                 _Float16* __restrict__ Af,
                                                 float* __restrict__ B, int M) {
    __shared__ char smem[65536];                      // 2 bufs x (A 16K + B 16K)
    int tid = threadIdx.x;
    int wave = tid >> 6, lane = tid & 63;
    int bid = blockIdx.x;
    int m_blk = bid >> 2, n_blk = bid & 3;
    int m0 = m_blk * 128;
    int wr = wave >> 1, wc = wave & 1;
    int r15 = lane & 15, c = lane >> 4;

    f32x4 acc[4][4];
#pragma unroll
    for (int mf = 0; mf < 4; ++mf)
#pragma unroll
        for (int nf = 0; nf < 4; ++nf) acc[mf][nf] = (f32x4){0.f, 0.f, 0.f, 0.f};

    stage32(Xhi, Xlo, m0, M - 1, 0, smem, wave, lane);
    stage32(Wthi, Wtlo, n_blk * 128, 511, 0, smem + 16384, wave, lane);
    __syncthreads();

    for (int t = 0; t < 8; ++t) {
        int buf = t & 1;
        if (t < 7) {
            char* nb = smem + (buf ^ 1) * 32768;
            stage32(Xhi, Xlo, m0, M - 1, (t + 1) * 32, nb, wave, lane);
            stage32(Wthi, Wtlo, n_blk * 128, 511, (t + 1) * 32, nb + 16384, wave, lane);
        }
        const char* At = smem + buf * 32768;
        const char* Bt = At + 16384;
        bf16x8 ah[4], al[4], bh[4], bo[4];
#pragma unroll
        for (int f = 0; f < 4; ++f) {
            int ar = wr * 64 + f * 16 + r15;
            ah[f] = *(const bf16x8*)(At + ar * 128 + ((c ^ (ar & 7)) << 4));
            al[f] = *(const bf16x8*)(At + ar * 128 + (((4 + c) ^ (ar & 7)) << 4));
            int br_ = wc * 64 + f * 16 + r15;
            bh[f] = *(const bf16x8*)(Bt + br_ * 128 + ((c ^ (br_ & 7)) << 4));
            bo[f] = *(const bf16x8*)(Bt + br_ * 128 + (((4 + c) ^ (br_ & 7)) << 4));
        }
#pragma unroll
        for (int mf = 0; mf < 4; ++mf)
#pragma unroll
            for (int nf = 0; nf < 4; ++nf) {
                acc[mf][nf] = __builtin_amdgcn_mfma_f32_16x16x32_bf16(ah[mf], bh[nf], acc[mf][nf], 0, 0, 0);
                acc[mf][nf] = __builtin_amdgcn_mfma_f32_16x16x32_bf16(al[mf], bh[nf], acc[mf][nf], 0, 0, 0);
                acc[mf][nf] = __builtin_amdgcn_mfma_f32_16x16x32_bf16(ah[mf], bo[nf], acc[mf][nf], 0, 0, 0);
            }
        __syncthreads();
    }

    int q4 = (lane >> 4) * 4;
#pragma unroll
    for (int nf = 0; nf < 4; ++nf) {
        int n_abs = n_blk * 128 + wc * 64 + nf * 16 + r15;
        bool left = n_abs < 256;
        float bb = left ? bl[n_abs] : br[n_abs - 256];
        int col = n_abs & 255;
#pragma unroll
        for (int mf = 0; mf < 4; ++mf) {
            int rowb = m0 + wr * 64 + mf * 16 + q4;
#pragma unroll
            for (int j = 0; j < 4; ++j) {
                int row = rowb + j;
                if (row < M) {
                    float v = acc[mf][nf][j] + bb;
                    if (left) Af[(size_t)row * 256 + col] = (_Float16)v;
                    else      B[(size_t)row * 256 + col] = v;
                }
            }
        }
    }
}

// ---- CSR build, both layers in one launch (grid.y = layer) ----
__global__ __launch_bounds__(256) void hist2(const int* __restrict__ dst0,
                                             const int* __restrict__ dst1,
                                             int Ereal, int nedges, int N,
                                             int* __restrict__ count) {
    int l = blockIdx.y;
    int i = blockIdx.x * blockDim.x + threadIdx.x;
    if (i >= nedges) return;
    const int* dst = l ? dst1 : dst0;
    int d = (i < Ereal) ? dst[i] : (i - Ereal);
    atomicAdd(&count[(size_t)l * N + d], 1);
}

// scanA: per-256-block exclusive prefix (written into rowptr slot) + block totals
__global__ __launch_bounds__(256) void scanA(const int* __restrict__ count,
                                             int* __restrict__ rowptr,
                                             int* __restrict__ blocksum, int n) {
    int l = blockIdx.y, t = threadIdx.x;
    int i = blockIdx.x * 256 + t;
    __shared__ int sh[256];
    int v = (i < n) ? count[(size_t)l * n + i] : 0;
    sh[t] = v;
    __syncthreads();
    for (int o = 1; o < 256; o <<= 1) {
        int x = (t >= o) ? sh[t - o] : 0;
        __syncthreads();
        sh[t] += x;
        __syncthreads();
    }
    if (i < n) rowptr[(size_t)l * (n + 1) + i] = sh[t] - v;   // local exclusive
    if (t == 255) blocksum[l * 256 + blockIdx.x] = sh[255];
}

// scanB: one block scans both layers' block totals (<=256 each)
__global__ __launch_bounds__(512) void scanB(int* __restrict__ blocksum, int nsb) {
    int t = threadIdx.x;
    int l = t >> 8, i = t & 255;
    __shared__ int sh[512];
    int v = (i < nsb) ? blocksum[l * 256 + i] : 0;
    sh[t] = v;
    __syncthreads();
    for (int o = 1; o < 256; o <<= 1) {
        int x = (i >= o) ? sh[t - o] : 0;
        __syncthreads();
        sh[t] += x;
        __syncthreads();
    }
    if (i < nsb) blocksum[l * 256 + i] = sh[t] - v;           // exclusive
}

// scanC: add block offsets; produce final rowptr and next
__global__ __launch_bounds__(256) void scanC(int* __restrict__ rowptr,
                                             int* __restrict__ next,
                                             const int* __restrict__ blocksum,
                                             int n, int EP) {
    int l = blockIdx.y;
    int i = blockIdx.x * 256 + threadIdx.x;
    int* rp = rowptr + (size_t)l * (n + 1);
    if (i < n) {
        int v = rp[i] + blocksum[l * 256 + blockIdx.x];
        rp[i] = v;
        next[(size_t)l * n + i] = v;
    }
    if (i == 0) rp[n] = EP;
}

__global__ __launch_bounds__(256) void scatter2(const int* __restrict__ src0,
                                                const int* __restrict__ dst0,
                                                const int* __restrict__ src1,
                                                const int* __restrict__ dst1,
                                                int Ereal, int nedges, int N,
                                                int* __restrict__ next,
                                                int* __restrict__ csr) {
    int l = blockIdx.y;
    int i = blockIdx.x * blockDim.x + threadIdx.x;
    if (i >= nedges) return;
    const int* src = l ? src1 : src0;
    const int* dst = l ? dst1 : dst0;
    int s, d;
    if (i < Ereal) { s = src[i]; d = dst[i]; }
    else           { s = d = i - Ereal; }
    int pos = atomicAdd(&next[(size_t)l * N + d], 1);
    csr[(size_t)l * nedges + pos] = s;
}

// ---- fused GATv2 node pass: one wave64 per node, defer-max online softmax,
//      fp16 xl gather (4-deep) + packed-fp16 math.
template <int MODE>
__global__ __launch_bounds__(256) void gat_node(const _Float16* __restrict__ xl,
                                                const float* __restrict__ xr,
                                                const int* __restrict__ rowptr,
                                                const int* __restrict__ csr_src,
                                                const float* __restrict__ att,
                                                const float* __restrict__ bias,
                                                unsigned short* __restrict__ yhi,
                                                unsigned short* __restrict__ ylo,
                                                const float* __restrict__ Wlin,
                                                const float* __restrict__ blin,
                                                float* __restrict__ out, int n) {
    int wid = (int)((blockIdx.x * (size_t)blockDim.x + threadIdx.x) >> 6);
    int lane = threadIdx.x & 63;
    if (wid >= n) return;
    int beg = rowptr[wid], end = rowptr[wid + 1];
    float4 xrv = ((const float4*)(xr + (size_t)wid * 256))[lane];
    f16x2 xr01 = {(f16)xrv.x, (f16)xrv.y};
    f16x2 xr23 = {(f16)xrv.z, (f16)xrv.w};
    float4 t = ((const float4*)att)[lane];
    f16x2 t01 = {(f16)t.x, (f16)t.y};
    f16x2 t23 = {(f16)t.z, (f16)t.w};
    const f16x2 n2 = {(f16)NEG, (f16)NEG};

    float m = -INFINITY, ssum = 0.f;
    float4 acc = make_float4(0.f, 0.f, 0.f, 0.f);

    auto step = [&](f16x4 a) {
        f16x2 a01 = {a.x, a.y}, a23 = {a.z, a.w};
        f16x2 v01 = a01 + xr01, v23 = a23 + xr23;
        f16x2 l01 = __builtin_elementwise_max(v01, v01 * n2);
        f16x2 l23 = __builtin_elementwise_max(v23, v23 * n2);
#ifdef HAVE_FDOT2
        float dot = __builtin_amdgcn_fdot2(l01, t01, 0.f, false);
        dot = __builtin_amdgcn_fdot2(l23, t23, dot, false);
#else
        float dot = (float)l01.x * (float)t01.x + (float)l01.y * (float)t01.y +
                    (float)l23.x * (float)t23.x + (float)l23.y * (float)t23.y;
#endif
#pragma unroll
        for (int off = 32; off > 0; off >>= 1) dot += __shfl_xor(dot, off);
        if (dot > m + 8.f) {            // wave-uniform; rare after warm-up
            float sc = __expf(m - dot); // -inf -> 0 on first edge
            ssum = ssum * sc + 1.f;
            acc.x = acc.x * sc + (float)a.x;
            acc.y = acc.y * sc + (float)a.y;
            acc.z = acc.z * sc + (float)a.z;
            acc.w = acc.w * sc + (float)a.w;
            m = dot;
        } else {                        // p bounded by e^8
            float p = __expf(dot - m);
            ssum += p;
            acc.x += p * (float)a.x;
            acc.y += p * (float)a.y;
            acc.z += p * (float)a.z;
            acc.w += p * (float)a.w;
        }
    };

    int j = beg;
    for (; j + 4 <= end; j += 4) {
        int s0 = csr_src[j], s1 = csr_src[j + 1];
        int s2 = csr_src[j + 2], s3 = csr_src[j + 3];
        f16x4 a0 = ((const f16x4*)(xl + (size_t)s0 * 256))[lane];
        f16x4 a1 = ((const f16x4*)(xl + (size_t)s1 * 256))[lane];
        f16x4 a2 = ((const f16x4*)(xl + (size_t)s2 * 256))[lane];
        f16x4 a3 = ((const f16x4*)(xl + (size_t)s3 * 256))[lane];
        step(a0); step(a1); step(a2); step(a3);
    }
    for (; j < end; ++j) {
        int s0 = csr_src[j];
        f16x4 a0 = ((const f16x4*)(xl + (size_t)s0 * 256))[lane];
        step(a0);
    }

    float inv = 1.f / ssum;
    float4 bb = ((const float4*)bias)[lane];
    float4 o;
    o.x = acc.x * inv + bb.x; o.x = o.x > 0.f ? o.x : NEG * o.x;
    o.y = acc.y * inv + bb.y; o.y = o.y > 0.f ? o.y : NEG * o.y;
    o.z = acc.z * inv + bb.z; o.z = o.z > 0.f ? o.z : NEG * o.z;
    o.w = acc.w * inv + bb.w; o.w = o.w > 0.f ? o.w : NEG * o.w;

    if (MODE == 0) {
        ushort4 h, l;
        h.x = f2bf(o.x); l.x = f2bf(o.x - bf2f(h.x));
        h.y = f2bf(o.y); l.y = f2bf(o.y - bf2f(h.y));
        h.z = f2bf(o.z); l.z = f2bf(o.z - bf2f(h.z));
        h.w = f2bf(o.w); l.w = f2bf(o.w - bf2f(h.w));
        ((ushort4*)(yhi + (size_t)wid * 256))[lane] = h;
        ((ushort4*)(ylo + (size_t)wid * 256))[lane] = l;
    } else {
        float4 w01 = ((const float4*)Wlin)[lane * 2];
        float4 w23 = ((const float4*)Wlin)[lane * 2 + 1];
        float z0 = o.x * w01.x + o.y * w01.z + o.z * w23.x + o.w * w23.z;
        float z1 = o.x * w01.y + o.y * w01.w + o.z * w23.y + o.w * w23.w;
#pragma unroll
        for (int off = 32; off > 0; off >>= 1) {
            z0 += __shfl_down(z0, off);
            z1 += __shfl_down(z1, off);
        }
        if (lane == 0) {
            z0 += blin[0];
            z1 += blin[1];
            float mx = fmaxf(z0, z1);
            float lse = mx + logf(expf(z0 - mx) + expf(z1 - mx));
            out[(size_t)wid * 2 + 0] = z0 - lse;
            out[(size_t)wid * 2 + 1] = z1 - lse;
        }
    }
}

extern "C" void kernel_launch(void* const* d_in, const int* in_sizes, int n_in,
                              void* d_out, int out_size, void* d_ws, size_t ws_size,
                              hipStream_t stream) {
    const float* fts   = (const float*)d_in[0];
    const int*   graph = (const int*)d_in[1];
    const float* Wl0 = (const float*)d_in[2];
    const float* Wr0 = (const float*)d_in[3];
    const float* bl0 = (const float*)d_in[4];
    const float* br0 = (const float*)d_in[5];
    const float* att0 = (const float*)d_in[6];
    const float* b0  = (const float*)d_in[7];
    const float* Wl1 = (const float*)d_in[8];
    const float* Wr1 = (const float*)d_in[9];
    const float* bl1 = (const float*)d_in[10];
    const float* br1 = (const float*)d_in[11];
    const float* att1 = (const float*)d_in[12];
    const float* b1  = (const float*)d_in[13];
    const float* Wlin = (const float*)d_in[14];
    const float* blin = (const float*)d_in[15];

    int N = out_size / 2;                                   // 40000
    long T = in_sizes[0] / ((long)N * 256);                 // 4
    long E = in_sizes[1] / (2 * T);                         // 640000
    int EP = (int)E + N;

    char* ws = (char*)d_ws;
    size_t off = 0;
    auto alloc = [&](size_t bytes) -> void* {
        void* p = ws + off;
        off += (bytes + 255) & ~(size_t)255;
        return p;
    };
    _Float16* Af = (_Float16*)alloc((size_t)N * 256 * 2);   // xl (fp16)
    float* B  = (float*)alloc((size_t)N * 256 * 4);         // xr (fp32)
    unsigned short* Xhi  = (unsigned short*)alloc((size_t)N * 256 * 2);
    unsigned short* Xlo  = (unsigned short*)alloc((size_t)N * 256 * 2);
    unsigned short* Whi  = (unsigned short*)alloc((size_t)2 * 512 * 256 * 2);
    unsigned short* Wlo  = (unsigned short*)alloc((size_t)2 * 512 * 256 * 2);
    int* count    = (int*)alloc((size_t)2 * N * 4);
    int* rowptr   = (int*)alloc((size_t)2 * (N + 1) * 4);
    int* next     = (int*)alloc((size_t)2 * N * 4);
    int* csr      = (int*)alloc((size_t)2 * EP * 4);
    int* blocksum = (int*)alloc((size_t)2 * 256 * 4);
    (void)ws_size; (void)n_in;

    int conv_blocks = (N * 256 / 4 + 255) / 256;
    int gemm_blocks = ((N + 127) / 128) * 4;
    int nsb = (N + 255) / 256;                              // 157
    dim3 edge_grid((EP + 255) / 256, 2);
    dim3 scan_grid(nsb, 2);
    int node_blocks = (N + 3) / 4;

    const int* src0 = graph;
    const int* dst0 = graph + E;
    const int* srcL = graph + (T - 1) * 2 * E;
    const int* dstL = graph + (T - 1) * 2 * E + E;

    // ---------- upfront: converts + CSR build for BOTH layers ----------
    convert_x<<<conv_blocks, 256, 0, stream>>>(fts, Xhi, Xlo, N * 256 / 4);
    convert_w2<<<dim3(512, 2), 256, 0, stream>>>(Wl0, Wr0, Wl1, Wr1, Whi, Wlo);
    hipMemsetAsync(count, 0, (size_t)2 * N * 4, stream);
    hist2<<<edge_grid, 256, 0, stream>>>(dst0, dstL, (int)E, EP, N, count);
    scanA<<<scan_grid, 256, 0, stream>>>(count, rowptr, blocksum, N);
    scanB<<<1, 512, 0, stream>>>(blocksum, nsb);
    scanC<<<scan_grid, 256, 0, stream>>>(rowptr, next, blocksum, N, EP);
    scatter2<<<edge_grid, 256, 0, stream>>>(src0, dst0, srcL, dstL, (int)E, EP, N, next, csr);

    // ---------- layer 0 ----------
    mfma_gemm<<<gemm_blocks, 256, 0, stream>>>(Xhi, Xlo, Whi, Wlo, bl0, br0, Af, B, N);
    gat_node<0><<<node_blocks, 256, 0, stream>>>(Af, B, rowptr, csr, att0, b0,
                                                 Xhi, Xlo, nullptr, nullptr, nullptr, N);

    // ---------- layer 1 ----------
    mfma_gemm<<<gemm_blocks, 256, 0, stream>>>(Xhi, Xlo, Whi + (size_t)512 * 256,
                                               Wlo + (size_t)512 * 256, bl1, br1, Af, B, N);
    gat_node<1><<<node_blocks, 256, 0, stream>>>(Af, B, rowptr + (N + 1), csr + EP, att1, b1,
                                                 nullptr, nullptr, Wlin, blin, (float*)d_out, N);
}

// Round 7
// 323.859 us; speedup vs baseline: 16.9047x; 1.3136x over previous
//
#include <hip/hip_runtime.h>
#include <hip/hip_bf16.h>
#include <math.h>

#define NEG 0.2f
#define NB_MAX 256

typedef short bf16x8 __attribute__((ext_vector_type(8)));
typedef float f32x4 __attribute__((ext_vector_type(4)));
typedef _Float16 f16;
typedef _Float16 f16x2 __attribute__((ext_vector_type(2)));
typedef _Float16 f16x4 __attribute__((ext_vector_type(4)));

#if defined(__has_builtin)
#if __has_builtin(__builtin_amdgcn_fdot2)
#define HAVE_FDOT2 1
#endif
#endif

typedef __attribute__((address_space(3))) void as3_void;
typedef __attribute__((address_space(1))) const void as1_void;

__device__ __forceinline__ void gl_lds16(const void* g, void* l) {
    __builtin_amdgcn_global_load_lds((as1_void*)g, (as3_void*)l, 16, 0, 0);
}

__device__ __forceinline__ unsigned short f2bf(float x) {
    unsigned u = __float_as_uint(x);
    unsigned r = (u + 0x7fffu + ((u >> 16) & 1u)) >> 16;
    return (unsigned short)r;
}
__device__ __forceinline__ float bf2f(unsigned short b) {
    return __uint_as_float(((unsigned)b) << 16);
}

// ---- fp32 -> bf16 hi/lo split, vectorized 4 at a time
__global__ __launch_bounds__(256) void convert_x(const float* __restrict__ X,
                                                 unsigned short* __restrict__ hi,
                                                 unsigned short* __restrict__ lo,
                                                 int total4) {
    int i = blockIdx.x * blockDim.x + threadIdx.x;
    if (i >= total4) return;
    float4 v = ((const float4*)X)[i];
    ushort4 h, l;
    h.x = f2bf(v.x); l.x = f2bf(v.x - bf2f(h.x));
    h.y = f2bf(v.y); l.y = f2bf(v.y - bf2f(h.y));
    h.z = f2bf(v.z); l.z = f2bf(v.z - bf2f(h.z));
    h.w = f2bf(v.w); l.w = f2bf(v.w - bf2f(h.w));
    ((ushort4*)hi)[i] = h;
    ((ushort4*)lo)[i] = l;
}

// ---- build transposed combined weights for BOTH layers in one launch (grid.y = layer)
__global__ __launch_bounds__(256) void convert_w2(const float* __restrict__ Wl0,
                                                  const float* __restrict__ Wr0,
                                                  const float* __restrict__ Wl1,
                                                  const float* __restrict__ Wr1,
                                                  unsigned short* __restrict__ Whi,
                                                  unsigned short* __restrict__ Wlo) {
    int l = blockIdx.y;
    int idx = blockIdx.x * blockDim.x + threadIdx.x;   // n*256 + k
    int n = idx >> 8, k = idx & 255;
    const float* Wl = l ? Wl1 : Wl0;
    const float* Wr = l ? Wr1 : Wr0;
    float v = (n < 256) ? Wl[k * 256 + n] : Wr[k * 256 + (n - 256)];
    unsigned short h = f2bf(v);
    size_t off = (size_t)l * 512 * 256 + idx;
    Whi[off] = h;
    Wlo[off] = f2bf(v - bf2f(h));
}

// ---- stage one 128-row x 32-k tile (hi|lo packed as [128][64] bf16, 16KB) into LDS
__device__ __forceinline__ void stage32(const unsigned short* __restrict__ hi,
                                        const unsigned short* __restrict__ lo,
                                        int row_base, int row_max, int k0,
                                        char* lds, int wave, int lane) {
#pragma unroll
    for (int q = 0; q < 4; ++q) {
        int off = q * 4096 + wave * 1024 + lane * 16;  // linear byte offset incl. lane
        int row = off >> 7;                            // 128 B per row
        int slot = (off >> 4) & 7;                     // 16B slot within row
        int se = slot ^ (row & 7);                     // swizzled global chunk
        int grow = row_base + row;
        if (grow > row_max) grow = row_max;
        const unsigned short* g = (se < 4)
            ? hi + (size_t)grow * 256 + k0 + se * 8
            : lo + (size_t)grow * 256 + k0 + (se - 4) * 8;
        gl_lds16(g, lds + q * 4096 + wave * 1024);     // wave-uniform LDS base
    }
}

// ---- split-bf16 MFMA GEMM: [M,256] x [256,512] -> Af f16 (cols 0-255,+bl), B f32 (cols 256-511,+br)
__global__ __launch_bounds__(256) void mfma_gemm(const unsigned short* __restrict__ Xhi,
                                                 const unsigned short* __restrict__ Xlo,
                                                 const unsigned short* __restrict__ Wthi,
                                                 const unsigned short* __restrict__ Wtlo,
                                                 const float* __restrict__ bl,
                                                 const float* __restrict__ br,
                                                 _Float16* __restrict__ Af,
                                                 float* __restrict__ B, int M) {
    __shared__ char smem[65536];                      // 2 bufs x (A 16K + B 16K)
    int tid = threadIdx.x;
    int wave = tid >> 6, lane = tid & 63;
    int bid = blockIdx.x;
    int m_blk = bid >> 2, n_blk = bid & 3;
    int m0 = m_blk * 128;
    int wr = wave >> 1, wc = wave & 1;
    int r15 = lane & 15, c = lane >> 4;

    f32x4 acc[4][4];
#pragma unroll
    for (int mf = 0; mf < 4; ++mf)
#pragma unroll
        for (int nf = 0; nf < 4; ++nf) acc[mf][nf] = (f32x4){0.f, 0.f, 0.f, 0.f};

    stage32(Xhi, Xlo, m0, M - 1, 0, smem, wave, lane);
    stage32(Wthi, Wtlo, n_blk * 128, 511, 0, smem + 16384, wave, lane);
    __syncthreads();

    for (int t = 0; t < 8; ++t) {
        int buf = t & 1;
        if (t < 7) {
            char* nb = smem + (buf ^ 1) * 32768;
            stage32(Xhi, Xlo, m0, M - 1, (t + 1) * 32, nb, wave, lane);
            stage32(Wthi, Wtlo, n_blk * 128, 511, (t + 1) * 32, nb + 16384, wave, lane);
        }
        const char* At = smem + buf * 32768;
        const char* Bt = At + 16384;
        bf16x8 ah[4], al[4], bh[4], bo[4];
#pragma unroll
        for (int f = 0; f < 4; ++f) {
            int ar = wr * 64 + f * 16 + r15;
            ah[f] = *(const bf16x8*)(At + ar * 128 + ((c ^ (ar & 7)) << 4));
            al[f] = *(const bf16x8*)(At + ar * 128 + (((4 + c) ^ (ar & 7)) << 4));
            int br_ = wc * 64 + f * 16 + r15;
            bh[f] = *(const bf16x8*)(Bt + br_ * 128 + ((c ^ (br_ & 7)) << 4));
            bo[f] = *(const bf16x8*)(Bt + br_ * 128 + (((4 + c) ^ (br_ & 7)) << 4));
        }
#pragma unroll
        for (int mf = 0; mf < 4; ++mf)
#pragma unroll
            for (int nf = 0; nf < 4; ++nf) {
                acc[mf][nf] = __builtin_amdgcn_mfma_f32_16x16x32_bf16(ah[mf], bh[nf], acc[mf][nf], 0, 0, 0);
                acc[mf][nf] = __builtin_amdgcn_mfma_f32_16x16x32_bf16(al[mf], bh[nf], acc[mf][nf], 0, 0, 0);
                acc[mf][nf] = __builtin_amdgcn_mfma_f32_16x16x32_bf16(ah[mf], bo[nf], acc[mf][nf], 0, 0, 0);
            }
        __syncthreads();
    }

    int q4 = (lane >> 4) * 4;
#pragma unroll
    for (int nf = 0; nf < 4; ++nf) {
        int n_abs = n_blk * 128 + wc * 64 + nf * 16 + r15;
        bool left = n_abs < 256;
        float bb = left ? bl[n_abs] : br[n_abs - 256];
        int col = n_abs & 255;
#pragma unroll
        for (int mf = 0; mf < 4; ++mf) {
            int rowb = m0 + wr * 64 + mf * 16 + q4;
#pragma unroll
            for (int j = 0; j < 4; ++j) {
                int row = rowb + j;
                if (row < M) {
                    float v = acc[mf][nf][j] + bb;
                    if (left) Af[(size_t)row * 256 + col] = (_Float16)v;
                    else      B[(size_t)row * 256 + col] = v;
                }
            }
        }
    }
}

// ==================== binned CSR build (both layers, grid.y = layer) ====================
// phase 0: coarse histogram over buckets (dst>>8)
__global__ __launch_bounds__(256) void bucket_hist(const int* __restrict__ dst0,
                                                   const int* __restrict__ dst1,
                                                   int Ereal, int EP, int nb,
                                                   int* __restrict__ bkt_count) {
    __shared__ int hist[NB_MAX];
    int l = blockIdx.y;
    for (int i = threadIdx.x; i < nb; i += 256) hist[i] = 0;
    __syncthreads();
    const int* dst = l ? dst1 : dst0;
    int c0 = blockIdx.x * 4096;
#pragma unroll
    for (int k = 0; k < 16; ++k) {
        int i = c0 + k * 256 + threadIdx.x;
        if (i < EP) {
            int d = (i < Ereal) ? dst[i] : (i - Ereal);
            atomicAdd(&hist[d >> 8], 1);
        }
    }
    __syncthreads();
    for (int i = threadIdx.x; i < nb; i += 256)
        if (hist[i]) atomicAdd(&bkt_count[l * nb + i], hist[i]);
}

// phase 1: tiny exclusive scan of bucket counts (both layers in one block)
__global__ __launch_bounds__(512) void bscan(const int* __restrict__ bkt_count,
                                             int* __restrict__ bkt_base,
                                             int* __restrict__ bkt_next,
                                             int* __restrict__ rowptr,
                                             int nb, int N, int EP) {
    __shared__ int sh[512];
    int t = threadIdx.x, l = t >> 8, i = t & 255;
    int v = (i < nb) ? bkt_count[l * nb + i] : 0;
    sh[t] = v;
    __syncthreads();
    for (int o = 1; o < 256; o <<= 1) {
        int x = (i >= o) ? sh[t - o] : 0;
        __syncthreads();
        sh[t] += x;
        __syncthreads();
    }
    if (i < nb) {
        int b = sh[t] - v;   // exclusive
        bkt_base[l * nb + i] = b;
        bkt_next[l * nb + i] = b;
    }
    if (i == 0) rowptr[(size_t)l * (N + 1) + N] = EP;
}

// phase 2: bin edges into coarse buckets; packed record (dlow<<16)|src (both < 2^16)
__global__ __launch_bounds__(256) void binA(const int* __restrict__ src0,
                                            const int* __restrict__ dst0,
                                            const int* __restrict__ src1,
                                            const int* __restrict__ dst1,
                                            int Ereal, int EP, int nb,
                                            int* __restrict__ bkt_next,
                                            unsigned* __restrict__ bucketBuf) {
    __shared__ int hist[NB_MAX], base[NB_MAX], ofs[NB_MAX];
    int l = blockIdx.y;
    for (int i = threadIdx.x; i < nb; i += 256) hist[i] = 0;
    __syncthreads();
    const int* src = l ? src1 : src0;
    const int* dst = l ? dst1 : dst0;
    int c0 = blockIdx.x * 4096;
    int dcache[16];
#pragma unroll
    for (int k = 0; k < 16; ++k) {
        int i = c0 + k * 256 + threadIdx.x;
        int d = -1;
        if (i < EP) d = (i < Ereal) ? dst[i] : (i - Ereal);
        dcache[k] = d;
        if (d >= 0) atomicAdd(&hist[d >> 8], 1);
    }
    __syncthreads();
    for (int i = threadIdx.x; i < nb; i += 256) {
        base[i] = hist[i] ? atomicAdd(&bkt_next[l * nb + i], hist[i]) : 0;
        ofs[i] = 0;
    }
    __syncthreads();
#pragma unroll
    for (int k = 0; k < 16; ++k) {
        int i = c0 + k * 256 + threadIdx.x;
        int d = dcache[k];
        if (d >= 0) {
            int s = (i < Ereal) ? src[i] : (i - Ereal);
            int b = d >> 8;
            int pos = base[b] + atomicAdd(&ofs[b], 1);
            bucketBuf[(size_t)l * EP + pos] = (unsigned)s | ((unsigned)(d & 255) << 16);
        }
    }
}

// phase 3: per-bucket local counting sort -> rowptr + csr (one block per bucket)
__global__ __launch_bounds__(256) void binB(const unsigned* __restrict__ bucketBuf,
                                            const int* __restrict__ bkt_base,
                                            const int* __restrict__ bkt_count,
                                            int nb, int N, int EP,
                                            int* __restrict__ rowptr,
                                            int* __restrict__ csr) {
    __shared__ int hist[256], sh[256], nxt[256];
    int b = blockIdx.x, l = blockIdx.y, t = threadIdx.x;
    int base = bkt_base[l * nb + b];
    int cnt = bkt_count[l * nb + b];
    hist[t] = 0;
    __syncthreads();
    const unsigned* buf = bucketBuf + (size_t)l * EP + base;
    for (int i = t; i < cnt; i += 256)
        atomicAdd(&hist[buf[i] >> 16], 1);
    __syncthreads();
    int h = hist[t];
    sh[t] = h;
    __syncthreads();
    for (int o = 1; o < 256; o <<= 1) {
        int x = (t >= o) ? sh[t - o] : 0;
        __syncthreads();
        sh[t] += x;
        __syncthreads();
    }
    int excl = sh[t] - h;
    nxt[t] = excl;
    int d = b * 256 + t;
    if (d < N) rowptr[(size_t)l * (N + 1) + d] = base + excl;
    __syncthreads();
    for (int i = t; i < cnt; i += 256) {
        unsigned v = buf[i];
        int pos = base + atomicAdd(&nxt[v >> 16], 1);
        csr[(size_t)l * EP + pos] = (int)(v & 0xFFFFu);
    }
}

// ---- fused GATv2 node pass: one wave64 per node, defer-max online softmax,
//      fp16 xl gather (8/4-deep) + packed-fp16 math.
template <int MODE>
__global__ __launch_bounds__(256) void gat_node(const _Float16* __restrict__ xl,
                                                const float* __restrict__ xr,
                                                const int* __restrict__ rowptr,
                                                const int* __restrict__ csr_src,
                                                const float* __restrict__ att,
                                                const float* __restrict__ bias,
                                                unsigned short* __restrict__ yhi,
                                                unsigned short* __restrict__ ylo,
                                                const float* __restrict__ Wlin,
                                                const float* __restrict__ blin,
                                                float* __restrict__ out, int n) {
    int wid = (int)((blockIdx.x * (size_t)blockDim.x + threadIdx.x) >> 6);
    int lane = threadIdx.x & 63;
    if (wid >= n) return;
    int beg = rowptr[wid], end = rowptr[wid + 1];
    float4 xrv = ((const float4*)(xr + (size_t)wid * 256))[lane];
    f16x2 xr01 = {(f16)xrv.x, (f16)xrv.y};
    f16x2 xr23 = {(f16)xrv.z, (f16)xrv.w};
    float4 t = ((const float4*)att)[lane];
    f16x2 t01 = {(f16)t.x, (f16)t.y};
    f16x2 t23 = {(f16)t.z, (f16)t.w};
    const f16x2 n2 = {(f16)NEG, (f16)NEG};

    float m = -INFINITY, ssum = 0.f;
    float4 acc = make_float4(0.f, 0.f, 0.f, 0.f);

    auto step = [&](f16x4 a) {
        f16x2 a01 = {a.x, a.y}, a23 = {a.z, a.w};
        f16x2 v01 = a01 + xr01, v23 = a23 + xr23;
        f16x2 l01 = __builtin_elementwise_max(v01, v01 * n2);
        f16x2 l23 = __builtin_elementwise_max(v23, v23 * n2);
#ifdef HAVE_FDOT2
        float dot = __builtin_amdgcn_fdot2(l01, t01, 0.f, false);
        dot = __builtin_amdgcn_fdot2(l23, t23, dot, false);
#else
        float dot = (float)l01.x * (float)t01.x + (float)l01.y * (float)t01.y +
                    (float)l23.x * (float)t23.x + (float)l23.y * (float)t23.y;
#endif
#pragma unroll
        for (int off = 32; off > 0; off >>= 1) dot += __shfl_xor(dot, off);
        if (dot > m + 8.f) {            // wave-uniform; rare after warm-up
            float sc = __expf(m - dot); // -inf -> 0 on first edge
            ssum = ssum * sc + 1.f;
            acc.x = acc.x * sc + (float)a.x;
            acc.y = acc.y * sc + (float)a.y;
            acc.z = acc.z * sc + (float)a.z;
            acc.w = acc.w * sc + (float)a.w;
            m = dot;
        } else {                        // p bounded by e^8
            float p = __expf(dot - m);
            ssum += p;
            acc.x += p * (float)a.x;
            acc.y += p * (float)a.y;
            acc.z += p * (float)a.z;
            acc.w += p * (float)a.w;
        }
    };

    int j = beg;
    for (; j + 8 <= end; j += 8) {
        f16x4 a[8];
#pragma unroll
        for (int u = 0; u < 8; ++u) {
            int s = csr_src[j + u];
            a[u] = ((const f16x4*)(xl + (size_t)s * 256))[lane];
        }
#pragma unroll
        for (int u = 0; u < 8; ++u) step(a[u]);
    }
    if (j + 4 <= end) {
        f16x4 a[4];
#pragma unroll
        for (int u = 0; u < 4; ++u) {
            int s = csr_src[j + u];
            a[u] = ((const f16x4*)(xl + (size_t)s * 256))[lane];
        }
#pragma unroll
        for (int u = 0; u < 4; ++u) step(a[u]);
        j += 4;
    }
    for (; j < end; ++j) {
        int s0 = csr_src[j];
        f16x4 a0 = ((const f16x4*)(xl + (size_t)s0 * 256))[lane];
        step(a0);
    }

    float inv = 1.f / ssum;
    float4 bb = ((const float4*)bias)[lane];
    float4 o;
    o.x = acc.x * inv + bb.x; o.x = o.x > 0.f ? o.x : NEG * o.x;
    o.y = acc.y * inv + bb.y; o.y = o.y > 0.f ? o.y : NEG * o.y;
    o.z = acc.z * inv + bb.z; o.z = o.z > 0.f ? o.z : NEG * o.z;
    o.w = acc.w * inv + bb.w; o.w = o.w > 0.f ? o.w : NEG * o.w;

    if (MODE == 0) {
        ushort4 h, l;
        h.x = f2bf(o.x); l.x = f2bf(o.x - bf2f(h.x));
        h.y = f2bf(o.y); l.y = f2bf(o.y - bf2f(h.y));
        h.z = f2bf(o.z); l.z = f2bf(o.z - bf2f(h.z));
        h.w = f2bf(o.w); l.w = f2bf(o.w - bf2f(h.w));
        ((ushort4*)(yhi + (size_t)wid * 256))[lane] = h;
        ((ushort4*)(ylo + (size_t)wid * 256))[lane] = l;
    } else {
        float4 w01 = ((const float4*)Wlin)[lane * 2];
        float4 w23 = ((const float4*)Wlin)[lane * 2 + 1];
        float z0 = o.x * w01.x + o.y * w01.z + o.z * w23.x + o.w * w23.z;
        float z1 = o.x * w01.y + o.y * w01.w + o.z * w23.y + o.w * w23.w;
#pragma unroll
        for (int off = 32; off > 0; off >>= 1) {
            z0 += __shfl_down(z0, off);
            z1 += __shfl_down(z1, off);
        }
        if (lane == 0) {
            z0 += blin[0];
            z1 += blin[1];
            float mx = fmaxf(z0, z1);
            float lse = mx + logf(expf(z0 - mx) + expf(z1 - mx));
            out[(size_t)wid * 2 + 0] = z0 - lse;
            out[(size_t)wid * 2 + 1] = z1 - lse;
        }
    }
}

extern "C" void kernel_launch(void* const* d_in, const int* in_sizes, int n_in,
                              void* d_out, int out_size, void* d_ws, size_t ws_size,
                              hipStream_t stream) {
    const float* fts   = (const float*)d_in[0];
    const int*   graph = (const int*)d_in[1];
    const float* Wl0 = (const float*)d_in[2];
    const float* Wr0 = (const float*)d_in[3];
    const float* bl0 = (const float*)d_in[4];
    const float* br0 = (const float*)d_in[5];
    const float* att0 = (const float*)d_in[6];
    const float* b0  = (const float*)d_in[7];
    const float* Wl1 = (const float*)d_in[8];
    const float* Wr1 = (const float*)d_in[9];
    const float* bl1 = (const float*)d_in[10];
    const float* br1 = (const float*)d_in[11];
    const float* att1 = (const float*)d_in[12];
    const float* b1  = (const float*)d_in[13];
    const float* Wlin = (const float*)d_in[14];
    const float* blin = (const float*)d_in[15];

    int N = out_size / 2;                                   // 40000
    long T = in_sizes[0] / ((long)N * 256);                 // 4
    long E = in_sizes[1] / (2 * T);                         // 640000
    int EP = (int)E + N;
    int nb = (N + 255) / 256;                               // 157 buckets

    char* ws = (char*)d_ws;
    size_t off = 0;
    auto alloc = [&](size_t bytes) -> void* {
        void* p = ws + off;
        off += (bytes + 255) & ~(size_t)255;
        return p;
    };
    _Float16* Af = (_Float16*)alloc((size_t)N * 256 * 2);   // xl (fp16)
    float* B  = (float*)alloc((size_t)N * 256 * 4);         // xr (fp32)
    unsigned short* Xhi  = (unsigned short*)alloc((size_t)N * 256 * 2);
    unsigned short* Xlo  = (unsigned short*)alloc((size_t)N * 256 * 2);
    unsigned short* Whi  = (unsigned short*)alloc((size_t)2 * 512 * 256 * 2);
    unsigned short* Wlo  = (unsigned short*)alloc((size_t)2 * 512 * 256 * 2);
    int* rowptr    = (int*)alloc((size_t)2 * (N + 1) * 4);
    int* csr       = (int*)alloc((size_t)2 * EP * 4);
    unsigned* bucketBuf = (unsigned*)alloc((size_t)2 * EP * 4);
    int* bkt_count = (int*)alloc((size_t)2 * nb * 4);
    int* bkt_base  = (int*)alloc((size_t)2 * nb * 4);
    int* bkt_next  = (int*)alloc((size_t)2 * nb * 4);
    (void)ws_size; (void)n_in;

    int conv_blocks = (N * 256 / 4 + 255) / 256;
    int gemm_blocks = ((N + 127) / 128) * 4;
    dim3 chunk_grid((EP + 4095) / 4096, 2);
    int node_blocks = (N + 3) / 4;

    const int* src0 = graph;
    const int* dst0 = graph + E;
    const int* srcL = graph + (T - 1) * 2 * E;
    const int* dstL = graph + (T - 1) * 2 * E + E;

    // ---------- upfront: converts + binned CSR build for BOTH layers ----------
    convert_x<<<conv_blocks, 256, 0, stream>>>(fts, Xhi, Xlo, N * 256 / 4);
    convert_w2<<<dim3(512, 2), 256, 0, stream>>>(Wl0, Wr0, Wl1, Wr1, Whi, Wlo);
    hipMemsetAsync(bkt_count, 0, (size_t)2 * nb * 4, stream);
    bucket_hist<<<chunk_grid, 256, 0, stream>>>(dst0, dstL, (int)E, EP, nb, bkt_count);
    bscan<<<1, 512, 0, stream>>>(bkt_count, bkt_base, bkt_next, rowptr, nb, N, EP);
    binA<<<chunk_grid, 256, 0, stream>>>(src0, dst0, srcL, dstL, (int)E, EP, nb,
                                         bkt_next, bucketBuf);
    binB<<<dim3(nb, 2), 256, 0, stream>>>(bucketBuf, bkt_base, bkt_count, nb, N, EP,
                                          rowptr, csr);

    // ---------- layer 0 ----------
    mfma_gemm<<<gemm_blocks, 256, 0, stream>>>(Xhi, Xlo, Whi, Wlo, bl0, br0, Af, B, N);
    gat_node<0><<<node_blocks, 256, 0, stream>>>(Af, B, rowptr, csr, att0, b0,
                                                 Xhi, Xlo, nullptr, nullptr, nullptr, N);

    // ---------- layer 1 ----------
    mfma_gemm<<<gemm_blocks, 256, 0, stream>>>(Xhi, Xlo, Whi + (size_t)512 * 256,
                                               Wlo + (size_t)512 * 256, bl1, br1, Af, B, N);
    gat_node<1><<<node_blocks, 256, 0, stream>>>(Af, B, rowptr + (N + 1), csr + EP, att1, b1,
                                                 nullptr, nullptr, Wlin, blin, (float*)d_out, N);
}

// Round 8
// 301.110 us; speedup vs baseline: 18.1819x; 1.0756x over previous
//
#include <hip/hip_runtime.h>
#include <hip/hip_bf16.h>
#include <math.h>

#define NEG 0.2f
#define NB_MAX 256

typedef short bf16x8 __attribute__((ext_vector_type(8)));
typedef float f32x4 __attribute__((ext_vector_type(4)));
typedef _Float16 f16;
typedef _Float16 f16x2 __attribute__((ext_vector_type(2)));
typedef _Float16 f16x8 __attribute__((ext_vector_type(8)));
typedef unsigned short u16x8 __attribute__((ext_vector_type(8)));

#if defined(__has_builtin)
#if __has_builtin(__builtin_amdgcn_fdot2)
#define HAVE_FDOT2 1
#endif
#endif

typedef __attribute__((address_space(3))) void as3_void;
typedef __attribute__((address_space(1))) const void as1_void;

__device__ __forceinline__ void gl_lds16(const void* g, void* l) {
    __builtin_amdgcn_global_load_lds((as1_void*)g, (as3_void*)l, 16, 0, 0);
}

__device__ __forceinline__ unsigned short f2bf(float x) {
    unsigned u = __float_as_uint(x);
    unsigned r = (u + 0x7fffu + ((u >> 16) & 1u)) >> 16;
    return (unsigned short)r;
}
__device__ __forceinline__ float bf2f(unsigned short b) {
    return __uint_as_float(((unsigned)b) << 16);
}

// ---- fp32 -> bf16 hi/lo split, vectorized 4 at a time
__global__ __launch_bounds__(256) void convert_x(const float* __restrict__ X,
                                                 unsigned short* __restrict__ hi,
                                                 unsigned short* __restrict__ lo,
                                                 int total4) {
    int i = blockIdx.x * blockDim.x + threadIdx.x;
    if (i >= total4) return;
    float4 v = ((const float4*)X)[i];
    ushort4 h, l;
    h.x = f2bf(v.x); l.x = f2bf(v.x - bf2f(h.x));
    h.y = f2bf(v.y); l.y = f2bf(v.y - bf2f(h.y));
    h.z = f2bf(v.z); l.z = f2bf(v.z - bf2f(h.z));
    h.w = f2bf(v.w); l.w = f2bf(v.w - bf2f(h.w));
    ((ushort4*)hi)[i] = h;
    ((ushort4*)lo)[i] = l;
}

// ---- build transposed combined weights for BOTH layers in one launch (grid.y = layer)
__global__ __launch_bounds__(256) void convert_w2(const float* __restrict__ Wl0,
                                                  const float* __restrict__ Wr0,
                                                  const float* __restrict__ Wl1,
                                                  const float* __restrict__ Wr1,
                                                  unsigned short* __restrict__ Whi,
                                                  unsigned short* __restrict__ Wlo) {
    int l = blockIdx.y;
    int idx = blockIdx.x * blockDim.x + threadIdx.x;   // n*256 + k
    int n = idx >> 8, k = idx & 255;
    const float* Wl = l ? Wl1 : Wl0;
    const float* Wr = l ? Wr1 : Wr0;
    float v = (n < 256) ? Wl[k * 256 + n] : Wr[k * 256 + (n - 256)];
    unsigned short h = f2bf(v);
    size_t off = (size_t)l * 512 * 256 + idx;
    Whi[off] = h;
    Wlo[off] = f2bf(v - bf2f(h));
}

// ---- stage one 128-row x 32-k tile (hi|lo packed as [128][64] bf16, 16KB) into LDS
__device__ __forceinline__ void stage32(const unsigned short* __restrict__ hi,
                                        const unsigned short* __restrict__ lo,
                                        int row_base, int row_max, int k0,
                                        char* lds, int wave, int lane) {
#pragma unroll
    for (int q = 0; q < 4; ++q) {
        int off = q * 4096 + wave * 1024 + lane * 16;  // linear byte offset incl. lane
        int row = off >> 7;                            // 128 B per row
        int slot = (off >> 4) & 7;                     // 16B slot within row
        int se = slot ^ (row & 7);                     // swizzled global chunk
        int grow = row_base + row;
        if (grow > row_max) grow = row_max;
        const unsigned short* g = (se < 4)
            ? hi + (size_t)grow * 256 + k0 + se * 8
            : lo + (size_t)grow * 256 + k0 + (se - 4) * 8;
        gl_lds16(g, lds + q * 4096 + wave * 1024);     // wave-uniform LDS base
    }
}

// ---- split-bf16 MFMA GEMM: [M,256] x [256,512] -> Af f16 (cols 0-255,+bl), Bf f16 (cols 256-511,+br)
__global__ __launch_bounds__(256) void mfma_gemm(const unsigned short* __restrict__ Xhi,
                                                 const unsigned short* __restrict__ Xlo,
                                                 const unsigned short* __restrict__ Wthi,
                                                 const unsigned short* __restrict__ Wtlo,
                                                 const float* __restrict__ bl,
                                                 const float* __restrict__ br,
                                                 _Float16* __restrict__ Af,
                                                 _Float16* __restrict__ Bf, int M) {
    __shared__ char smem[65536];                      // 2 bufs x (A 16K + B 16K)
    int tid = threadIdx.x;
    int wave = tid >> 6, lane = tid & 63;
    int bid = blockIdx.x;
    int m_blk = bid >> 2, n_blk = bid & 3;
    int m0 = m_blk * 128;
    int wr = wave >> 1, wc = wave & 1;
    int r15 = lane & 15, c = lane >> 4;

    f32x4 acc[4][4];
#pragma unroll
    for (int mf = 0; mf < 4; ++mf)
#pragma unroll
        for (int nf = 0; nf < 4; ++nf) acc[mf][nf] = (f32x4){0.f, 0.f, 0.f, 0.f};

    stage32(Xhi, Xlo, m0, M - 1, 0, smem, wave, lane);
    stage32(Wthi, Wtlo, n_blk * 128, 511, 0, smem + 16384, wave, lane);
    __syncthreads();

    for (int t = 0; t < 8; ++t) {
        int buf = t & 1;
        if (t < 7) {
            char* nb = smem + (buf ^ 1) * 32768;
            stage32(Xhi, Xlo, m0, M - 1, (t + 1) * 32, nb, wave, lane);
            stage32(Wthi, Wtlo, n_blk * 128, 511, (t + 1) * 32, nb + 16384, wave, lane);
        }
        const char* At = smem + buf * 32768;
        const char* Bt = At + 16384;
        bf16x8 ah[4], al[4], bh[4], bo[4];
#pragma unroll
        for (int f = 0; f < 4; ++f) {
            int ar = wr * 64 + f * 16 + r15;
            ah[f] = *(const bf16x8*)(At + ar * 128 + ((c ^ (ar & 7)) << 4));
            al[f] = *(const bf16x8*)(At + ar * 128 + (((4 + c) ^ (ar & 7)) << 4));
            int br_ = wc * 64 + f * 16 + r15;
            bh[f] = *(const bf16x8*)(Bt + br_ * 128 + ((c ^ (br_ & 7)) << 4));
            bo[f] = *(const bf16x8*)(Bt + br_ * 128 + (((4 + c) ^ (br_ & 7)) << 4));
        }
#pragma unroll
        for (int mf = 0; mf < 4; ++mf)
#pragma unroll
            for (int nf = 0; nf < 4; ++nf) {
                acc[mf][nf] = __builtin_amdgcn_mfma_f32_16x16x32_bf16(ah[mf], bh[nf], acc[mf][nf], 0, 0, 0);
                acc[mf][nf] = __builtin_amdgcn_mfma_f32_16x16x32_bf16(al[mf], bh[nf], acc[mf][nf], 0, 0, 0);
                acc[mf][nf] = __builtin_amdgcn_mfma_f32_16x16x32_bf16(ah[mf], bo[nf], acc[mf][nf], 0, 0, 0);
            }
        __syncthreads();
    }

    int q4 = (lane >> 4) * 4;
#pragma unroll
    for (int nf = 0; nf < 4; ++nf) {
        int n_abs = n_blk * 128 + wc * 64 + nf * 16 + r15;
        bool left = n_abs < 256;
        float bb = left ? bl[n_abs] : br[n_abs - 256];
        int col = n_abs & 255;
#pragma unroll
        for (int mf = 0; mf < 4; ++mf) {
            int rowb = m0 + wr * 64 + mf * 16 + q4;
#pragma unroll
            for (int j = 0; j < 4; ++j) {
                int row = rowb + j;
                if (row < M) {
                    float v = acc[mf][nf][j] + bb;
                    if (left) Af[(size_t)row * 256 + col] = (_Float16)v;
                    else      Bf[(size_t)row * 256 + col] = (_Float16)v;
                }
            }
        }
    }
}

// ==================== binned CSR build (both layers, grid.y = layer) ====================
__global__ __launch_bounds__(256) void bucket_hist(const int* __restrict__ dst0,
                                                   const int* __restrict__ dst1,
                                                   int Ereal, int EP, int nb,
                                                   int* __restrict__ bkt_count) {
    __shared__ int hist[NB_MAX];
    int l = blockIdx.y;
    for (int i = threadIdx.x; i < nb; i += 256) hist[i] = 0;
    __syncthreads();
    const int* dst = l ? dst1 : dst0;
    int c0 = blockIdx.x * 4096;
#pragma unroll
    for (int k = 0; k < 16; ++k) {
        int i = c0 + k * 256 + threadIdx.x;
        if (i < EP) {
            int d = (i < Ereal) ? dst[i] : (i - Ereal);
            atomicAdd(&hist[d >> 8], 1);
        }
    }
    __syncthreads();
    for (int i = threadIdx.x; i < nb; i += 256)
        if (hist[i]) atomicAdd(&bkt_count[l * nb + i], hist[i]);
}

__global__ __launch_bounds__(512) void bscan(const int* __restrict__ bkt_count,
                                             int* __restrict__ bkt_base,
                                             int* __restrict__ bkt_next,
                                             int* __restrict__ rowptr,
                                             int nb, int N, int EP) {
    __shared__ int sh[512];
    int t = threadIdx.x, l = t >> 8, i = t & 255;
    int v = (i < nb) ? bkt_count[l * nb + i] : 0;
    sh[t] = v;
    __syncthreads();
    for (int o = 1; o < 256; o <<= 1) {
        int x = (i >= o) ? sh[t - o] : 0;
        __syncthreads();
        sh[t] += x;
        __syncthreads();
    }
    if (i < nb) {
        int b = sh[t] - v;   // exclusive
        bkt_base[l * nb + i] = b;
        bkt_next[l * nb + i] = b;
    }
    if (i == 0) rowptr[(size_t)l * (N + 1) + N] = EP;
}

__global__ __launch_bounds__(256) void binA(const int* __restrict__ src0,
                                            const int* __restrict__ dst0,
                                            const int* __restrict__ src1,
                                            const int* __restrict__ dst1,
                                            int Ereal, int EP, int nb,
                                            int* __restrict__ bkt_next,
                                            unsigned* __restrict__ bucketBuf) {
    __shared__ int hist[NB_MAX], base[NB_MAX], ofs[NB_MAX];
    int l = blockIdx.y;
    for (int i = threadIdx.x; i < nb; i += 256) hist[i] = 0;
    __syncthreads();
    const int* src = l ? src1 : src0;
    const int* dst = l ? dst1 : dst0;
    int c0 = blockIdx.x * 4096;
    int dcache[16];
#pragma unroll
    for (int k = 0; k < 16; ++k) {
        int i = c0 + k * 256 + threadIdx.x;
        int d = -1;
        if (i < EP) d = (i < Ereal) ? dst[i] : (i - Ereal);
        dcache[k] = d;
        if (d >= 0) atomicAdd(&hist[d >> 8], 1);
    }
    __syncthreads();
    for (int i = threadIdx.x; i < nb; i += 256) {
        base[i] = hist[i] ? atomicAdd(&bkt_next[l * nb + i], hist[i]) : 0;
        ofs[i] = 0;
    }
    __syncthreads();
#pragma unroll
    for (int k = 0; k < 16; ++k) {
        int i = c0 + k * 256 + threadIdx.x;
        int d = dcache[k];
        if (d >= 0) {
            int s = (i < Ereal) ? src[i] : (i - Ereal);
            int b = d >> 8;
            int pos = base[b] + atomicAdd(&ofs[b], 1);
            bucketBuf[(size_t)l * EP + pos] = (unsigned)s | ((unsigned)(d & 255) << 16);
        }
    }
}

__global__ __launch_bounds__(256) void binB(const unsigned* __restrict__ bucketBuf,
                                            const int* __restrict__ bkt_base,
                                            const int* __restrict__ bkt_count,
                                            int nb, int N, int EP,
                                            int* __restrict__ rowptr,
                                            int* __restrict__ csr) {
    __shared__ int hist[256], sh[256], nxt[256];
    int b = blockIdx.x, l = blockIdx.y, t = threadIdx.x;
    int base = bkt_base[l * nb + b];
    int cnt = bkt_count[l * nb + b];
    hist[t] = 0;
    __syncthreads();
    const unsigned* buf = bucketBuf + (size_t)l * EP + base;
    for (int i = t; i < cnt; i += 256)
        atomicAdd(&hist[buf[i] >> 16], 1);
    __syncthreads();
    int h = hist[t];
    sh[t] = h;
    __syncthreads();
    for (int o = 1; o < 256; o <<= 1) {
        int x = (t >= o) ? sh[t - o] : 0;
        __syncthreads();
        sh[t] += x;
        __syncthreads();
    }
    int excl = sh[t] - h;
    nxt[t] = excl;
    int d = b * 256 + t;
    if (d < N) rowptr[(size_t)l * (N + 1) + d] = base + excl;
    __syncthreads();
    for (int i = t; i < cnt; i += 256) {
        unsigned v = buf[i];
        int pos = base + atomicAdd(&nxt[v >> 16], 1);
        csr[(size_t)l * EP + pos] = (int)(v & 0xFFFFu);
    }
}

// ---- fused GATv2 node pass: one wave64 per node, 32-lane groups x 2 edges,
//      per-group online softmax + single cross-group merge. fp16 xl/xr.
//      MODE 0: write bf16 hi/lo split; MODE 1: fused 256->2 head + log_softmax.
template <int MODE>
__global__ __launch_bounds__(256) void gat_node(const _Float16* __restrict__ xl,
                                                const _Float16* __restrict__ xr,
                                                const int* __restrict__ rowptr,
                                                const int* __restrict__ csr_src,
                                                const float* __restrict__ att,
                                                const float* __restrict__ bias,
                                                unsigned short* __restrict__ yhi,
                                                unsigned short* __restrict__ ylo,
                                                const float* __restrict__ Wlin,
                                                const float* __restrict__ blin,
                                                float* __restrict__ out, int n) {
    int wid = (int)((blockIdx.x * (size_t)blockDim.x + threadIdx.x) >> 6);
    int lane = threadIdx.x & 63;
    if (wid >= n) return;
    int g = lane >> 5, li = lane & 31;                 // group, lane-in-group
    int beg = rowptr[wid], end = rowptr[wid + 1];

    f16x8 xr8 = ((const f16x8*)(xr + (size_t)wid * 256))[li];  // ch 8li..8li+7
    float4 t0 = ((const float4*)att)[li * 2];
    float4 t1 = ((const float4*)att)[li * 2 + 1];
    f16x2 t01 = {(f16)t0.x, (f16)t0.y}, t23 = {(f16)t0.z, (f16)t0.w};
    f16x2 t45 = {(f16)t1.x, (f16)t1.y}, t67 = {(f16)t1.z, (f16)t1.w};
    const f16 ng = (f16)NEG;
    const f16x8 n8 = {ng, ng, ng, ng, ng, ng, ng, ng};

    float m = -INFINITY, ssum = 0.f;
    float acc[8] = {0.f, 0.f, 0.f, 0.f, 0.f, 0.f, 0.f, 0.f};

    auto step = [&](f16x8 a, bool valid) {
        f16x8 v = a + xr8;
        f16x8 lk = __builtin_elementwise_max(v, v * n8);
#ifdef HAVE_FDOT2
        f16x2 q;
        q[0] = lk[0]; q[1] = lk[1];
        float dot = __builtin_amdgcn_fdot2(q, t01, 0.f, false);
        q[0] = lk[2]; q[1] = lk[3];
        dot = __builtin_amdgcn_fdot2(q, t23, dot, false);
        q[0] = lk[4]; q[1] = lk[5];
        dot = __builtin_amdgcn_fdot2(q, t45, dot, false);
        q[0] = lk[6]; q[1] = lk[7];
        dot = __builtin_amdgcn_fdot2(q, t67, dot, false);
#else
        float dot = (float)lk[0] * (float)t01[0] + (float)lk[1] * (float)t01[1] +
                    (float)lk[2] * (float)t23[0] + (float)lk[3] * (float)t23[1] +
                    (float)lk[4] * (float)t45[0] + (float)lk[5] * (float)t45[1] +
                    (float)lk[6] * (float)t67[0] + (float)lk[7] * (float)t67[1];
#endif
#pragma unroll
        for (int off = 16; off > 0; off >>= 1) dot += __shfl_xor(dot, off);
        if (valid) {
            if (dot > m + 8.f) {            // rare after warm-up
                float sc = __expf(m - dot); // m=-inf first edge -> 0
                ssum = ssum * sc + 1.f;
#pragma unroll
                for (int i = 0; i < 8; ++i) acc[i] = acc[i] * sc + (float)a[i];
                m = dot;
            } else {                        // p bounded by e^8
                float p = __expf(dot - m);
                ssum += p;
#pragma unroll
                for (int i = 0; i < 8; ++i) acc[i] += p * (float)a[i];
            }
        }
    };

    int j = beg;
    for (; j + 8 <= end; j += 8) {          // 4 pairs in flight
        f16x8 a[4];
#pragma unroll
        for (int u = 0; u < 4; ++u) {
            int s = csr_src[j + 2 * u + g];
            a[u] = ((const f16x8*)(xl + (size_t)s * 256))[li];
        }
#pragma unroll
        for (int u = 0; u < 4; ++u) step(a[u], true);
    }
    for (; j < end; j += 2) {
        int e = j + g;
        int s = csr_src[e < end ? e : end - 1];
        f16x8 a = ((const f16x8*)(xl + (size_t)s * 256))[li];
        step(a, e < end);
    }

    // ---- merge the two group states (all lanes end with identical merged values)
    float m_o = __shfl_xor(m, 32);
    float s_o = __shfl_xor(ssum, 32);
    float ms = fmaxf(m, m_o);
    float wa = __expf(m - ms), wb = __expf(m_o - ms);
    float inv = 1.f / (ssum * wa + s_o * wb);
    float4 bb0 = ((const float4*)bias)[li * 2];
    float4 bb1 = ((const float4*)bias)[li * 2 + 1];
    float bbv[8] = {bb0.x, bb0.y, bb0.z, bb0.w, bb1.x, bb1.y, bb1.z, bb1.w};
    float o8[8];
#pragma unroll
    for (int i = 0; i < 8; ++i) {
        float ao = __shfl_xor(acc[i], 32);
        float o = (acc[i] * wa + ao * wb) * inv + bbv[i];
        o8[i] = o > 0.f ? o : NEG * o;
    }

    if (MODE == 0) {
        u16x8 w;
        if (g == 0) {
#pragma unroll
            for (int i = 0; i < 8; ++i) w[i] = f2bf(o8[i]);
            ((u16x8*)(yhi + (size_t)wid * 256))[li] = w;
        } else {
#pragma unroll
            for (int i = 0; i < 8; ++i) {
                unsigned short h = f2bf(o8[i]);
                w[i] = f2bf(o8[i] - bf2f(h));
            }
            ((u16x8*)(ylo + (size_t)wid * 256))[li] = w;
        }
    } else {
        float z0 = 0.f, z1 = 0.f;
#pragma unroll
        for (int p = 0; p < 4; ++p) {
            float4 q = ((const float4*)Wlin)[li * 4 + p];   // ch 8li+2p, 8li+2p+1
            z0 += o8[2 * p] * q.x + o8[2 * p + 1] * q.z;
            z1 += o8[2 * p] * q.y + o8[2 * p + 1] * q.w;
        }
#pragma unroll
        for (int off = 16; off > 0; off >>= 1) {
            z0 += __shfl_xor(z0, off);
            z1 += __shfl_xor(z1, off);
        }
        if (lane == 0) {
            z0 += blin[0];
            z1 += blin[1];
            float mx = fmaxf(z0, z1);
            float lse = mx + logf(expf(z0 - mx) + expf(z1 - mx));
            out[(size_t)wid * 2 + 0] = z0 - lse;
            out[(size_t)wid * 2 + 1] = z1 - lse;
        }
    }
}

extern "C" void kernel_launch(void* const* d_in, const int* in_sizes, int n_in,
                              void* d_out, int out_size, void* d_ws, size_t ws_size,
                              hipStream_t stream) {
    const float* fts   = (const float*)d_in[0];
    const int*   graph = (const int*)d_in[1];
    const float* Wl0 = (const float*)d_in[2];
    const float* Wr0 = (const float*)d_in[3];
    const float* bl0 = (const float*)d_in[4];
    const float* br0 = (const float*)d_in[5];
    const float* att0 = (const float*)d_in[6];
    const float* b0  = (const float*)d_in[7];
    const float* Wl1 = (const float*)d_in[8];
    const float* Wr1 = (const float*)d_in[9];
    const float* bl1 = (const float*)d_in[10];
    const float* br1 = (const float*)d_in[11];
    const float* att1 = (const float*)d_in[12];
    const float* b1  = (const float*)d_in[13];
    const float* Wlin = (const float*)d_in[14];
    const float* blin = (const float*)d_in[15];

    int N = out_size / 2;                                   // 40000
    long T = in_sizes[0] / ((long)N * 256);                 // 4
    long E = in_sizes[1] / (2 * T);                         // 640000
    int EP = (int)E + N;
    int nb = (N + 255) / 256;                               // 157 buckets

    char* ws = (char*)d_ws;
    size_t off = 0;
    auto alloc = [&](size_t bytes) -> void* {
        void* p = ws + off;
        off += (bytes + 255) & ~(size_t)255;
        return p;
    };
    _Float16* Af = (_Float16*)alloc((size_t)N * 256 * 2);   // xl (fp16)
    _Float16* Bf = (_Float16*)alloc((size_t)N * 256 * 2);   // xr (fp16)
    unsigned short* Xhi  = (unsigned short*)alloc((size_t)N * 256 * 2);
    unsigned short* Xlo  = (unsigned short*)alloc((size_t)N * 256 * 2);
    unsigned short* Whi  = (unsigned short*)alloc((size_t)2 * 512 * 256 * 2);
    unsigned short* Wlo  = (unsigned short*)alloc((size_t)2 * 512 * 256 * 2);
    int* rowptr    = (int*)alloc((size_t)2 * (N + 1) * 4);
    int* csr       = (int*)alloc((size_t)2 * EP * 4);
    unsigned* bucketBuf = (unsigned*)alloc((size_t)2 * EP * 4);
    int* bkt_count = (int*)alloc((size_t)2 * nb * 4);
    int* bkt_base  = (int*)alloc((size_t)2 * nb * 4);
    int* bkt_next  = (int*)alloc((size_t)2 * nb * 4);
    (void)ws_size; (void)n_in;

    int conv_blocks = (N * 256 / 4 + 255) / 256;
    int gemm_blocks = ((N + 127) / 128) * 4;
    dim3 chunk_grid((EP + 4095) / 4096, 2);
    int node_blocks = (N + 3) / 4;

    const int* src0 = graph;
    const int* dst0 = graph + E;
    const int* srcL = graph + (T - 1) * 2 * E;
    const int* dstL = graph + (T - 1) * 2 * E + E;

    // ---------- upfront: converts + binned CSR build for BOTH layers ----------
    convert_x<<<conv_blocks, 256, 0, stream>>>(fts, Xhi, Xlo, N * 256 / 4);
    convert_w2<<<dim3(512, 2), 256, 0, stream>>>(Wl0, Wr0, Wl1, Wr1, Whi, Wlo);
    hipMemsetAsync(bkt_count, 0, (size_t)2 * nb * 4, stream);
    bucket_hist<<<chunk_grid, 256, 0, stream>>>(dst0, dstL, (int)E, EP, nb, bkt_count);
    bscan<<<1, 512, 0, stream>>>(bkt_count, bkt_base, bkt_next, rowptr, nb, N, EP);
    binA<<<chunk_grid, 256, 0, stream>>>(src0, dst0, srcL, dstL, (int)E, EP, nb,
                                         bkt_next, bucketBuf);
    binB<<<dim3(nb, 2), 256, 0, stream>>>(bucketBuf, bkt_base, bkt_count, nb, N, EP,
                                          rowptr, csr);

    // ---------- layer 0 ----------
    mfma_gemm<<<gemm_blocks, 256, 0, stream>>>(Xhi, Xlo, Whi, Wlo, bl0, br0, Af, Bf, N);
    gat_node<0><<<node_blocks, 256, 0, stream>>>(Af, Bf, rowptr, csr, att0, b0,
                                                 Xhi, Xlo, nullptr, nullptr, nullptr, N);

    // ---------- layer 1 ----------
    mfma_gemm<<<gemm_blocks, 256, 0, stream>>>(Xhi, Xlo, Whi + (size_t)512 * 256,
                                               Wlo + (size_t)512 * 256, bl1, br1, Af, Bf, N);
    gat_node<1><<<node_blocks, 256, 0, stream>>>(Af, Bf, rowptr + (N + 1), csr + EP, att1, b1,
                                                 nullptr, nullptr, Wlin, blin, (float*)d_out, N);
}

// Round 9
// 296.661 us; speedup vs baseline: 18.4545x; 1.0150x over previous
//
#include <hip/hip_runtime.h>
#include <hip/hip_bf16.h>
#include <math.h>

#define NEG 0.2f
#define NB_MAX 256

typedef short bf16x8 __attribute__((ext_vector_type(8)));
typedef float f32x4 __attribute__((ext_vector_type(4)));
typedef _Float16 f16;
typedef _Float16 f16x2 __attribute__((ext_vector_type(2)));
typedef _Float16 f16x8 __attribute__((ext_vector_type(8)));
typedef unsigned short u16x8 __attribute__((ext_vector_type(8)));

#if defined(__has_builtin)
#if __has_builtin(__builtin_amdgcn_fdot2)
#define HAVE_FDOT2 1
#endif
#endif

typedef __attribute__((address_space(3))) void as3_void;
typedef __attribute__((address_space(1))) const void as1_void;

__device__ __forceinline__ void gl_lds16(const void* g, void* l) {
    __builtin_amdgcn_global_load_lds((as1_void*)g, (as3_void*)l, 16, 0, 0);
}

__device__ __forceinline__ unsigned short f2bf(float x) {
    unsigned u = __float_as_uint(x);
    unsigned r = (u + 0x7fffu + ((u >> 16) & 1u)) >> 16;
    return (unsigned short)r;
}
__device__ __forceinline__ float bf2f(unsigned short b) {
    return __uint_as_float(((unsigned)b) << 16);
}

// ---- build transposed combined weights for BOTH layers in one launch (grid.y = layer)
__global__ __launch_bounds__(256) void convert_w2(const float* __restrict__ Wl0,
                                                  const float* __restrict__ Wr0,
                                                  const float* __restrict__ Wl1,
                                                  const float* __restrict__ Wr1,
                                                  unsigned short* __restrict__ Whi,
                                                  unsigned short* __restrict__ Wlo) {
    int l = blockIdx.y;
    int idx = blockIdx.x * blockDim.x + threadIdx.x;   // n*256 + k
    int n = idx >> 8, k = idx & 255;
    const float* Wl = l ? Wl1 : Wl0;
    const float* Wr = l ? Wr1 : Wr0;
    float v = (n < 256) ? Wl[k * 256 + n] : Wr[k * 256 + (n - 256)];
    unsigned short h = f2bf(v);
    size_t off = (size_t)l * 512 * 256 + idx;
    Whi[off] = h;
    Wlo[off] = f2bf(v - bf2f(h));
}

// ---- stage one 128-row x 32-k tile (hi|lo packed as [128][64] bf16, 16KB) into LDS
//      via global_load_lds from pre-split arrays; source pre-swizzled.
__device__ __forceinline__ void stage32(const unsigned short* __restrict__ hi,
                                        const unsigned short* __restrict__ lo,
                                        int row_base, int row_max, int k0,
                                        char* lds, int wave, int lane) {
#pragma unroll
    for (int q = 0; q < 4; ++q) {
        int off = q * 4096 + wave * 1024 + lane * 16;  // linear byte offset incl. lane
        int row = off >> 7;                            // 128 B per row
        int slot = (off >> 4) & 7;                     // 16B slot within row
        int se = slot ^ (row & 7);                     // swizzled global chunk
        int grow = row_base + row;
        if (grow > row_max) grow = row_max;
        const unsigned short* g = (se < 4)
            ? hi + (size_t)grow * 256 + k0 + se * 8
            : lo + (size_t)grow * 256 + k0 + (se - 4) * 8;
        gl_lds16(g, lds + q * 4096 + wave * 1024);     // wave-uniform LDS base
    }
}

// ---- stage same tile from an fp32 source: reg-staged load + in-register hi/lo
//      split + ds_write_b64 to the same swizzled layout.
__device__ __forceinline__ void stage32_f32(const float* __restrict__ X,
                                            int row_base, int row_max, int k0,
                                            char* lds, int tid) {
#pragma unroll
    for (int u = 0; u < 4; ++u) {
        int unit = u * 256 + tid;                      // (row, half-slot h)
        int r = unit >> 3, h = unit & 7;               // h covers k = 4h..4h+3
        int grow = row_base + r;
        if (grow > row_max) grow = row_max;
        float4 v = *(const float4*)(X + (size_t)grow * 256 + k0 + h * 4);
        unsigned short hx = f2bf(v.x), hy = f2bf(v.y), hz = f2bf(v.z), hw = f2bf(v.w);
        uint2 hiw, low;
        hiw.x = (unsigned)hx | ((unsigned)hy << 16);
        hiw.y = (unsigned)hz | ((unsigned)hw << 16);
        low.x = (unsigned)f2bf(v.x - bf2f(hx)) | ((unsigned)f2bf(v.y - bf2f(hy)) << 16);
        low.y = (unsigned)f2bf(v.z - bf2f(hz)) | ((unsigned)f2bf(v.w - bf2f(hw)) << 16);
        int sub = (h & 1) * 8;
        int shi = ((h >> 1) ^ (r & 7)) << 4;
        int slo = ((4 + (h >> 1)) ^ (r & 7)) << 4;
        *(uint2*)(lds + r * 128 + shi + sub) = hiw;
        *(uint2*)(lds + r * 128 + slo + sub) = low;
    }
}

// ---- split-bf16 MFMA GEMM: [M,256] x [256,512] -> Af f16 (cols 0-255,+bl), Bf f16 (+br)
//      SRC=0: X from fp32 (reg-staged split); SRC=1: X from pre-split hi/lo arrays.
//      XCD-aware block remap: 4 n-blocks of one m-tile share an XCD (L2 reuse of X).
template <int SRC>
__global__ __launch_bounds__(256) void mfma_gemm(const float* __restrict__ Xf,
                                                 const unsigned short* __restrict__ Xhi,
                                                 const unsigned short* __restrict__ Xlo,
                                                 const unsigned short* __restrict__ Wthi,
                                                 const unsigned short* __restrict__ Wtlo,
                                                 const float* __restrict__ bl,
                                                 const float* __restrict__ br,
                                                 _Float16* __restrict__ Af,
                                                 _Float16* __restrict__ Bf, int M) {
    __shared__ char smem[65536];                      // 2 bufs x (A 16K + B 16K)
    int Mb = (M + 127) >> 7;
    int b = blockIdx.x;
    int cx = b & 7, rr = b >> 3;                      // cx = XCD slot
    int m_blk = (rr >> 2) * 8 + cx;
    int n_blk = rr & 3;
    if (m_blk >= Mb) return;
    int tid = threadIdx.x;
    int wave = tid >> 6, lane = tid & 63;
    int m0 = m_blk * 128;
    int wr = wave >> 1, wc = wave & 1;
    int r15 = lane & 15, c = lane >> 4;

    f32x4 acc[4][4];
#pragma unroll
    for (int mf = 0; mf < 4; ++mf)
#pragma unroll
        for (int nf = 0; nf < 4; ++nf) acc[mf][nf] = (f32x4){0.f, 0.f, 0.f, 0.f};

    auto stageX = [&](int k0, char* dst) {
        if constexpr (SRC == 0) stage32_f32(Xf, m0, M - 1, k0, dst, tid);
        else                    stage32(Xhi, Xlo, m0, M - 1, k0, dst, wave, lane);
    };

    stageX(0, smem);
    stage32(Wthi, Wtlo, n_blk * 128, 511, 0, smem + 16384, wave, lane);
    __syncthreads();

    for (int t = 0; t < 8; ++t) {
        int buf = t & 1;
        if (t < 7) {
            char* nb = smem + (buf ^ 1) * 32768;
            stageX((t + 1) * 32, nb);
            stage32(Wthi, Wtlo, n_blk * 128, 511, (t + 1) * 32, nb + 16384, wave, lane);
        }
        const char* At = smem + buf * 32768;
        const char* Bt = At + 16384;
        bf16x8 ah[4], al[4], bh[4], bo[4];
#pragma unroll
        for (int f = 0; f < 4; ++f) {
            int ar = wr * 64 + f * 16 + r15;
            ah[f] = *(const bf16x8*)(At + ar * 128 + ((c ^ (ar & 7)) << 4));
            al[f] = *(const bf16x8*)(At + ar * 128 + (((4 + c) ^ (ar & 7)) << 4));
            int br_ = wc * 64 + f * 16 + r15;
            bh[f] = *(const bf16x8*)(Bt + br_ * 128 + ((c ^ (br_ & 7)) << 4));
            bo[f] = *(const bf16x8*)(Bt + br_ * 128 + (((4 + c) ^ (br_ & 7)) << 4));
        }
#pragma unroll
        for (int mf = 0; mf < 4; ++mf)
#pragma unroll
            for (int nf = 0; nf < 4; ++nf) {
                acc[mf][nf] = __builtin_amdgcn_mfma_f32_16x16x32_bf16(ah[mf], bh[nf], acc[mf][nf], 0, 0, 0);
                acc[mf][nf] = __builtin_amdgcn_mfma_f32_16x16x32_bf16(al[mf], bh[nf], acc[mf][nf], 0, 0, 0);
                acc[mf][nf] = __builtin_amdgcn_mfma_f32_16x16x32_bf16(ah[mf], bo[nf], acc[mf][nf], 0, 0, 0);
            }
        __syncthreads();
    }

    int q4 = (lane >> 4) * 4;
#pragma unroll
    for (int nf = 0; nf < 4; ++nf) {
        int n_abs = n_blk * 128 + wc * 64 + nf * 16 + r15;
        bool left = n_abs < 256;
        float bb = left ? bl[n_abs] : br[n_abs - 256];
        int col = n_abs & 255;
#pragma unroll
        for (int mf = 0; mf < 4; ++mf) {
            int rowb = m0 + wr * 64 + mf * 16 + q4;
#pragma unroll
            for (int j = 0; j < 4; ++j) {
                int row = rowb + j;
                if (row < M) {
                    float v = acc[mf][nf][j] + bb;
                    if (left) Af[(size_t)row * 256 + col] = (_Float16)v;
                    else      Bf[(size_t)row * 256 + col] = (_Float16)v;
                }
            }
        }
    }
}

// ==================== binned CSR build (both layers, grid.y = layer) ====================
__global__ __launch_bounds__(256) void bucket_hist(const int* __restrict__ dst0,
                                                   const int* __restrict__ dst1,
                                                   int Ereal, int EP, int nb,
                                                   int* __restrict__ bkt_count) {
    __shared__ int hist[NB_MAX];
    int l = blockIdx.y;
    for (int i = threadIdx.x; i < nb; i += 256) hist[i] = 0;
    __syncthreads();
    const int* dst = l ? dst1 : dst0;
    int c0 = blockIdx.x * 4096;
#pragma unroll
    for (int k = 0; k < 16; ++k) {
        int i = c0 + k * 256 + threadIdx.x;
        if (i < EP) {
            int d = (i < Ereal) ? dst[i] : (i - Ereal);
            atomicAdd(&hist[d >> 8], 1);
        }
    }
    __syncthreads();
    for (int i = threadIdx.x; i < nb; i += 256)
        if (hist[i]) atomicAdd(&bkt_count[l * nb + i], hist[i]);
}

__global__ __launch_bounds__(512) void bscan(const int* __restrict__ bkt_count,
                                             int* __restrict__ bkt_base,
                                             int* __restrict__ bkt_next,
                                             int* __restrict__ rowptr,
                                             int nb, int N, int EP) {
    __shared__ int sh[512];
    int t = threadIdx.x, l = t >> 8, i = t & 255;
    int v = (i < nb) ? bkt_count[l * nb + i] : 0;
    sh[t] = v;
    __syncthreads();
    for (int o = 1; o < 256; o <<= 1) {
        int x = (i >= o) ? sh[t - o] : 0;
        __syncthreads();
        sh[t] += x;
        __syncthreads();
    }
    if (i < nb) {
        int b = sh[t] - v;   // exclusive
        bkt_base[l * nb + i] = b;
        bkt_next[l * nb + i] = b;
    }
    if (i == 0) rowptr[(size_t)l * (N + 1) + N] = EP;
}

__global__ __launch_bounds__(256) void binA(const int* __restrict__ src0,
                                            const int* __restrict__ dst0,
                                            const int* __restrict__ src1,
                                            const int* __restrict__ dst1,
                                            int Ereal, int EP, int nb,
                                            int* __restrict__ bkt_next,
                                            unsigned* __restrict__ bucketBuf) {
    __shared__ int hist[NB_MAX], base[NB_MAX], ofs[NB_MAX];
    int l = blockIdx.y;
    for (int i = threadIdx.x; i < nb; i += 256) hist[i] = 0;
    __syncthreads();
    const int* src = l ? src1 : src0;
    const int* dst = l ? dst1 : dst0;
    int c0 = blockIdx.x * 4096;
    int dcache[16];
#pragma unroll
    for (int k = 0; k < 16; ++k) {
        int i = c0 + k * 256 + threadIdx.x;
        int d = -1;
        if (i < EP) d = (i < Ereal) ? dst[i] : (i - Ereal);
        dcache[k] = d;
        if (d >= 0) atomicAdd(&hist[d >> 8], 1);
    }
    __syncthreads();
    for (int i = threadIdx.x; i < nb; i += 256) {
        base[i] = hist[i] ? atomicAdd(&bkt_next[l * nb + i], hist[i]) : 0;
        ofs[i] = 0;
    }
    __syncthreads();
#pragma unroll
    for (int k = 0; k < 16; ++k) {
        int i = c0 + k * 256 + threadIdx.x;
        int d = dcache[k];
        if (d >= 0) {
            int s = (i < Ereal) ? src[i] : (i - Ereal);
            int b = d >> 8;
            int pos = base[b] + atomicAdd(&ofs[b], 1);
            bucketBuf[(size_t)l * EP + pos] = (unsigned)s | ((unsigned)(d & 255) << 16);
        }
    }
}

__global__ __launch_bounds__(256) void binB(const unsigned* __restrict__ bucketBuf,
                                            const int* __restrict__ bkt_base,
                                            const int* __restrict__ bkt_count,
                                            int nb, int N, int EP,
                                            int* __restrict__ rowptr,
                                            int* __restrict__ csr) {
    __shared__ int hist[256], sh[256], nxt[256];
    int b = blockIdx.x, l = blockIdx.y, t = threadIdx.x;
    int base = bkt_base[l * nb + b];
    int cnt = bkt_count[l * nb + b];
    hist[t] = 0;
    __syncthreads();
    const unsigned* buf = bucketBuf + (size_t)l * EP + base;
    for (int i = t; i < cnt; i += 256)
        atomicAdd(&hist[buf[i] >> 16], 1);
    __syncthreads();
    int h = hist[t];
    sh[t] = h;
    __syncthreads();
    for (int o = 1; o < 256; o <<= 1) {
        int x = (t >= o) ? sh[t - o] : 0;
        __syncthreads();
        sh[t] += x;
        __syncthreads();
    }
    int excl = sh[t] - h;
    nxt[t] = excl;
    int d = b * 256 + t;
    if (d < N) rowptr[(size_t)l * (N + 1) + d] = base + excl;
    __syncthreads();
    for (int i = t; i < cnt; i += 256) {
        unsigned v = buf[i];
        int pos = base + atomicAdd(&nxt[v >> 16], 1);
        csr[(size_t)l * EP + pos] = (int)(v & 0xFFFFu);
    }
}

// ---- fused GATv2 node pass: one wave64 per node, 32-lane groups x 2 edges,
//      8 gathers in flight, per-group online softmax + single cross-group merge.
template <int MODE>
__global__ __launch_bounds__(256) void gat_node(const _Float16* __restrict__ xl,
                                                const _Float16* __restrict__ xr,
                                                const int* __restrict__ rowptr,
                                                const int* __restrict__ csr_src,
                                                const float* __restrict__ att,
                                                const float* __restrict__ bias,
                                                unsigned short* __restrict__ yhi,
                                                unsigned short* __restrict__ ylo,
                                                const float* __restrict__ Wlin,
                                                const float* __restrict__ blin,
                                                float* __restrict__ out, int n) {
    int wid = (int)((blockIdx.x * (size_t)blockDim.x + threadIdx.x) >> 6);
    int lane = threadIdx.x & 63;
    if (wid >= n) return;
    int g = lane >> 5, li = lane & 31;                 // group, lane-in-group
    int beg = rowptr[wid], end = rowptr[wid + 1];

    f16x8 xr8 = ((const f16x8*)(xr + (size_t)wid * 256))[li];  // ch 8li..8li+7
    float4 t0 = ((const float4*)att)[li * 2];
    float4 t1 = ((const float4*)att)[li * 2 + 1];
    f16x2 t01 = {(f16)t0.x, (f16)t0.y}, t23 = {(f16)t0.z, (f16)t0.w};
    f16x2 t45 = {(f16)t1.x, (f16)t1.y}, t67 = {(f16)t1.z, (f16)t1.w};
    const f16 ng = (f16)NEG;
    const f16x8 n8 = {ng, ng, ng, ng, ng, ng, ng, ng};

    float m = -INFINITY, ssum = 0.f;
    float acc[8] = {0.f, 0.f, 0.f, 0.f, 0.f, 0.f, 0.f, 0.f};

    auto step = [&](f16x8 a, bool valid) {
        f16x8 v = a + xr8;
        f16x8 lk = __builtin_elementwise_max(v, v * n8);
#ifdef HAVE_FDOT2
        f16x2 q;
        q[0] = lk[0]; q[1] = lk[1];
        float dot = __builtin_amdgcn_fdot2(q, t01, 0.f, false);
        q[0] = lk[2]; q[1] = lk[3];
        dot = __builtin_amdgcn_fdot2(q, t23, dot, false);
        q[0] = lk[4]; q[1] = lk[5];
        dot = __builtin_amdgcn_fdot2(q, t45, dot, false);
        q[0] = lk[6]; q[1] = lk[7];
        dot = __builtin_amdgcn_fdot2(q, t67, dot, false);
#else
        float dot = (float)lk[0] * (float)t01[0] + (float)lk[1] * (float)t01[1] +
                    (float)lk[2] * (float)t23[0] + (float)lk[3] * (float)t23[1] +
                    (float)lk[4] * (float)t45[0] + (float)lk[5] * (float)t45[1] +
                    (float)lk[6] * (float)t67[0] + (float)lk[7] * (float)t67[1];
#endif
#pragma unroll
        for (int off = 16; off > 0; off >>= 1) dot += __shfl_xor(dot, off);
        if (valid) {
            if (dot > m + 8.f) {            // rare after warm-up
                float sc = __expf(m - dot); // m=-inf first edge -> 0
                ssum = ssum * sc + 1.f;
#pragma unroll
                for (int i = 0; i < 8; ++i) acc[i] = acc[i] * sc + (float)a[i];
                m = dot;
            } else {                        // p bounded by e^8
                float p = __expf(dot - m);
                ssum += p;
#pragma unroll
                for (int i = 0; i < 8; ++i) acc[i] += p * (float)a[i];
            }
        }
    };

    int j = beg;
    for (; j + 16 <= end; j += 16) {        // 8 rows in flight per group
        f16x8 a[8];
#pragma unroll
        for (int u = 0; u < 8; ++u) {
            int s = csr_src[j + 2 * u + g];
            a[u] = ((const f16x8*)(xl + (size_t)s * 256))[li];
        }
#pragma unroll
        for (int u = 0; u < 8; ++u) step(a[u], true);
    }
    if (j + 8 <= end) {
        f16x8 a[4];
#pragma unroll
        for (int u = 0; u < 4; ++u) {
            int s = csr_src[j + 2 * u + g];
            a[u] = ((const f16x8*)(xl + (size_t)s * 256))[li];
        }
#pragma unroll
        for (int u = 0; u < 4; ++u) step(a[u], true);
        j += 8;
    }
    for (; j < end; j += 2) {
        int e = j + g;
        int s = csr_src[e < end ? e : end - 1];
        f16x8 a = ((const f16x8*)(xl + (size_t)s * 256))[li];
        step(a, e < end);
    }

    // ---- merge the two group states
    float m_o = __shfl_xor(m, 32);
    float s_o = __shfl_xor(ssum, 32);
    float ms = fmaxf(m, m_o);
    float wa = __expf(m - ms), wb = __expf(m_o - ms);
    float inv = 1.f / (ssum * wa + s_o * wb);
    float4 bb0 = ((const float4*)bias)[li * 2];
    float4 bb1 = ((const float4*)bias)[li * 2 + 1];
    float bbv[8] = {bb0.x, bb0.y, bb0.z, bb0.w, bb1.x, bb1.y, bb1.z, bb1.w};
    float o8[8];
#pragma unroll
    for (int i = 0; i < 8; ++i) {
        float ao = __shfl_xor(acc[i], 32);
        float o = (acc[i] * wa + ao * wb) * inv + bbv[i];
        o8[i] = o > 0.f ? o : NEG * o;
    }

    if (MODE == 0) {
        u16x8 w;
        if (g == 0) {
#pragma unroll
            for (int i = 0; i < 8; ++i) w[i] = f2bf(o8[i]);
            ((u16x8*)(yhi + (size_t)wid * 256))[li] = w;
        } else {
#pragma unroll
            for (int i = 0; i < 8; ++i) {
                unsigned short h = f2bf(o8[i]);
                w[i] = f2bf(o8[i] - bf2f(h));
            }
            ((u16x8*)(ylo + (size_t)wid * 256))[li] = w;
        }
    } else {
        float z0 = 0.f, z1 = 0.f;
#pragma unroll
        for (int p = 0; p < 4; ++p) {
            float4 q = ((const float4*)Wlin)[li * 4 + p];
            z0 += o8[2 * p] * q.x + o8[2 * p + 1] * q.z;
            z1 += o8[2 * p] * q.y + o8[2 * p + 1] * q.w;
        }
#pragma unroll
        for (int off = 16; off > 0; off >>= 1) {
            z0 += __shfl_xor(z0, off);
            z1 += __shfl_xor(z1, off);
        }
        if (lane == 0) {
            z0 += blin[0];
            z1 += blin[1];
            float mx = fmaxf(z0, z1);
            float lse = mx + logf(expf(z0 - mx) + expf(z1 - mx));
            out[(size_t)wid * 2 + 0] = z0 - lse;
            out[(size_t)wid * 2 + 1] = z1 - lse;
        }
    }
}

extern "C" void kernel_launch(void* const* d_in, const int* in_sizes, int n_in,
                              void* d_out, int out_size, void* d_ws, size_t ws_size,
                              hipStream_t stream) {
    const float* fts   = (const float*)d_in[0];
    const int*   graph = (const int*)d_in[1];
    const float* Wl0 = (const float*)d_in[2];
    const float* Wr0 = (const float*)d_in[3];
    const float* bl0 = (const float*)d_in[4];
    const float* br0 = (const float*)d_in[5];
    const float* att0 = (const float*)d_in[6];
    const float* b0  = (const float*)d_in[7];
    const float* Wl1 = (const float*)d_in[8];
    const float* Wr1 = (const float*)d_in[9];
    const float* bl1 = (const float*)d_in[10];
    const float* br1 = (const float*)d_in[11];
    const float* att1 = (const float*)d_in[12];
    const float* b1  = (const float*)d_in[13];
    const float* Wlin = (const float*)d_in[14];
    const float* blin = (const float*)d_in[15];

    int N = out_size / 2;                                   // 40000
    long T = in_sizes[0] / ((long)N * 256);                 // 4
    long E = in_sizes[1] / (2 * T);                         // 640000
    int EP = (int)E + N;
    int nb = (N + 255) / 256;                               // 157 buckets

    char* ws = (char*)d_ws;
    size_t off = 0;
    auto alloc = [&](size_t bytes) -> void* {
        void* p = ws + off;
        off += (bytes + 255) & ~(size_t)255;
        return p;
    };
    _Float16* Af = (_Float16*)alloc((size_t)N * 256 * 2);   // xl (fp16)
    _Float16* Bf = (_Float16*)alloc((size_t)N * 256 * 2);   // xr (fp16)
    unsigned short* Xhi  = (unsigned short*)alloc((size_t)N * 256 * 2);
    unsigned short* Xlo  = (unsigned short*)alloc((size_t)N * 256 * 2);
    unsigned short* Whi  = (unsigned short*)alloc((size_t)2 * 512 * 256 * 2);
    unsigned short* Wlo  = (unsigned short*)alloc((size_t)2 * 512 * 256 * 2);
    int* rowptr    = (int*)alloc((size_t)2 * (N + 1) * 4);
    int* csr       = (int*)alloc((size_t)2 * EP * 4);
    unsigned* bucketBuf = (unsigned*)alloc((size_t)2 * EP * 4);
    int* bkt_count = (int*)alloc((size_t)2 * nb * 4);
    int* bkt_base  = (int*)alloc((size_t)2 * nb * 4);
    int* bkt_next  = (int*)alloc((size_t)2 * nb * 4);
    (void)ws_size; (void)n_in;

    int Mb = (N + 127) / 128;                               // 313
    int gemm_blocks = ((Mb + 7) / 8) * 8 * 4;               // XCD-padded grid
    dim3 chunk_grid((EP + 4095) / 4096, 2);
    int node_blocks = (N + 3) / 4;

    const int* src0 = graph;
    const int* dst0 = graph + E;
    const int* srcL = graph + (T - 1) * 2 * E;
    const int* dstL = graph + (T - 1) * 2 * E + E;

    // ---------- upfront: weight convert + binned CSR build for BOTH layers ----------
    convert_w2<<<dim3(512, 2), 256, 0, stream>>>(Wl0, Wr0, Wl1, Wr1, Whi, Wlo);
    hipMemsetAsync(bkt_count, 0, (size_t)2 * nb * 4, stream);
    bucket_hist<<<chunk_grid, 256, 0, stream>>>(dst0, dstL, (int)E, EP, nb, bkt_count);
    bscan<<<1, 512, 0, stream>>>(bkt_count, bkt_base, bkt_next, rowptr, nb, N, EP);
    binA<<<chunk_grid, 256, 0, stream>>>(src0, dst0, srcL, dstL, (int)E, EP, nb,
                                         bkt_next, bucketBuf);
    binB<<<dim3(nb, 2), 256, 0, stream>>>(bucketBuf, bkt_base, bkt_count, nb, N, EP,
                                          rowptr, csr);

    // ---------- layer 0 (GEMM reads fts fp32 directly) ----------
    mfma_gemm<0><<<gemm_blocks, 256, 0, stream>>>(fts, nullptr, nullptr, Whi, Wlo,
                                                  bl0, br0, Af, Bf, N);
    gat_node<0><<<node_blocks, 256, 0, stream>>>(Af, Bf, rowptr, csr, att0, b0,
                                                 Xhi, Xlo, nullptr, nullptr, nullptr, N);

    // ---------- layer 1 ----------
    mfma_gemm<1><<<gemm_blocks, 256, 0, stream>>>(nullptr, Xhi, Xlo,
                                                  Whi + (size_t)512 * 256,
                                                  Wlo + (size_t)512 * 256, bl1, br1, Af, Bf, N);
    gat_node<1><<<node_blocks, 256, 0, stream>>>(Af, Bf, rowptr + (N + 1), csr + EP, att1, b1,
                                                 nullptr, nullptr, Wlin, blin, (float*)d_out, N);
}

// Round 10
// 235.072 us; speedup vs baseline: 23.2896x; 1.2620x over previous
//
#include <hip/hip_runtime.h>
#include <hip/hip_bf16.h>
#include <math.h>

#define NEG 0.2f
#define NB_MAX 256
#define CAP 5120

typedef float f32x4 __attribute__((ext_vector_type(4)));
typedef _Float16 f16;
typedef _Float16 f16x2 __attribute__((ext_vector_type(2)));
typedef _Float16 f16x8 __attribute__((ext_vector_type(8)));

#if defined(__has_builtin)
#if __has_builtin(__builtin_amdgcn_fdot2)
#define HAVE_FDOT2 1
#endif
#endif

typedef __attribute__((address_space(3))) void as3_void;
typedef __attribute__((address_space(1))) const void as1_void;

__device__ __forceinline__ void gl_lds16(const void* g, void* l) {
    __builtin_amdgcn_global_load_lds((as1_void*)g, (as3_void*)l, 16, 0, 0);
}

// ---- build transposed combined fp16 weights for BOTH layers; block (0,0) also
//      zeroes the bucket counters (runs before binA on the same stream).
__global__ __launch_bounds__(256) void convert_w2(const float* __restrict__ Wl0,
                                                  const float* __restrict__ Wr0,
                                                  const float* __restrict__ Wl1,
                                                  const float* __restrict__ Wr1,
                                                  _Float16* __restrict__ Wt,
                                                  int* __restrict__ bkt_next, int nb2) {
    int l = blockIdx.y;
    int idx = blockIdx.x * blockDim.x + threadIdx.x;   // n*256 + k
    int n = idx >> 8, k = idx & 255;
    const float* Wl = l ? Wl1 : Wl0;
    const float* Wr = l ? Wr1 : Wr0;
    float v = (n < 256) ? Wl[k * 256 + n] : Wr[k * 256 + (n - 256)];
    Wt[(size_t)l * 512 * 256 + idx] = (_Float16)v;
    if (blockIdx.x == 0 && l == 0)
        for (int i = threadIdx.x; i < nb2; i += 256) bkt_next[i] = 0;
}

// ---- stage one 128-row x 32-k fp16 tile (8KB, [128][64B] rows, slot^(row&3)
//      swizzle) into LDS via global_load_lds with pre-swizzled source.
__device__ __forceinline__ void stage16(const _Float16* __restrict__ src,
                                        int row_base, int row_max, int k0,
                                        char* lds, int tid) {
#pragma unroll
    for (int q = 0; q < 2; ++q) {
        int off = q * 4096 + tid * 16;
        int row = off >> 6;
        int slot = (off >> 4) & 3;
        int se = slot ^ (row & 3);
        int grow = row_base + row;
        if (grow > row_max) grow = row_max;
        gl_lds16(src + (size_t)grow * 256 + k0 + se * 8,
                 lds + q * 4096 + (tid >> 6) * 1024);   // wave-uniform LDS base
    }
}

// ---- same tile from an fp32 source: reg-staged load + cvt + ds_write (swizzled)
__device__ __forceinline__ void stage16_f32(const float* __restrict__ X,
                                            int row_base, int row_max, int k0,
                                            char* lds, int tid) {
#pragma unroll
    for (int u = 0; u < 4; ++u) {
        int unit = u * 256 + tid;                      // 8B units
        int r = unit >> 3, hu = unit & 7;
        int slot = hu >> 1, sub = (hu & 1) * 8;
        int se = slot ^ (r & 3);
        int grow = row_base + r;
        if (grow > row_max) grow = row_max;
        float4 v = *(const float4*)(X + (size_t)grow * 256 + k0 + se * 8 + (hu & 1) * 4);
        f16x2 p0 = {(f16)v.x, (f16)v.y};
        f16x2 p1 = {(f16)v.z, (f16)v.w};
        uint2 w;
        w.x = __builtin_bit_cast(unsigned, p0);
        w.y = __builtin_bit_cast(unsigned, p1);
        *(uint2*)(lds + r * 64 + slot * 16 + sub) = w;
    }
}

// ---- fp16 MFMA GEMM: [M,256] x [256,512] -> Af f16 (cols 0-255,+bl), Bf f16 (+br)
//      128x128 tile, 4 waves, BK=32, double-buffered 32KB LDS, XCD-aware remap.
//      SRC=0: X fp32 (layer 0, fts); SRC=1: X fp16.
template <int SRC>
__global__ __launch_bounds__(256) void mfma_gemm(const float* __restrict__ Xf,
                                                 const _Float16* __restrict__ X16,
                                                 const _Float16* __restrict__ Wt,
                                                 const float* __restrict__ bl,
                                                 const float* __restrict__ br,
                                                 _Float16* __restrict__ Af,
                                                 _Float16* __restrict__ Bf, int M) {
    __shared__ char smem[32768];                      // 2 bufs x (A 8K + B 8K)
    int Mb = (M + 127) >> 7;
    int b = blockIdx.x;
    int cx = b & 7, rr = b >> 3;                      // cx = XCD slot
    int m_blk = (rr >> 2) * 8 + cx;
    int n_blk = rr & 3;
    if (m_blk >= Mb) return;
    int tid = threadIdx.x;
    int wave = tid >> 6, lane = tid & 63;
    int m0 = m_blk * 128;
    int wr = wave >> 1, wc = wave & 1;
    int r15 = lane & 15, c = lane >> 4;

    f32x4 acc[4][4];
#pragma unroll
    for (int mf = 0; mf < 4; ++mf)
#pragma unroll
        for (int nf = 0; nf < 4; ++nf) acc[mf][nf] = (f32x4){0.f, 0.f, 0.f, 0.f};

    auto stageX = [&](int k0, char* dst) {
        if constexpr (SRC == 0) stage16_f32(Xf, m0, M - 1, k0, dst, tid);
        else                    stage16(X16, m0, M - 1, k0, dst, tid);
    };

    stageX(0, smem);
    stage16(Wt, n_blk * 128, 511, 0, smem + 8192, tid);
    __syncthreads();

    for (int t = 0; t < 8; ++t) {
        int buf = t & 1;
        if (t < 7) {
            char* nb = smem + (buf ^ 1) * 16384;
            stageX((t + 1) * 32, nb);
            stage16(Wt, n_blk * 128, 511, (t + 1) * 32, nb + 8192, tid);
        }
        const char* At = smem + buf * 16384;
        const char* Bt = At + 8192;
        f16x8 af[4], bf[4];
#pragma unroll
        for (int f = 0; f < 4; ++f) {
            int ar = wr * 64 + f * 16 + r15;
            af[f] = *(const f16x8*)(At + ar * 64 + ((c ^ (ar & 3)) << 4));
            int br_ = wc * 64 + f * 16 + r15;
            bf[f] = *(const f16x8*)(Bt + br_ * 64 + ((c ^ (br_ & 3)) << 4));
        }
#pragma unroll
        for (int mf = 0; mf < 4; ++mf)
#pragma unroll
            for (int nf = 0; nf < 4; ++nf)
                acc[mf][nf] = __builtin_amdgcn_mfma_f32_16x16x32_f16(af[mf], bf[nf], acc[mf][nf], 0, 0, 0);
        __syncthreads();
    }

    int q4 = (lane >> 4) * 4;
#pragma unroll
    for (int nf = 0; nf < 4; ++nf) {
        int n_abs = n_blk * 128 + wc * 64 + nf * 16 + r15;
        bool left = n_abs < 256;
        float bb = left ? bl[n_abs] : br[n_abs - 256];
        int col = n_abs & 255;
#pragma unroll
        for (int mf = 0; mf < 4; ++mf) {
            int rowb = m0 + wr * 64 + mf * 16 + q4;
#pragma unroll
            for (int j = 0; j < 4; ++j) {
                int row = rowb + j;
                if (row < M) {
                    float v = acc[mf][nf][j] + bb;
                    if (left) Af[(size_t)row * 256 + col] = (_Float16)v;
                    else      Bf[(size_t)row * 256 + col] = (_Float16)v;
                }
            }
        }
    }
}

// ==================== fixed-capacity binned CSR build (grid.y = layer) ====================
// binA: bin edges by dst>>8 into per-bucket CAP-sized slots; record (dlow<<16)|src
__global__ __launch_bounds__(256) void binA(const int* __restrict__ src0,
                                            const int* __restrict__ dst0,
                                            const int* __restrict__ src1,
                                            const int* __restrict__ dst1,
                                            int Ereal, int EP, int nb,
                                            int* __restrict__ bkt_next,
                                            unsigned* __restrict__ bucketBuf) {
    __shared__ int hist[NB_MAX], base[NB_MAX], ofs[NB_MAX];
    int l = blockIdx.y;
    for (int i = threadIdx.x; i < nb; i += 256) hist[i] = 0;
    __syncthreads();
    const int* src = l ? src1 : src0;
    const int* dst = l ? dst1 : dst0;
    int c0 = blockIdx.x * 4096;
    int dcache[16];
#pragma unroll
    for (int k = 0; k < 16; ++k) {
        int i = c0 + k * 256 + threadIdx.x;
        int d = -1;
        if (i < EP) d = (i < Ereal) ? dst[i] : (i - Ereal);
        dcache[k] = d;
        if (d >= 0) atomicAdd(&hist[d >> 8], 1);
    }
    __syncthreads();
    for (int i = threadIdx.x; i < nb; i += 256) {
        base[i] = hist[i] ? atomicAdd(&bkt_next[l * nb + i], hist[i]) : 0;
        ofs[i] = 0;
    }
    __syncthreads();
#pragma unroll
    for (int k = 0; k < 16; ++k) {
        int i = c0 + k * 256 + threadIdx.x;
        int d = dcache[k];
        if (d >= 0) {
            int s = (i < Ereal) ? src[i] : (i - Ereal);
            int bk = d >> 8;
            int pos = base[bk] + atomicAdd(&ofs[bk], 1);
            bucketBuf[(size_t)(l * nb + bk) * CAP + pos] = (unsigned)s | ((unsigned)(d & 255) << 16);
        }
    }
}

// binB: per-bucket 256-bin counting sort -> beg/end per node + csr (padded layout)
__global__ __launch_bounds__(256) void binB(const unsigned* __restrict__ bucketBuf,
                                            const int* __restrict__ bkt_cnt,
                                            int nb, int N,
                                            int* __restrict__ beg,
                                            int* __restrict__ end_,
                                            int* __restrict__ csr) {
    __shared__ int hist[256], sh[256], nxt[256];
    int b = blockIdx.x, l = blockIdx.y, t = threadIdx.x;
    int cnt = bkt_cnt[l * nb + b];
    const unsigned* buf = bucketBuf + (size_t)(l * nb + b) * CAP;
    int* csrL = csr + (size_t)l * nb * CAP;
    hist[t] = 0;
    __syncthreads();
    for (int i = t; i < cnt; i += 256)
        atomicAdd(&hist[buf[i] >> 16], 1);
    __syncthreads();
    int h = hist[t];
    sh[t] = h;
    __syncthreads();
    for (int o = 1; o < 256; o <<= 1) {
        int x = (t >= o) ? sh[t - o] : 0;
        __syncthreads();
        sh[t] += x;
        __syncthreads();
    }
    int excl = sh[t] - h;
    nxt[t] = excl;
    int d = b * 256 + t;
    if (d < N) {
        beg[(size_t)l * N + d] = b * CAP + excl;
        end_[(size_t)l * N + d] = b * CAP + excl + h;
    }
    __syncthreads();
    for (int i = t; i < cnt; i += 256) {
        unsigned v = buf[i];
        int pos = b * CAP + atomicAdd(&nxt[v >> 16], 1);
        csrL[pos] = (int)(v & 0xFFFFu);
    }
}

// ---- fused GATv2 node pass: one wave64 per node, 32-lane groups x 2 edges,
//      8 gathers in flight, per-group online softmax + single cross-group merge.
//      MODE 0: write y fp16 (feeds next GEMM + next gather); MODE 1: fused head.
template <int MODE>
__global__ __launch_bounds__(256) void gat_node(const _Float16* __restrict__ xl,
                                                const _Float16* __restrict__ xr,
                                                const int* __restrict__ beg_,
                                                const int* __restrict__ end_,
                                                const int* __restrict__ csr_src,
                                                const float* __restrict__ att,
                                                const float* __restrict__ bias,
                                                _Float16* __restrict__ y16,
                                                const float* __restrict__ Wlin,
                                                const float* __restrict__ blin,
                                                float* __restrict__ out, int n) {
    int wid = (int)((blockIdx.x * (size_t)blockDim.x + threadIdx.x) >> 6);
    int lane = threadIdx.x & 63;
    if (wid >= n) return;
    int g = lane >> 5, li = lane & 31;                 // group, lane-in-group
    int beg = beg_[wid], end = end_[wid];

    f16x8 xr8 = ((const f16x8*)(xr + (size_t)wid * 256))[li];  // ch 8li..8li+7
    float4 t0 = ((const float4*)att)[li * 2];
    float4 t1 = ((const float4*)att)[li * 2 + 1];
    f16x2 t01 = {(f16)t0.x, (f16)t0.y}, t23 = {(f16)t0.z, (f16)t0.w};
    f16x2 t45 = {(f16)t1.x, (f16)t1.y}, t67 = {(f16)t1.z, (f16)t1.w};
    const f16 ng = (f16)NEG;
    const f16x8 n8 = {ng, ng, ng, ng, ng, ng, ng, ng};

    float m = -INFINITY, ssum = 0.f;
    float acc[8] = {0.f, 0.f, 0.f, 0.f, 0.f, 0.f, 0.f, 0.f};

    auto step = [&](f16x8 a, bool valid) {
        f16x8 v = a + xr8;
        f16x8 lk = __builtin_elementwise_max(v, v * n8);
#ifdef HAVE_FDOT2
        f16x2 q;
        q[0] = lk[0]; q[1] = lk[1];
        float dot = __builtin_amdgcn_fdot2(q, t01, 0.f, false);
        q[0] = lk[2]; q[1] = lk[3];
        dot = __builtin_amdgcn_fdot2(q, t23, dot, false);
        q[0] = lk[4]; q[1] = lk[5];
        dot = __builtin_amdgcn_fdot2(q, t45, dot, false);
        q[0] = lk[6]; q[1] = lk[7];
        dot = __builtin_amdgcn_fdot2(q, t67, dot, false);
#else
        float dot = (float)lk[0] * (float)t01[0] + (float)lk[1] * (float)t01[1] +
                    (float)lk[2] * (float)t23[0] + (float)lk[3] * (float)t23[1] +
                    (float)lk[4] * (float)t45[0] + (float)lk[5] * (float)t45[1] +
                    (float)lk[6] * (float)t67[0] + (float)lk[7] * (float)t67[1];
#endif
#pragma unroll
        for (int off = 16; off > 0; off >>= 1) dot += __shfl_xor(dot, off);
        if (valid) {
            if (dot > m + 8.f) {            // rare after warm-up
                float sc = __expf(m - dot); // m=-inf first edge -> 0
                ssum = ssum * sc + 1.f;
#pragma unroll
                for (int i = 0; i < 8; ++i) acc[i] = acc[i] * sc + (float)a[i];
                m = dot;
            } else {                        // p bounded by e^8
                float p = __expf(dot - m);
                ssum += p;
#pragma unroll
                for (int i = 0; i < 8; ++i) acc[i] += p * (float)a[i];
            }
        }
    };

    int j = beg;
    for (; j + 16 <= end; j += 16) {        // 8 rows in flight per group
        f16x8 a[8];
#pragma unroll
        for (int u = 0; u < 8; ++u) {
            int s = csr_src[j + 2 * u + g];
            a[u] = ((const f16x8*)(xl + (size_t)s * 256))[li];
        }
#pragma unroll
        for (int u = 0; u < 8; ++u) step(a[u], true);
    }
    if (j + 8 <= end) {
        f16x8 a[4];
#pragma unroll
        for (int u = 0; u < 4; ++u) {
            int s = csr_src[j + 2 * u + g];
            a[u] = ((const f16x8*)(xl + (size_t)s * 256))[li];
        }
#pragma unroll
        for (int u = 0; u < 4; ++u) step(a[u], true);
        j += 8;
    }
    for (; j < end; j += 2) {
        int e = j + g;
        int s = csr_src[e < end ? e : end - 1];
        f16x8 a = ((const f16x8*)(xl + (size_t)s * 256))[li];
        step(a, e < end);
    }

    // ---- merge the two group states
    float m_o = __shfl_xor(m, 32);
    float s_o = __shfl_xor(ssum, 32);
    float ms = fmaxf(m, m_o);
    float wa = __expf(m - ms), wb = __expf(m_o - ms);
    float inv = 1.f / (ssum * wa + s_o * wb);
    float4 bb0 = ((const float4*)bias)[li * 2];
    float4 bb1 = ((const float4*)bias)[li * 2 + 1];
    float bbv[8] = {bb0.x, bb0.y, bb0.z, bb0.w, bb1.x, bb1.y, bb1.z, bb1.w};
    float o8[8];
#pragma unroll
    for (int i = 0; i < 8; ++i) {
        float ao = __shfl_xor(acc[i], 32);
        float o = (acc[i] * wa + ao * wb) * inv + bbv[i];
        o8[i] = o > 0.f ? o : NEG * o;
    }

    if (MODE == 0) {
        if (g == 0) {
            f16x8 w;
#pragma unroll
            for (int i = 0; i < 8; ++i) w[i] = (f16)o8[i];
            ((f16x8*)(y16 + (size_t)wid * 256))[li] = w;
        }
    } else {
        float z0 = 0.f, z1 = 0.f;
#pragma unroll
        for (int p = 0; p < 4; ++p) {
            float4 q = ((const float4*)Wlin)[li * 4 + p];
            z0 += o8[2 * p] * q.x + o8[2 * p + 1] * q.z;
            z1 += o8[2 * p] * q.y + o8[2 * p + 1] * q.w;
        }
#pragma unroll
        for (int off = 16; off > 0; off >>= 1) {
            z0 += __shfl_xor(z0, off);
            z1 += __shfl_xor(z1, off);
        }
        if (lane == 0) {
            z0 += blin[0];
            z1 += blin[1];
            float mx = fmaxf(z0, z1);
            float lse = mx + logf(expf(z0 - mx) + expf(z1 - mx));
            out[(size_t)wid * 2 + 0] = z0 - lse;
            out[(size_t)wid * 2 + 1] = z1 - lse;
        }
    }
}

extern "C" void kernel_launch(void* const* d_in, const int* in_sizes, int n_in,
                              void* d_out, int out_size, void* d_ws, size_t ws_size,
                              hipStream_t stream) {
    const float* fts   = (const float*)d_in[0];
    const int*   graph = (const int*)d_in[1];
    const float* Wl0 = (const float*)d_in[2];
    const float* Wr0 = (const float*)d_in[3];
    const float* bl0 = (const float*)d_in[4];
    const float* br0 = (const float*)d_in[5];
    const float* att0 = (const float*)d_in[6];
    const float* b0  = (const float*)d_in[7];
    const float* Wl1 = (const float*)d_in[8];
    const float* Wr1 = (const float*)d_in[9];
    const float* bl1 = (const float*)d_in[10];
    const float* br1 = (const float*)d_in[11];
    const float* att1 = (const float*)d_in[12];
    const float* b1  = (const float*)d_in[13];
    const float* Wlin = (const float*)d_in[14];
    const float* blin = (const float*)d_in[15];

    int N = out_size / 2;                                   // 40000
    long T = in_sizes[0] / ((long)N * 256);                 // 4
    long E = in_sizes[1] / (2 * T);                         // 640000
    int EP = (int)E + N;
    int nb = (N + 255) / 256;                               // 157 buckets

    char* ws = (char*)d_ws;
    size_t off = 0;
    auto alloc = [&](size_t bytes) -> void* {
        void* p = ws + off;
        off += (bytes + 255) & ~(size_t)255;
        return p;
    };
    _Float16* Af  = (_Float16*)alloc((size_t)N * 256 * 2);  // xl (fp16)
    _Float16* Bf  = (_Float16*)alloc((size_t)N * 256 * 2);  // xr (fp16)
    _Float16* Y16 = (_Float16*)alloc((size_t)N * 256 * 2);  // layer-0 output
    _Float16* Wt  = (_Float16*)alloc((size_t)2 * 512 * 256 * 2);
    int* beg      = (int*)alloc((size_t)2 * N * 4);
    int* end_     = (int*)alloc((size_t)2 * N * 4);
    int* csr      = (int*)alloc((size_t)2 * nb * CAP * 4);
    unsigned* bucketBuf = (unsigned*)alloc((size_t)2 * nb * CAP * 4);
    int* bkt_next = (int*)alloc((size_t)2 * nb * 4);
    (void)ws_size; (void)n_in;

    int Mb = (N + 127) / 128;                               // 313
    int gemm_blocks = ((Mb + 7) / 8) * 8 * 4;               // XCD-padded grid
    dim3 chunk_grid((EP + 4095) / 4096, 2);
    int node_blocks = (N + 3) / 4;

    const int* src0 = graph;
    const int* dst0 = graph + E;
    const int* srcL = graph + (T - 1) * 2 * E;
    const int* dstL = graph + (T - 1) * 2 * E + E;

    // ---------- upfront: weight convert (+ zero counters) + CSR build ----------
    convert_w2<<<dim3(512, 2), 256, 0, stream>>>(Wl0, Wr0, Wl1, Wr1, Wt, bkt_next, 2 * nb);
    binA<<<chunk_grid, 256, 0, stream>>>(src0, dst0, srcL, dstL, (int)E, EP, nb,
                                         bkt_next, bucketBuf);
    binB<<<dim3(nb, 2), 256, 0, stream>>>(bucketBuf, bkt_next, nb, N, beg, end_, csr);

    // ---------- layer 0 (GEMM reads fts fp32 directly) ----------
    mfma_gemm<0><<<gemm_blocks, 256, 0, stream>>>(fts, nullptr, Wt, bl0, br0, Af, Bf, N);
    gat_node<0><<<node_blocks, 256, 0, stream>>>(Af, Bf, beg, end_, csr, att0, b0,
                                                 Y16, nullptr, nullptr, nullptr, N);

    // ---------- layer 1 ----------
    mfma_gemm<1><<<gemm_blocks, 256, 0, stream>>>(nullptr, Y16, Wt + (size_t)512 * 256,
                                                  bl1, br1, Af, Bf, N);
    gat_node<1><<<node_blocks, 256, 0, stream>>>(Af, Bf, beg + N, end_ + N,
                                                 csr + (size_t)nb * CAP, att1, b1,
                                                 nullptr, Wlin, blin, (float*)d_out, N);
}

// Round 11
// 232.598 us; speedup vs baseline: 23.5374x; 1.0106x over previous
//
#include <hip/hip_runtime.h>
#include <hip/hip_bf16.h>
#include <math.h>

#define NEG 0.2f
#define NB_MAX 256
#define CAP 5120

typedef float f32x4 __attribute__((ext_vector_type(4)));
typedef _Float16 f16;
typedef _Float16 f16x2 __attribute__((ext_vector_type(2)));
typedef _Float16 f16x8 __attribute__((ext_vector_type(8)));

#if defined(__has_builtin)
#if __has_builtin(__builtin_amdgcn_fdot2)
#define HAVE_FDOT2 1
#endif
#endif

typedef __attribute__((address_space(3))) void as3_void;
typedef __attribute__((address_space(1))) const void as1_void;

__device__ __forceinline__ void gl_lds16(const void* g, void* l) {
    __builtin_amdgcn_global_load_lds((as1_void*)g, (as3_void*)l, 16, 0, 0);
}

// ---- build transposed combined fp16 weights for BOTH layers; block (0,0) also
//      zeroes the bucket counters (runs before binA on the same stream).
__global__ __launch_bounds__(256) void convert_w2(const float* __restrict__ Wl0,
                                                  const float* __restrict__ Wr0,
                                                  const float* __restrict__ Wl1,
                                                  const float* __restrict__ Wr1,
                                                  _Float16* __restrict__ Wt,
                                                  int* __restrict__ bkt_next, int nb2) {
    int l = blockIdx.y;
    int idx = blockIdx.x * blockDim.x + threadIdx.x;   // n*256 + k
    int n = idx >> 8, k = idx & 255;
    const float* Wl = l ? Wl1 : Wl0;
    const float* Wr = l ? Wr1 : Wr0;
    float v = (n < 256) ? Wl[k * 256 + n] : Wr[k * 256 + (n - 256)];
    Wt[(size_t)l * 512 * 256 + idx] = (_Float16)v;
    if (blockIdx.x == 0 && l == 0)
        for (int i = threadIdx.x; i < nb2; i += 256) bkt_next[i] = 0;
}

// ---- stage one 128-row x 32-k fp16 tile (8KB, [128][64B] rows, slot^(row&3)
//      swizzle) into LDS via global_load_lds with pre-swizzled source.
__device__ __forceinline__ void stage16(const _Float16* __restrict__ src,
                                        int row_base, int row_max, int k0,
                                        char* lds, int tid) {
#pragma unroll
    for (int q = 0; q < 2; ++q) {
        int off = q * 4096 + tid * 16;
        int row = off >> 6;
        int slot = (off >> 4) & 3;
        int se = slot ^ (row & 3);
        int grow = row_base + row;
        if (grow > row_max) grow = row_max;
        gl_lds16(src + (size_t)grow * 256 + k0 + se * 8,
                 lds + q * 4096 + (tid >> 6) * 1024);   // wave-uniform LDS base
    }
}

// ---- same tile from an fp32 source: reg-staged load + cvt + ds_write (swizzled)
__device__ __forceinline__ void stage16_f32(const float* __restrict__ X,
                                            int row_base, int row_max, int k0,
                                            char* lds, int tid) {
#pragma unroll
    for (int u = 0; u < 4; ++u) {
        int unit = u * 256 + tid;                      // 8B units
        int r = unit >> 3, hu = unit & 7;
        int slot = hu >> 1, sub = (hu & 1) * 8;
        int se = slot ^ (r & 3);
        int grow = row_base + r;
        if (grow > row_max) grow = row_max;
        float4 v = *(const float4*)(X + (size_t)grow * 256 + k0 + se * 8 + (hu & 1) * 4);
        f16x2 p0 = {(f16)v.x, (f16)v.y};
        f16x2 p1 = {(f16)v.z, (f16)v.w};
        uint2 w;
        w.x = __builtin_bit_cast(unsigned, p0);
        w.y = __builtin_bit_cast(unsigned, p1);
        *(uint2*)(lds + r * 64 + slot * 16 + sub) = w;
    }
}

// ---- fp16 MFMA GEMM body: [M,256] x [256,512] -> Af f16 (+bl), Bf f16 (+br)
//      128x128 tile, 4 waves, BK=32, double-buffered 32KB LDS, XCD-aware remap.
template <int SRC>
__device__ __forceinline__ void gemm_body(char* smem, int b,
                                          const float* __restrict__ Xf,
                                          const _Float16* __restrict__ X16,
                                          const _Float16* __restrict__ Wt,
                                          const float* __restrict__ bl,
                                          const float* __restrict__ br,
                                          _Float16* __restrict__ Af,
                                          _Float16* __restrict__ Bf, int M) {
    int Mb = (M + 127) >> 7;
    int cx = b & 7, rr = b >> 3;                      // cx = XCD slot
    int m_blk = (rr >> 2) * 8 + cx;
    int n_blk = rr & 3;
    if (m_blk >= Mb) return;
    int tid = threadIdx.x;
    int wave = tid >> 6, lane = tid & 63;
    int m0 = m_blk * 128;
    int wr = wave >> 1, wc = wave & 1;
    int r15 = lane & 15, c = lane >> 4;

    f32x4 acc[4][4];
#pragma unroll
    for (int mf = 0; mf < 4; ++mf)
#pragma unroll
        for (int nf = 0; nf < 4; ++nf) acc[mf][nf] = (f32x4){0.f, 0.f, 0.f, 0.f};

    auto stageX = [&](int k0, char* dst) {
        if constexpr (SRC == 0) stage16_f32(Xf, m0, M - 1, k0, dst, tid);
        else                    stage16(X16, m0, M - 1, k0, dst, tid);
    };

    stageX(0, smem);
    stage16(Wt, n_blk * 128, 511, 0, smem + 8192, tid);
    __syncthreads();

    for (int t = 0; t < 8; ++t) {
        int buf = t & 1;
        if (t < 7) {
            char* nb2 = smem + (buf ^ 1) * 16384;
            stageX((t + 1) * 32, nb2);
            stage16(Wt, n_blk * 128, 511, (t + 1) * 32, nb2 + 8192, tid);
        }
        const char* At = smem + buf * 16384;
        const char* Bt = At + 8192;
        f16x8 af[4], bf[4];
#pragma unroll
        for (int f = 0; f < 4; ++f) {
            int ar = wr * 64 + f * 16 + r15;
            af[f] = *(const f16x8*)(At + ar * 64 + ((c ^ (ar & 3)) << 4));
            int br_ = wc * 64 + f * 16 + r15;
            bf[f] = *(const f16x8*)(Bt + br_ * 64 + ((c ^ (br_ & 3)) << 4));
        }
#pragma unroll
        for (int mf = 0; mf < 4; ++mf)
#pragma unroll
            for (int nf = 0; nf < 4; ++nf)
                acc[mf][nf] = __builtin_amdgcn_mfma_f32_16x16x32_f16(af[mf], bf[nf], acc[mf][nf], 0, 0, 0);
        __syncthreads();
    }

    int q4 = (lane >> 4) * 4;
#pragma unroll
    for (int nf = 0; nf < 4; ++nf) {
        int n_abs = n_blk * 128 + wc * 64 + nf * 16 + r15;
        bool left = n_abs < 256;
        float bb = left ? bl[n_abs] : br[n_abs - 256];
        int col = n_abs & 255;
#pragma unroll
        for (int mf = 0; mf < 4; ++mf) {
            int rowb = m0 + wr * 64 + mf * 16 + q4;
#pragma unroll
            for (int j = 0; j < 4; ++j) {
                int row = rowb + j;
                if (row < M) {
                    float v = acc[mf][nf][j] + bb;
                    if (left) Af[(size_t)row * 256 + col] = (_Float16)v;
                    else      Bf[(size_t)row * 256 + col] = (_Float16)v;
                }
            }
        }
    }
}

// ==================== binA: bin edges by dst>>8 (CAP-sized buckets, both layers) ====
__global__ __launch_bounds__(256) void binA(const int* __restrict__ src0,
                                            const int* __restrict__ dst0,
                                            const int* __restrict__ src1,
                                            const int* __restrict__ dst1,
                                            int Ereal, int EP, int nb,
                                            int* __restrict__ bkt_next,
                                            unsigned* __restrict__ bucketBuf) {
    __shared__ int hist[NB_MAX], base[NB_MAX], ofs[NB_MAX];
    int l = blockIdx.y;
    for (int i = threadIdx.x; i < nb; i += 256) hist[i] = 0;
    __syncthreads();
    const int* src = l ? src1 : src0;
    const int* dst = l ? dst1 : dst0;
    int c0 = blockIdx.x * 4096;
    int dcache[16];
#pragma unroll
    for (int k = 0; k < 16; ++k) {
        int i = c0 + k * 256 + threadIdx.x;
        int d = -1;
        if (i < EP) d = (i < Ereal) ? dst[i] : (i - Ereal);
        dcache[k] = d;
        if (d >= 0) atomicAdd(&hist[d >> 8], 1);
    }
    __syncthreads();
    for (int i = threadIdx.x; i < nb; i += 256) {
        base[i] = hist[i] ? atomicAdd(&bkt_next[l * nb + i], hist[i]) : 0;
        ofs[i] = 0;
    }
    __syncthreads();
#pragma unroll
    for (int k = 0; k < 16; ++k) {
        int i = c0 + k * 256 + threadIdx.x;
        int d = dcache[k];
        if (d >= 0) {
            int s = (i < Ereal) ? src[i] : (i - Ereal);
            int bk = d >> 8;
            int pos = base[bk] + atomicAdd(&ofs[bk], 1);
            bucketBuf[(size_t)(l * nb + bk) * CAP + pos] = (unsigned)s | ((unsigned)(d & 255) << 16);
        }
    }
}

// ==================== merged: binB (blocks 0..2*nb) || gemm layer-0 (rest) ==========
__global__ __launch_bounds__(256) void binB_gemm0(const unsigned* __restrict__ bucketBuf,
                                                  const int* __restrict__ bkt_cnt,
                                                  int nb, int N,
                                                  int* __restrict__ beg,
                                                  int* __restrict__ end_,
                                                  unsigned short* __restrict__ csr16,
                                                  const float* __restrict__ Xf,
                                                  const _Float16* __restrict__ Wt,
                                                  const float* __restrict__ bl,
                                                  const float* __restrict__ br,
                                                  _Float16* __restrict__ Af,
                                                  _Float16* __restrict__ Bf, int M) {
    __shared__ char smem[32768];
    int blk = blockIdx.x;
    if (blk < 2 * nb) {
        // ---- binB: per-bucket 256-bin counting sort -> beg/end + u16 csr ----
        int* hist = (int*)smem;
        int* sh   = (int*)(smem + 1024);
        int* nxt  = (int*)(smem + 2048);
        int l = blk / nb, b = blk % nb, t = threadIdx.x;
        int cnt = bkt_cnt[l * nb + b];
        const unsigned* buf = bucketBuf + (size_t)(l * nb + b) * CAP;
        unsigned short* csrL = csr16 + (size_t)l * nb * CAP;
        hist[t] = 0;
        __syncthreads();
        for (int i = t; i < cnt; i += 256)
            atomicAdd(&hist[buf[i] >> 16], 1);
        __syncthreads();
        int h = hist[t];
        sh[t] = h;
        __syncthreads();
        for (int o = 1; o < 256; o <<= 1) {
            int x = (t >= o) ? sh[t - o] : 0;
            __syncthreads();
            sh[t] += x;
            __syncthreads();
        }
        int excl = sh[t] - h;
        nxt[t] = excl;
        int d = b * 256 + t;
        if (d < N) {
            beg[(size_t)l * N + d] = b * CAP + excl;
            end_[(size_t)l * N + d] = b * CAP + excl + h;
        }
        __syncthreads();
        for (int i = t; i < cnt; i += 256) {
            unsigned v = buf[i];
            int pos = b * CAP + atomicAdd(&nxt[v >> 16], 1);
            csrL[pos] = (unsigned short)(v & 0xFFFFu);
        }
        return;
    }
    gemm_body<0>(smem, blk - 2 * nb, Xf, nullptr, Wt, bl, br, Af, Bf, M);
}

// ---- standalone layer-1 GEMM (fp16 X) ----
__global__ __launch_bounds__(256) void mfma_gemm1(const _Float16* __restrict__ X16,
                                                  const _Float16* __restrict__ Wt,
                                                  const float* __restrict__ bl,
                                                  const float* __restrict__ br,
                                                  _Float16* __restrict__ Af,
                                                  _Float16* __restrict__ Bf, int M) {
    __shared__ char smem[32768];
    gemm_body<1>(smem, blockIdx.x, nullptr, X16, Wt, bl, br, Af, Bf, M);
}

// ---- fused GATv2 node pass: one wave64 per node, 32-lane groups x 2 edges,
//      8 gathers in flight, per-group online softmax + single cross-group merge.
//      MODE 0: write y fp16 (feeds next GEMM + next gather); MODE 1: fused head.
template <int MODE>
__global__ __launch_bounds__(256) void gat_node(const _Float16* __restrict__ xl,
                                                const _Float16* __restrict__ xr,
                                                const int* __restrict__ beg_,
                                                const int* __restrict__ end_,
                                                const unsigned short* __restrict__ csr,
                                                const float* __restrict__ att,
                                                const float* __restrict__ bias,
                                                _Float16* __restrict__ y16,
                                                const float* __restrict__ Wlin,
                                                const float* __restrict__ blin,
                                                float* __restrict__ out, int n) {
    int wid = (int)((blockIdx.x * (size_t)blockDim.x + threadIdx.x) >> 6);
    int lane = threadIdx.x & 63;
    if (wid >= n) return;
    int g = lane >> 5, li = lane & 31;                 // group, lane-in-group
    int beg = beg_[wid], end = end_[wid];

    f16x8 xr8 = ((const f16x8*)(xr + (size_t)wid * 256))[li];  // ch 8li..8li+7
    float4 t0 = ((const float4*)att)[li * 2];
    float4 t1 = ((const float4*)att)[li * 2 + 1];
    f16x2 t01 = {(f16)t0.x, (f16)t0.y}, t23 = {(f16)t0.z, (f16)t0.w};
    f16x2 t45 = {(f16)t1.x, (f16)t1.y}, t67 = {(f16)t1.z, (f16)t1.w};
    const f16 ng = (f16)NEG;
    const f16x8 n8 = {ng, ng, ng, ng, ng, ng, ng, ng};

    float m = -INFINITY, ssum = 0.f;
    float acc[8] = {0.f, 0.f, 0.f, 0.f, 0.f, 0.f, 0.f, 0.f};

    auto step = [&](f16x8 a, bool valid) {
        f16x8 v = a + xr8;
        f16x8 lk = __builtin_elementwise_max(v, v * n8);
#ifdef HAVE_FDOT2
        f16x2 q;
        q[0] = lk[0]; q[1] = lk[1];
        float dot = __builtin_amdgcn_fdot2(q, t01, 0.f, false);
        q[0] = lk[2]; q[1] = lk[3];
        dot = __builtin_amdgcn_fdot2(q, t23, dot, false);
        q[0] = lk[4]; q[1] = lk[5];
        dot = __builtin_amdgcn_fdot2(q, t45, dot, false);
        q[0] = lk[6]; q[1] = lk[7];
        dot = __builtin_amdgcn_fdot2(q, t67, dot, false);
#else
        float dot = (float)lk[0] * (float)t01[0] + (float)lk[1] * (float)t01[1] +
                    (float)lk[2] * (float)t23[0] + (float)lk[3] * (float)t23[1] +
                    (float)lk[4] * (float)t45[0] + (float)lk[5] * (float)t45[1] +
                    (float)lk[6] * (float)t67[0] + (float)lk[7] * (float)t67[1];
#endif
#pragma unroll
        for (int off = 16; off > 0; off >>= 1) dot += __shfl_xor(dot, off);
        if (valid) {
            if (dot > m + 8.f) {            // rare after warm-up
                float sc = __expf(m - dot); // m=-inf first edge -> 0
                ssum = ssum * sc + 1.f;
#pragma unroll
                for (int i = 0; i < 8; ++i) acc[i] = acc[i] * sc + (float)a[i];
                m = dot;
            } else {                        // p bounded by e^8
                float p = __expf(dot - m);
                ssum += p;
#pragma unroll
                for (int i = 0; i < 8; ++i) acc[i] += p * (float)a[i];
            }
        }
    };

    int j = beg;
    for (; j + 16 <= end; j += 16) {        // 8 rows in flight per group
        f16x8 a[8];
#pragma unroll
        for (int u = 0; u < 8; ++u) {
            int s = csr[j + 2 * u + g];
            a[u] = ((const f16x8*)(xl + (size_t)s * 256))[li];
        }
#pragma unroll
        for (int u = 0; u < 8; ++u) step(a[u], true);
    }
    if (j + 8 <= end) {
        f16x8 a[4];
#pragma unroll
        for (int u = 0; u < 4; ++u) {
            int s = csr[j + 2 * u + g];
            a[u] = ((const f16x8*)(xl + (size_t)s * 256))[li];
        }
#pragma unroll
        for (int u = 0; u < 4; ++u) step(a[u], true);
        j += 8;
    }
    for (; j < end; j += 2) {
        int e = j + g;
        int s = csr[e < end ? e : end - 1];
        f16x8 a = ((const f16x8*)(xl + (size_t)s * 256))[li];
        step(a, e < end);
    }

    // ---- merge the two group states
    float m_o = __shfl_xor(m, 32);
    float s_o = __shfl_xor(ssum, 32);
    float ms = fmaxf(m, m_o);
    float wa = __expf(m - ms), wb = __expf(m_o - ms);
    float inv = 1.f / (ssum * wa + s_o * wb);
    float4 bb0 = ((const float4*)bias)[li * 2];
    float4 bb1 = ((const float4*)bias)[li * 2 + 1];
    float bbv[8] = {bb0.x, bb0.y, bb0.z, bb0.w, bb1.x, bb1.y, bb1.z, bb1.w};
    float o8[8];
#pragma unroll
    for (int i = 0; i < 8; ++i) {
        float ao = __shfl_xor(acc[i], 32);
        float o = (acc[i] * wa + ao * wb) * inv + bbv[i];
        o8[i] = o > 0.f ? o : NEG * o;
    }

    if (MODE == 0) {
        if (g == 0) {
            f16x8 w;
#pragma unroll
            for (int i = 0; i < 8; ++i) w[i] = (f16)o8[i];
            ((f16x8*)(y16 + (size_t)wid * 256))[li] = w;
        }
    } else {
        float z0 = 0.f, z1 = 0.f;
#pragma unroll
        for (int p = 0; p < 4; ++p) {
            float4 q = ((const float4*)Wlin)[li * 4 + p];
            z0 += o8[2 * p] * q.x + o8[2 * p + 1] * q.z;
            z1 += o8[2 * p] * q.y + o8[2 * p + 1] * q.w;
        }
#pragma unroll
        for (int off = 16; off > 0; off >>= 1) {
            z0 += __shfl_xor(z0, off);
            z1 += __shfl_xor(z1, off);
        }
        if (lane == 0) {
            z0 += blin[0];
            z1 += blin[1];
            float mx = fmaxf(z0, z1);
            float lse = mx + logf(expf(z0 - mx) + expf(z1 - mx));
            out[(size_t)wid * 2 + 0] = z0 - lse;
            out[(size_t)wid * 2 + 1] = z1 - lse;
        }
    }
}

extern "C" void kernel_launch(void* const* d_in, const int* in_sizes, int n_in,
                              void* d_out, int out_size, void* d_ws, size_t ws_size,
                              hipStream_t stream) {
    const float* fts   = (const float*)d_in[0];
    const int*   graph = (const int*)d_in[1];
    const float* Wl0 = (const float*)d_in[2];
    const float* Wr0 = (const float*)d_in[3];
    const float* bl0 = (const float*)d_in[4];
    const float* br0 = (const float*)d_in[5];
    const float* att0 = (const float*)d_in[6];
    const float* b0  = (const float*)d_in[7];
    const float* Wl1 = (const float*)d_in[8];
    const float* Wr1 = (const float*)d_in[9];
    const float* bl1 = (const float*)d_in[10];
    const float* br1 = (const float*)d_in[11];
    const float* att1 = (const float*)d_in[12];
    const float* b1  = (const float*)d_in[13];
    const float* Wlin = (const float*)d_in[14];
    const float* blin = (const float*)d_in[15];

    int N = out_size / 2;                                   // 40000
    long T = in_sizes[0] / ((long)N * 256);                 // 4
    long E = in_sizes[1] / (2 * T);                         // 640000
    int EP = (int)E + N;
    int nb = (N + 255) / 256;                               // 157 buckets

    char* ws = (char*)d_ws;
    size_t off = 0;
    auto alloc = [&](size_t bytes) -> void* {
        void* p = ws + off;
        off += (bytes + 255) & ~(size_t)255;
        return p;
    };
    _Float16* Af  = (_Float16*)alloc((size_t)N * 256 * 2);  // xl (fp16)
    _Float16* Bf  = (_Float16*)alloc((size_t)N * 256 * 2);  // xr (fp16)
    _Float16* Y16 = (_Float16*)alloc((size_t)N * 256 * 2);  // layer-0 output
    _Float16* Wt  = (_Float16*)alloc((size_t)2 * 512 * 256 * 2);
    int* beg      = (int*)alloc((size_t)2 * N * 4);
    int* end_     = (int*)alloc((size_t)2 * N * 4);
    unsigned short* csr16 = (unsigned short*)alloc((size_t)2 * nb * CAP * 2);
    unsigned* bucketBuf = (unsigned*)alloc((size_t)2 * nb * CAP * 4);
    int* bkt_next = (int*)alloc((size_t)2 * nb * 4);
    (void)ws_size; (void)n_in;

    int Mb = (N + 127) / 128;                               // 313
    int gemm_blocks = ((Mb + 7) / 8) * 8 * 4;               // XCD-padded grid
    dim3 chunk_grid((EP + 4095) / 4096, 2);
    int node_blocks = (N + 3) / 4;

    const int* src0 = graph;
    const int* dst0 = graph + E;
    const int* srcL = graph + (T - 1) * 2 * E;
    const int* dstL = graph + (T - 1) * 2 * E + E;

    // 1. weight convert (+ zero bucket counters)
    convert_w2<<<dim3(512, 2), 256, 0, stream>>>(Wl0, Wr0, Wl1, Wr1, Wt, bkt_next, 2 * nb);
    // 2. bin edges into CAP-sized dst/256 buckets (both layers)
    binA<<<chunk_grid, 256, 0, stream>>>(src0, dst0, srcL, dstL, (int)E, EP, nb,
                                         bkt_next, bucketBuf);
    // 3. merged: per-bucket counting sort (both layers) || layer-0 GEMM
    binB_gemm0<<<2 * nb + gemm_blocks, 256, 0, stream>>>(bucketBuf, bkt_next, nb, N,
                                                         beg, end_, csr16,
                                                         fts, Wt, bl0, br0, Af, Bf, N);
    // 4. layer-0 node pass
    gat_node<0><<<node_blocks, 256, 0, stream>>>(Af, Bf, beg, end_, csr16, att0, b0,
                                                 Y16, nullptr, nullptr, nullptr, N);
    // 5. layer-1 GEMM
    mfma_gemm1<<<gemm_blocks, 256, 0, stream>>>(Y16, Wt + (size_t)512 * 256,
                                                bl1, br1, Af, Bf, N);
    // 6. layer-1 node pass + fused head
    gat_node<1><<<node_blocks, 256, 0, stream>>>(Af, Bf, beg + N, end_ + N,
                                                 csr16 + (size_t)nb * CAP, att1, b1,
                                                 nullptr, Wlin, blin, (float*)d_out, N);
}